// Round 6
// baseline (642.498 us; speedup 1.0000x reference)
//
#include <hip/hip_runtime.h>

typedef __attribute__((ext_vector_type(8))) short bf16x8;
typedef __attribute__((ext_vector_type(4))) float f32x4;

#define HHE 512

__device__ __forceinline__ unsigned short rne_bf16(float f) {
    union { float f; unsigned u; } v; v.f = f;
    unsigned r = v.u + 0x7FFFu + ((v.u >> 16) & 1u);
    return (unsigned short)(r >> 16);
}
__device__ __forceinline__ float bf2f(unsigned short s) {
    union { unsigned u; float f; } v; v.u = ((unsigned)s) << 16; return v.f;
}
__device__ __forceinline__ float sigf(float v)   { return 1.0f / (1.0f + __expf(-v)); }
__device__ __forceinline__ float tanhf_(float v) { return 2.0f / (1.0f + __expf(-2.0f * v)) - 1.0f; }

#define MFMA16(a, b, c) __builtin_amdgcn_mfma_f32_16x16x32_bf16(a, b, c, 0, 0, 0)

#define GLOAD_LDS16(g, l) \
    __builtin_amdgcn_global_load_lds((const __attribute__((address_space(1))) void*)(g), \
                                     (__attribute__((address_space(3))) void*)(l), 16, 0, 0)

// ---------- one-time prep, fused into a single dispatch:
//   blocks [0, 1024)    : pack 4 gate weight matrices into MFMA B-fragment order
//                         [gate][jtile(32)][kstep(32)][lane(64)][8]
//   blocks [1024, 9216) : x fp32 -> bf16
__global__ __launch_bounds__(256) void prep(
    const float* __restrict__ x,
    const float* __restrict__ Wi, const float* __restrict__ Wf,
    const float* __restrict__ Wo, const float* __restrict__ Wu,
    unsigned short* __restrict__ xb, unsigned short* __restrict__ wp)
{
    const int b = blockIdx.x;
    if (b < 1024) {
        int t    = b * 256 + threadIdx.x;
        int lane = t & 63;
        int fid  = t >> 6;
        int ks   = fid & 31;
        int jt   = (fid >> 5) & 31;
        int g    = fid >> 10;
        const float* W = (g == 0) ? Wi : (g == 1) ? Wf : (g == 2) ? Wo : Wu;
        int row = jt * 16 + (lane & 15);
        int col = ks * 32 + (lane >> 4) * 8;
        const float* src = W + (size_t)row * 1024 + col;
        float4 f0 = *(const float4*)(src);
        float4 f1 = *(const float4*)(src + 4);
        uint4 o;
        o.x = (unsigned)rne_bf16(f0.x) | ((unsigned)rne_bf16(f0.y) << 16);
        o.y = (unsigned)rne_bf16(f0.z) | ((unsigned)rne_bf16(f0.w) << 16);
        o.z = (unsigned)rne_bf16(f1.x) | ((unsigned)rne_bf16(f1.y) << 16);
        o.w = (unsigned)rne_bf16(f1.z) | ((unsigned)rne_bf16(f1.w) << 16);
        ((uint4*)wp)[t] = o;
    } else {
        size_t idx = (size_t)(b - 1024) * 256 + threadIdx.x;
        if (idx >= 2097088) return;
        const float4* p = (const float4*)x + idx * 2;
        float4 f0 = p[0], f1 = p[1];
        uint4 o;
        o.x = (unsigned)rne_bf16(f0.x) | ((unsigned)rne_bf16(f0.y) << 16);
        o.y = (unsigned)rne_bf16(f0.z) | ((unsigned)rne_bf16(f0.w) << 16);
        o.z = (unsigned)rne_bf16(f1.x) | ((unsigned)rne_bf16(f1.y) << 16);
        o.w = (unsigned)rne_bf16(f1.z) | ((unsigned)rne_bf16(f1.w) << 16);
        ((uint4*)xb)[idx] = o;
    }
}

// ---------- leaf level: 512 threads, 128 rows x 4 jtiles/block (halves total W
// traffic vs 64-row blocks — W is the dominant byte stream). R4 dbuf structure:
// global_load_lds A-staging, __syncthreads per K-step, W register ping-pong.
// wm = wv&3 picks 32-row quarter; wj = wv>>2 picks jtile pair. grid (128, 8). ----------
__global__ __launch_bounds__(512) void leaf_w(
    const unsigned short* __restrict__ xb, const unsigned short* __restrict__ wp,
    const float* __restrict__ bi, const float* __restrict__ bo, const float* __restrict__ bu,
    unsigned short* __restrict__ hw, unsigned short* __restrict__ cw,
    unsigned short* __restrict__ hso,
    int start, int cnt)
{
    __shared__ __align__(16) unsigned short SH[2 * 4096];   // 2 bufs x (128 rows x 32 cols)

    const int tid  = threadIdx.x;
    const int lane = tid & 63;
    const int wv   = tid >> 6;          // 0..7
    const int q    = lane >> 4;
    const int ln   = lane & 15;
    const int wm   = wv & 3;            // 32-row quarter
    const int wj   = wv >> 2;           // jtile pair
    const int mb   = blockIdx.x * 128;
    const int jt0  = blockIdx.y * 4 + wj * 2;

    const int srow   = lane >> 2;
    const int gchunk = (lane & 3) ^ ((lane >> 3) & 3);
    const int stage_row = mb + wv * 16 + srow;
    const int rdoff = ((q ^ ((ln >> 1) & 3)) * 8);

    const unsigned short* wpl = wp + (size_t)lane * 8;

    f32x4 zero = {0.f, 0.f, 0.f, 0.f};
    f32x4 acc_i[2][2], acc_o[2][2], acc_u[2][2];
    #pragma unroll
    for (int t = 0; t < 2; ++t)
        #pragma unroll
        for (int ji = 0; ji < 2; ++ji) {
            acc_i[t][ji] = zero; acc_o[t][ji] = zero; acc_u[t][ji] = zero;
        }

    bf16x8 WA[3][2], WB[3][2];

    // gate map: 0 -> Wi(0), 1 -> Wo(2), 2 -> Wu(3)
    auto loadW = [&](bf16x8 (&W)[3][2], int ksabs) {
        #pragma unroll
        for (int g = 0; g < 3; ++g) {
            const int gg = (g == 0) ? 0 : (g + 1);
            #pragma unroll
            for (int ji = 0; ji < 2; ++ji)
                W[g][ji] = *(const bf16x8*)(wpl + ((size_t)((gg * 32 + jt0 + ji) * 32 + ksabs)) * 512);
        }
    };

    loadW(WA, 0);
    {
        const unsigned short* g = xb + (size_t)(start + stage_row) * HHE + gchunk * 8;
        GLOAD_LDS16(g, &SH[0 * 4096 + wv * 512]);
    }
    __syncthreads();

    auto body = [&](int ks, bf16x8 (&WU)[3][2], bf16x8 (&WP)[3][2], int prefks) {
        const int cur = ks & 1;
        if (ks < 15) {
            const unsigned short* g = xb + (size_t)(start + stage_row) * HHE + (ks + 1) * 32 + gchunk * 8;
            GLOAD_LDS16(g, &SH[(cur ^ 1) * 4096 + wv * 512]);
        }
        loadW(WP, prefks);
        bf16x8 a0 = *(const bf16x8*)&SH[cur * 4096 + (wm * 32 + 0 + ln) * 32 + rdoff];
        bf16x8 a1 = *(const bf16x8*)&SH[cur * 4096 + (wm * 32 + 16 + ln) * 32 + rdoff];
        #pragma unroll
        for (int ji = 0; ji < 2; ++ji) {
            acc_i[0][ji] = MFMA16(a0, WU[0][ji], acc_i[0][ji]);
            acc_i[1][ji] = MFMA16(a1, WU[0][ji], acc_i[1][ji]);
            acc_o[0][ji] = MFMA16(a0, WU[1][ji], acc_o[0][ji]);
            acc_o[1][ji] = MFMA16(a1, WU[1][ji], acc_o[1][ji]);
            acc_u[0][ji] = MFMA16(a0, WU[2][ji], acc_u[0][ji]);
            acc_u[1][ji] = MFMA16(a1, WU[2][ji], acc_u[1][ji]);
        }
        __syncthreads();
    };

    for (int kk = 0; kk < 8; ++kk) {
        body(2 * kk,     WA, WB, 2 * kk + 1);
        body(2 * kk + 1, WB, WA, (kk == 7) ? 15 : 2 * kk + 2);   // last: dummy reload
    }

    // epilogue
    #pragma unroll
    for (int ji = 0; ji < 2; ++ji) {
        const int jj = (jt0 + ji) * 16 + ln;
        const float bij = bi[jj], boj = bo[jj], buj = bu[jj];
        #pragma unroll
        for (int t = 0; t < 2; ++t) {
            const int n0 = mb + wm * 32 + t * 16 + q * 4;
            float hv[4];
            #pragma unroll
            for (int r = 0; r < 4; ++r) {
                const int node = n0 + r;
                float gi = sigf(acc_i[t][ji][r] + bij);
                float go = sigf(acc_o[t][ji][r] + boj);
                float gu = tanhf_(acc_u[t][ji][r] + buj);
                float cnv = gi * gu;
                float hnv = go * tanhf_(cnv);
                hv[r] = hnv;
                size_t oix = (size_t)node * HHE + jj;
                hw[oix] = rne_bf16(hnv);
                cw[oix] = rne_bf16(cnv);
            }
            hso[(size_t)(n0 >> 1) * HHE + jj]       = rne_bf16(hv[0] + hv[1]);
            hso[(size_t)((n0 >> 1) + 1) * HHE + jj] = rne_bf16(hv[2] + hv[3]);
        }
    }
}

// ---------- internal levels 13..7: 512 threads, 128 rows x 4 jtiles/block,
// R4 dbuf structure (LDS-staged A, __syncthreads per K-step, W ping-pong) ----------
__global__ __launch_bounds__(512) void level_w(
    const unsigned short* __restrict__ xb, const unsigned short* __restrict__ wp,
    const float* __restrict__ bi, const float* __restrict__ bfv,
    const float* __restrict__ bo, const float* __restrict__ bu,
    const unsigned short* __restrict__ hc, const unsigned short* __restrict__ cc,
    const unsigned short* __restrict__ hs,
    unsigned short* __restrict__ hw, unsigned short* __restrict__ cw,
    unsigned short* __restrict__ hso,
    int start, int cnt)
{
    __shared__ __align__(16) unsigned short SH[2 * 3 * 4096];   // 48 KB

    const int tid  = threadIdx.x;
    const int lane = tid & 63;
    const int wv   = tid >> 6;          // 0..7
    const int q    = lane >> 4;
    const int ln   = lane & 15;
    const int wm   = wv & 3;
    const int wj   = wv >> 2;
    const int mb   = blockIdx.x * 128;
    const int jt0  = blockIdx.y * 4 + wj * 2;

    const int srow   = lane >> 2;
    const int gchunk = (lane & 3) ^ ((lane >> 3) & 3);
    const int stage_row = mb + wv * 16 + srow;
    const int rdoff = ((q ^ ((ln >> 1) & 3)) * 8);

    const unsigned short* wpl = wp + (size_t)lane * 8;

    f32x4 zero = {0.f, 0.f, 0.f, 0.f};
    f32x4 acc_i[2][2], acc_f[2][2], acc_o[2][2], acc_u[2][2];
    #pragma unroll
    for (int t = 0; t < 2; ++t)
        #pragma unroll
        for (int ji = 0; ji < 2; ++ji) {
            acc_i[t][ji] = zero; acc_f[t][ji] = zero;
            acc_o[t][ji] = zero; acc_u[t][ji] = zero;
        }

    bf16x8 WA[4][2], WB[4][2];

    auto loadW = [&](bf16x8 (&W)[4][2], int ksabs) {
        #pragma unroll
        for (int g = 0; g < 4; ++g)
            #pragma unroll
            for (int ji = 0; ji < 2; ++ji)
                W[g][ji] = *(const bf16x8*)(wpl + ((size_t)((g * 32 + jt0 + ji) * 32 + ksabs)) * 512);
    };

    // ---------------- phase 1: x ----------------
    loadW(WA, 0);
    {
        const unsigned short* g = xb + (size_t)(start + stage_row) * HHE + gchunk * 8;
        GLOAD_LDS16(g, &SH[(0 * 3 + 0) * 4096 + wv * 512]);
    }
    __syncthreads();

    auto p1_body = [&](int ks, bf16x8 (&WU)[4][2], bf16x8 (&WP)[4][2], int prefks) {
        const int cur = ks & 1;
        if (ks < 15) {
            const unsigned short* g = xb + (size_t)(start + stage_row) * HHE + (ks + 1) * 32 + gchunk * 8;
            GLOAD_LDS16(g, &SH[((cur ^ 1) * 3 + 0) * 4096 + wv * 512]);
        }
        loadW(WP, prefks);
        bf16x8 a0 = *(const bf16x8*)&SH[(cur * 3 + 0) * 4096 + (wm * 32 + 0 + ln) * 32 + rdoff];
        bf16x8 a1 = *(const bf16x8*)&SH[(cur * 3 + 0) * 4096 + (wm * 32 + 16 + ln) * 32 + rdoff];
        #pragma unroll
        for (int ji = 0; ji < 2; ++ji) {
            acc_i[0][ji] = MFMA16(a0, WU[0][ji], acc_i[0][ji]);
            acc_i[1][ji] = MFMA16(a1, WU[0][ji], acc_i[1][ji]);
            acc_f[0][ji] = MFMA16(a0, WU[1][ji], acc_f[0][ji]);
            acc_f[1][ji] = MFMA16(a1, WU[1][ji], acc_f[1][ji]);
            acc_o[0][ji] = MFMA16(a0, WU[2][ji], acc_o[0][ji]);
            acc_o[1][ji] = MFMA16(a1, WU[2][ji], acc_o[1][ji]);
            acc_u[0][ji] = MFMA16(a0, WU[3][ji], acc_u[0][ji]);
            acc_u[1][ji] = MFMA16(a1, WU[3][ji], acc_u[1][ji]);
        }
        __syncthreads();
    };

    for (int kk = 0; kk < 8; ++kk) {
        p1_body(2 * kk,     WA, WB, 2 * kk + 1);
        p1_body(2 * kk + 1, WB, WA, (kk == 7) ? 16 : 2 * kk + 2);
    }

    f32x4 acc_fl[2][2], acc_fr[2][2];
    #pragma unroll
    for (int t = 0; t < 2; ++t)
        #pragma unroll
        for (int ji = 0; ji < 2; ++ji) { acc_fl[t][ji] = acc_f[t][ji]; acc_fr[t][ji] = acc_f[t][ji]; }

    // ---------------- phase 2: hsum / h_l / h_r ----------------
    {
        const unsigned short* gs = hs + (size_t)stage_row * HHE + gchunk * 8;
        const unsigned short* gl = hc + ((size_t)(2 * stage_row)) * HHE + gchunk * 8;
        GLOAD_LDS16(gs, &SH[(0 * 3 + 0) * 4096 + wv * 512]);
        GLOAD_LDS16(gl, &SH[(0 * 3 + 1) * 4096 + wv * 512]);
        GLOAD_LDS16(gl + HHE, &SH[(0 * 3 + 2) * 4096 + wv * 512]);
    }
    __syncthreads();

    auto p2_body = [&](int ks, bf16x8 (&WU)[4][2], bf16x8 (&WP)[4][2], int prefks) {
        const int cur = ks & 1;
        if (ks < 15) {
            const unsigned short* gs = hs + (size_t)stage_row * HHE + (ks + 1) * 32 + gchunk * 8;
            const unsigned short* gl = hc + ((size_t)(2 * stage_row)) * HHE + (ks + 1) * 32 + gchunk * 8;
            GLOAD_LDS16(gs, &SH[((cur ^ 1) * 3 + 0) * 4096 + wv * 512]);
            GLOAD_LDS16(gl, &SH[((cur ^ 1) * 3 + 1) * 4096 + wv * 512]);
            GLOAD_LDS16(gl + HHE, &SH[((cur ^ 1) * 3 + 2) * 4096 + wv * 512]);
        }
        loadW(WP, prefks);
        bf16x8 s0 = *(const bf16x8*)&SH[(cur * 3 + 0) * 4096 + (wm * 32 + 0 + ln) * 32 + rdoff];
        bf16x8 s1 = *(const bf16x8*)&SH[(cur * 3 + 0) * 4096 + (wm * 32 + 16 + ln) * 32 + rdoff];
        bf16x8 l0 = *(const bf16x8*)&SH[(cur * 3 + 1) * 4096 + (wm * 32 + 0 + ln) * 32 + rdoff];
        bf16x8 l1 = *(const bf16x8*)&SH[(cur * 3 + 1) * 4096 + (wm * 32 + 16 + ln) * 32 + rdoff];
        bf16x8 r0 = *(const bf16x8*)&SH[(cur * 3 + 2) * 4096 + (wm * 32 + 0 + ln) * 32 + rdoff];
        bf16x8 r1 = *(const bf16x8*)&SH[(cur * 3 + 2) * 4096 + (wm * 32 + 16 + ln) * 32 + rdoff];
        #pragma unroll
        for (int ji = 0; ji < 2; ++ji) {
            acc_i[0][ji]  = MFMA16(s0, WU[0][ji], acc_i[0][ji]);
            acc_i[1][ji]  = MFMA16(s1, WU[0][ji], acc_i[1][ji]);
            acc_o[0][ji]  = MFMA16(s0, WU[2][ji], acc_o[0][ji]);
            acc_o[1][ji]  = MFMA16(s1, WU[2][ji], acc_o[1][ji]);
            acc_u[0][ji]  = MFMA16(s0, WU[3][ji], acc_u[0][ji]);
            acc_u[1][ji]  = MFMA16(s1, WU[3][ji], acc_u[1][ji]);
            acc_fl[0][ji] = MFMA16(l0, WU[1][ji], acc_fl[0][ji]);
            acc_fl[1][ji] = MFMA16(l1, WU[1][ji], acc_fl[1][ji]);
            acc_fr[0][ji] = MFMA16(r0, WU[1][ji], acc_fr[0][ji]);
            acc_fr[1][ji] = MFMA16(r1, WU[1][ji], acc_fr[1][ji]);
        }
        __syncthreads();
    };

    for (int kk = 0; kk < 8; ++kk) {
        p2_body(2 * kk,     WA, WB, 16 + 2 * kk + 1);
        p2_body(2 * kk + 1, WB, WA, (kk == 7) ? 31 : 16 + 2 * kk + 2);
    }

    // ---------------- epilogue ----------------
    #pragma unroll
    for (int ji = 0; ji < 2; ++ji) {
        const int jj = (jt0 + ji) * 16 + ln;
        const float bij = bi[jj], bfj = bfv[jj], boj = bo[jj], buj = bu[jj];
        #pragma unroll
        for (int t = 0; t < 2; ++t) {
            const int n0 = mb + wm * 32 + t * 16 + q * 4;
            float hv[4];
            #pragma unroll
            for (int r = 0; r < 4; ++r) {
                const int node = n0 + r;
                size_t cix = (size_t)(2 * node) * HHE + jj;
                float cl = bf2f(cc[cix]);
                float cr = bf2f(cc[cix + HHE]);
                float gi  = sigf(acc_i[t][ji][r] + bij);
                float gfl = sigf(acc_fl[t][ji][r] + bfj);
                float gfr = sigf(acc_fr[t][ji][r] + bfj);
                float go  = sigf(acc_o[t][ji][r] + boj);
                float gu  = tanhf_(acc_u[t][ji][r] + buj);
                float cnv = gi * gu + gfl * cl + gfr * cr;
                float hnv = go * tanhf_(cnv);
                hv[r] = hnv;
                size_t oix = (size_t)node * HHE + jj;
                hw[oix] = rne_bf16(hnv);
                cw[oix] = rne_bf16(cnv);
            }
            hso[(size_t)(n0 >> 1) * HHE + jj]       = rne_bf16(hv[0] + hv[1]);
            hso[(size_t)((n0 >> 1) + 1) * HHE + jj] = rne_bf16(hv[2] + hv[3]);
        }
    }
}

// ---------- level 6 only (cnt = 64): R4 64-row 4-wave dbuf kernel ----------
__global__ __launch_bounds__(256) void level_v3(
    const unsigned short* __restrict__ xb, const unsigned short* __restrict__ wp,
    const float* __restrict__ bi, const float* __restrict__ bfv,
    const float* __restrict__ bo, const float* __restrict__ bu,
    const unsigned short* __restrict__ hc, const unsigned short* __restrict__ cc,
    const unsigned short* __restrict__ hs,
    unsigned short* __restrict__ hw, unsigned short* __restrict__ cw,
    unsigned short* __restrict__ hso,
    int start, int cnt)
{
    __shared__ __align__(16) unsigned short SH[2 * 3 * 2048];

    const int tid  = threadIdx.x;
    const int lane = tid & 63;
    const int wv   = tid >> 6;
    const int q    = lane >> 4;
    const int ln   = lane & 15;
    const int wm   = wv & 1;
    const int wj   = wv >> 1;
    const int mb   = blockIdx.x * 64;
    const int jt0  = blockIdx.y * 4 + wj * 2;

    const int srow   = lane >> 2;
    const int gchunk = (lane & 3) ^ ((lane >> 3) & 3);
    const int stage_row = mb + wv * 16 + srow;
    const int rdoff = ((q ^ ((ln >> 1) & 3)) * 8);

    const unsigned short* wpl = wp + (size_t)lane * 8;

    f32x4 zero = {0.f, 0.f, 0.f, 0.f};
    f32x4 acc_i[2][2], acc_f[2][2], acc_o[2][2], acc_u[2][2];
    #pragma unroll
    for (int t = 0; t < 2; ++t)
        #pragma unroll
        for (int ji = 0; ji < 2; ++ji) {
            acc_i[t][ji] = zero; acc_f[t][ji] = zero;
            acc_o[t][ji] = zero; acc_u[t][ji] = zero;
        }

    bf16x8 WA[4][2], WB[4][2];

    auto loadW = [&](bf16x8 (&W)[4][2], int ksabs) {
        #pragma unroll
        for (int g = 0; g < 4; ++g)
            #pragma unroll
            for (int ji = 0; ji < 2; ++ji)
                W[g][ji] = *(const bf16x8*)(wpl + ((size_t)((g * 32 + jt0 + ji) * 32 + ksabs)) * 512);
    };

    loadW(WA, 0);
    {
        const unsigned short* g = xb + (size_t)(start + stage_row) * HHE + gchunk * 8;
        GLOAD_LDS16(g, &SH[(0 * 3 + 0) * 2048 + wv * 512]);
    }
    __syncthreads();

    auto p1_body = [&](int ks, bf16x8 (&WU)[4][2], bf16x8 (&WP)[4][2], int prefks) {
        const int cur = ks & 1;
        if (ks < 15) {
            const unsigned short* g = xb + (size_t)(start + stage_row) * HHE + (ks + 1) * 32 + gchunk * 8;
            GLOAD_LDS16(g, &SH[((cur ^ 1) * 3 + 0) * 2048 + wv * 512]);
        }
        loadW(WP, prefks);
        bf16x8 a0 = *(const bf16x8*)&SH[(cur * 3 + 0) * 2048 + (wm * 32 + 0 + ln) * 32 + rdoff];
        bf16x8 a1 = *(const bf16x8*)&SH[(cur * 3 + 0) * 2048 + (wm * 32 + 16 + ln) * 32 + rdoff];
        #pragma unroll
        for (int ji = 0; ji < 2; ++ji) {
            acc_i[0][ji] = MFMA16(a0, WU[0][ji], acc_i[0][ji]);
            acc_i[1][ji] = MFMA16(a1, WU[0][ji], acc_i[1][ji]);
            acc_f[0][ji] = MFMA16(a0, WU[1][ji], acc_f[0][ji]);
            acc_f[1][ji] = MFMA16(a1, WU[1][ji], acc_f[1][ji]);
            acc_o[0][ji] = MFMA16(a0, WU[2][ji], acc_o[0][ji]);
            acc_o[1][ji] = MFMA16(a1, WU[2][ji], acc_o[1][ji]);
            acc_u[0][ji] = MFMA16(a0, WU[3][ji], acc_u[0][ji]);
            acc_u[1][ji] = MFMA16(a1, WU[3][ji], acc_u[1][ji]);
        }
        __syncthreads();
    };

    for (int kk = 0; kk < 8; ++kk) {
        p1_body(2 * kk,     WA, WB, 2 * kk + 1);
        p1_body(2 * kk + 1, WB, WA, (kk == 7) ? 16 : 2 * kk + 2);
    }

    f32x4 acc_fl[2][2], acc_fr[2][2];
    #pragma unroll
    for (int t = 0; t < 2; ++t)
        #pragma unroll
        for (int ji = 0; ji < 2; ++ji) { acc_fl[t][ji] = acc_f[t][ji]; acc_fr[t][ji] = acc_f[t][ji]; }

    {
        const unsigned short* gs = hs + (size_t)stage_row * HHE + gchunk * 8;
        const unsigned short* gl = hc + ((size_t)(2 * stage_row)) * HHE + gchunk * 8;
        GLOAD_LDS16(gs, &SH[(0 * 3 + 0) * 2048 + wv * 512]);
        GLOAD_LDS16(gl, &SH[(0 * 3 + 1) * 2048 + wv * 512]);
        GLOAD_LDS16(gl + HHE, &SH[(0 * 3 + 2) * 2048 + wv * 512]);
    }
    __syncthreads();

    auto p2_body = [&](int ks, bf16x8 (&WU)[4][2], bf16x8 (&WP)[4][2], int prefks) {
        const int cur = ks & 1;
        if (ks < 15) {
            const unsigned short* gs = hs + (size_t)stage_row * HHE + (ks + 1) * 32 + gchunk * 8;
            const unsigned short* gl = hc + ((size_t)(2 * stage_row)) * HHE + (ks + 1) * 32 + gchunk * 8;
            GLOAD_LDS16(gs, &SH[((cur ^ 1) * 3 + 0) * 2048 + wv * 512]);
            GLOAD_LDS16(gl, &SH[((cur ^ 1) * 3 + 1) * 2048 + wv * 512]);
            GLOAD_LDS16(gl + HHE, &SH[((cur ^ 1) * 3 + 2) * 2048 + wv * 512]);
        }
        loadW(WP, prefks);
        bf16x8 s0 = *(const bf16x8*)&SH[(cur * 3 + 0) * 2048 + (wm * 32 + 0 + ln) * 32 + rdoff];
        bf16x8 s1 = *(const bf16x8*)&SH[(cur * 3 + 0) * 2048 + (wm * 32 + 16 + ln) * 32 + rdoff];
        bf16x8 l0 = *(const bf16x8*)&SH[(cur * 3 + 1) * 2048 + (wm * 32 + 0 + ln) * 32 + rdoff];
        bf16x8 l1 = *(const bf16x8*)&SH[(cur * 3 + 1) * 2048 + (wm * 32 + 16 + ln) * 32 + rdoff];
        bf16x8 r0 = *(const bf16x8*)&SH[(cur * 3 + 2) * 2048 + (wm * 32 + 0 + ln) * 32 + rdoff];
        bf16x8 r1 = *(const bf16x8*)&SH[(cur * 3 + 2) * 2048 + (wm * 32 + 16 + ln) * 32 + rdoff];
        #pragma unroll
        for (int ji = 0; ji < 2; ++ji) {
            acc_i[0][ji]  = MFMA16(s0, WU[0][ji], acc_i[0][ji]);
            acc_i[1][ji]  = MFMA16(s1, WU[0][ji], acc_i[1][ji]);
            acc_o[0][ji]  = MFMA16(s0, WU[2][ji], acc_o[0][ji]);
            acc_o[1][ji]  = MFMA16(s1, WU[2][ji], acc_o[1][ji]);
            acc_u[0][ji]  = MFMA16(s0, WU[3][ji], acc_u[0][ji]);
            acc_u[1][ji]  = MFMA16(s1, WU[3][ji], acc_u[1][ji]);
            acc_fl[0][ji] = MFMA16(l0, WU[1][ji], acc_fl[0][ji]);
            acc_fl[1][ji] = MFMA16(l1, WU[1][ji], acc_fl[1][ji]);
            acc_fr[0][ji] = MFMA16(r0, WU[1][ji], acc_fr[0][ji]);
            acc_fr[1][ji] = MFMA16(r1, WU[1][ji], acc_fr[1][ji]);
        }
        __syncthreads();
    };

    for (int kk = 0; kk < 8; ++kk) {
        p2_body(2 * kk,     WA, WB, 16 + 2 * kk + 1);
        p2_body(2 * kk + 1, WB, WA, (kk == 7) ? 31 : 16 + 2 * kk + 2);
    }

    #pragma unroll
    for (int ji = 0; ji < 2; ++ji) {
        const int jj = (jt0 + ji) * 16 + ln;
        const float bij = bi[jj], bfj = bfv[jj], boj = bo[jj], buj = bu[jj];
        #pragma unroll
        for (int t = 0; t < 2; ++t) {
            const int n0 = mb + wm * 32 + t * 16 + q * 4;
            float hv[4];
            #pragma unroll
            for (int r = 0; r < 4; ++r) {
                const int node = n0 + r;
                size_t cix = (size_t)(2 * node) * HHE + jj;
                float cl = bf2f(cc[cix]);
                float cr = bf2f(cc[cix + HHE]);
                float gi  = sigf(acc_i[t][ji][r] + bij);
                float gfl = sigf(acc_fl[t][ji][r] + bfj);
                float gfr = sigf(acc_fr[t][ji][r] + bfj);
                float go  = sigf(acc_o[t][ji][r] + boj);
                float gu  = tanhf_(acc_u[t][ji][r] + buj);
                float cnv = gi * gu + gfl * cl + gfr * cr;
                float hnv = go * tanhf_(cnv);
                hv[r] = hnv;
                size_t oix = (size_t)node * HHE + jj;
                hw[oix] = rne_bf16(hnv);
                cw[oix] = rne_bf16(cnv);
            }
            hso[(size_t)(n0 >> 1) * HHE + jj]       = rne_bf16(hv[0] + hv[1]);
            hso[(size_t)((n0 >> 1) + 1) * HHE + jj] = rne_bf16(hv[2] + hv[3]);
        }
    }
}

// ---------- small levels (5..0): register kernel, 2 m-tiles/wave; grid ((cnt+31)/32, 8) ----------
__global__ __launch_bounds__(256) void level_sm(
    const unsigned short* __restrict__ xb, const unsigned short* __restrict__ wp,
    const float* __restrict__ bi, const float* __restrict__ bfv,
    const float* __restrict__ bo, const float* __restrict__ bu,
    const unsigned short* __restrict__ hc, const unsigned short* __restrict__ cc,
    const unsigned short* __restrict__ hs,
    unsigned short* __restrict__ hw, unsigned short* __restrict__ cw,
    unsigned short* __restrict__ hso,
    float* __restrict__ f32out,
    int start, int cnt)
{
    const int tid  = threadIdx.x;
    const int lane = tid & 63;
    const int wv   = tid >> 6;
    const int quad = lane >> 4;
    const int ln   = lane & 15;
    const int mb   = blockIdx.x * 32;
    const int jt   = blockIdx.y * 4 + wv;
    const int j    = jt * 16 + ln;

    int row[2];
    #pragma unroll
    for (int t = 0; t < 2; ++t) {
        int r = mb + t * 16 + ln;
        row[t] = (r < cnt) ? r : (cnt - 1);
    }
    const unsigned short* ax[2];
    #pragma unroll
    for (int t = 0; t < 2; ++t) ax[t] = xb + (size_t)(start + row[t]) * HHE + quad * 8;

    const unsigned short* bw[4];
    #pragma unroll
    for (int g = 0; g < 4; ++g) bw[g] = wp + ((size_t)(g * 32 + jt) * 32) * 512 + lane * 8;

    f32x4 zero = {0.f, 0.f, 0.f, 0.f};
    f32x4 acc_i[2], acc_f[2], acc_o[2], acc_u[2];
    #pragma unroll
    for (int t = 0; t < 2; ++t) { acc_i[t] = zero; acc_f[t] = zero; acc_o[t] = zero; acc_u[t] = zero; }

    #pragma unroll 4
    for (int ks = 0; ks < 16; ++ks) {
        bf16x8 a[2];
        #pragma unroll
        for (int t = 0; t < 2; ++t) { a[t] = *(const bf16x8*)ax[t]; ax[t] += 32; }
        bf16x8 b0 = *(const bf16x8*)bw[0]; bw[0] += 512;
        bf16x8 b1 = *(const bf16x8*)bw[1]; bw[1] += 512;
        bf16x8 b2 = *(const bf16x8*)bw[2]; bw[2] += 512;
        bf16x8 b3 = *(const bf16x8*)bw[3]; bw[3] += 512;
        #pragma unroll
        for (int t = 0; t < 2; ++t) {
            acc_i[t] = MFMA16(a[t], b0, acc_i[t]);
            acc_f[t] = MFMA16(a[t], b1, acc_f[t]);
            acc_o[t] = MFMA16(a[t], b2, acc_o[t]);
            acc_u[t] = MFMA16(a[t], b3, acc_u[t]);
        }
    }

    f32x4 acc_fl[2], acc_fr[2];
    #pragma unroll
    for (int t = 0; t < 2; ++t) { acc_fl[t] = acc_f[t]; acc_fr[t] = acc_f[t]; }

    const unsigned short* as[2];
    const unsigned short* al[2];
    const unsigned short* ar[2];
    #pragma unroll
    for (int t = 0; t < 2; ++t) {
        as[t] = hs + (size_t)row[t] * HHE + quad * 8;
        al[t] = hc + (size_t)(2 * row[t]) * HHE + quad * 8;
        ar[t] = al[t] + HHE;
    }

    #pragma unroll 4
    for (int ks = 0; ks < 16; ++ks) {
        bf16x8 b0 = *(const bf16x8*)bw[0]; bw[0] += 512;
        bf16x8 b1 = *(const bf16x8*)bw[1]; bw[1] += 512;
        bf16x8 b2 = *(const bf16x8*)bw[2]; bw[2] += 512;
        bf16x8 b3 = *(const bf16x8*)bw[3]; bw[3] += 512;
        bf16x8 s[2];
        #pragma unroll
        for (int t = 0; t < 2; ++t) { s[t] = *(const bf16x8*)as[t]; as[t] += 32; }
        #pragma unroll
        for (int t = 0; t < 2; ++t) {
            acc_i[t] = MFMA16(s[t], b0, acc_i[t]);
            acc_o[t] = MFMA16(s[t], b2, acc_o[t]);
            acc_u[t] = MFMA16(s[t], b3, acc_u[t]);
        }
        bf16x8 l[2];
        #pragma unroll
        for (int t = 0; t < 2; ++t) { l[t] = *(const bf16x8*)al[t]; al[t] += 32; }
        #pragma unroll
        for (int t = 0; t < 2; ++t) acc_fl[t] = MFMA16(l[t], b1, acc_fl[t]);
        bf16x8 rr[2];
        #pragma unroll
        for (int t = 0; t < 2; ++t) { rr[t] = *(const bf16x8*)ar[t]; ar[t] += 32; }
        #pragma unroll
        for (int t = 0; t < 2; ++t) acc_fr[t] = MFMA16(rr[t], b1, acc_fr[t]);
    }

    const float bij = bi[j], bfj = bfv[j], boj = bo[j], buj = bu[j];
    #pragma unroll
    for (int t = 0; t < 2; ++t) {
        const int n0 = mb + t * 16 + quad * 4;
        float hv[4];
        #pragma unroll
        for (int r = 0; r < 4; ++r) {
            const int node = n0 + r;
            const int ncl  = (node < cnt) ? node : (cnt - 1);
            size_t cix = (size_t)(2 * ncl) * HHE + j;
            float cl = bf2f(cc[cix]);
            float cr = bf2f(cc[cix + HHE]);
            float gi  = sigf(acc_i[t][r] + bij);
            float gfl = sigf(acc_fl[t][r] + bfj);
            float gfr = sigf(acc_fr[t][r] + bfj);
            float go  = sigf(acc_o[t][r] + boj);
            float gu  = tanhf_(acc_u[t][r] + buj);
            float cnv = gi * gu + gfl * cl + gfr * cr;
            float hnv = go * tanhf_(cnv);
            hv[r] = hnv;
            if (node < cnt) {
                size_t oix = (size_t)node * HHE + j;
                hw[oix] = rne_bf16(hnv);
                cw[oix] = rne_bf16(cnv);
                if (f32out) {
                    f32out[(size_t)node * 1024 + j]       = hnv;
                    f32out[(size_t)node * 1024 + 512 + j] = cnv;
                }
            }
        }
        if (n0 + 1 < cnt) hso[(size_t)(n0 >> 1) * HHE + j]       = rne_bf16(hv[0] + hv[1]);
        if (n0 + 3 < cnt) hso[(size_t)((n0 >> 1) + 1) * HHE + j] = rne_bf16(hv[2] + hv[3]);
    }
}

extern "C" void kernel_launch(void* const* d_in, const int* in_sizes, int n_in,
                              void* d_out, int out_size, void* d_ws, size_t ws_size,
                              hipStream_t stream) {
    const float* x  = (const float*)d_in[0];
    const float* Wi = (const float*)d_in[1];
    const float* bi = (const float*)d_in[2];
    const float* Wf = (const float*)d_in[3];
    const float* bf = (const float*)d_in[4];
    const float* Wo = (const float*)d_in[5];
    const float* bo = (const float*)d_in[6];
    const float* Wu = (const float*)d_in[7];
    const float* bu = (const float*)d_in[8];
    float* out = (float*)d_out;

    unsigned short* xb  = (unsigned short*)d_ws;          // x bf16
    unsigned short* wp  = xb  + 16776704;                 // packed W bf16
    unsigned short* hA  = wp  + 2097152;                  // h ping (16384 rows)
    unsigned short* hB  = hA  + 8388608;                  // h pong ( 8192 rows)
    unsigned short* hs1 = hB  + 4194304;                  // hsum ( 8192 rows)
    unsigned short* hs2 = hs1 + 4194304;                  // hsum ( 4096 rows)
    unsigned short* cA  = hs2 + 2097152;                  // c ping
    unsigned short* cB  = cA  + 8388608;                  // c pong

    // fused one-time prep: W pack (1024 blocks) + x conversion (8192 blocks)
    prep<<<9216, 256, 0, stream>>>(x, Wi, Wf, Wo, Wu, xb, wp);

    // leaf: 128-row x 4-jtile blocks; grid (128, 8) m-major
    leaf_w<<<dim3(128, 8), 512, 0, stream>>>(xb, wp, bi, bo, bu, hA, cA, hs1, 16383, 16384);

    // levels 13..7 (cnt >= 128): wide 128-row blocks
    for (int lvl = 13; lvl >= 7; --lvl) {
        int cnt   = 1 << lvl;
        int start = cnt - 1;
        const unsigned short *hc, *cc, *hs;
        unsigned short *hw, *cw, *hso;
        if (lvl & 1) { hc = hA; cc = cA; hs = hs1; hw = hB; cw = cB; hso = hs2; }
        else         { hc = hB; cc = cB; hs = hs2; hw = hA; cw = cA; hso = hs1; }
        level_w<<<dim3(cnt / 128, 8), 512, 0, stream>>>(xb, wp, bi, bf, bo, bu,
                                                        hc, cc, hs, hw, cw, hso, start, cnt);
    }

    // level 6 (cnt = 64): R4 64-row kernel
    level_v3<<<dim3(1, 8), 256, 0, stream>>>(xb, wp, bi, bf, bo, bu,
                                             hB, cB, hs2, hA, cA, hs1, 63, 64);

    // levels 5..0: 2-tile register kernel
    for (int lvl = 5; lvl >= 0; --lvl) {
        int cnt   = 1 << lvl;
        int start = cnt - 1;
        const unsigned short *hc, *cc, *hs;
        unsigned short *hw, *cw, *hso;
        if (lvl & 1) { hc = hA; cc = cA; hs = hs1; hw = hB; cw = cB; hso = hs2; }
        else         { hc = hB; cc = cB; hs = hs2; hw = hA; cw = cA; hso = hs1; }
        float* f32out = (lvl == 0) ? out : nullptr;
        level_sm<<<dim3((cnt + 31) / 32, 8), 256, 0, stream>>>(xb, wp, bi, bf, bo, bu,
                                                               hc, cc, hs, hw, cw, hso, f32out,
                                                               start, cnt);
    }
}

// Round 7
// 517.823 us; speedup vs baseline: 1.2408x; 1.2408x over previous
//
#include <hip/hip_runtime.h>

typedef __attribute__((ext_vector_type(8))) short bf16x8;
typedef __attribute__((ext_vector_type(4))) float f32x4;

#define HHE 512

__device__ __forceinline__ unsigned short rne_bf16(float f) {
    union { float f; unsigned u; } v; v.f = f;
    unsigned r = v.u + 0x7FFFu + ((v.u >> 16) & 1u);
    return (unsigned short)(r >> 16);
}
__device__ __forceinline__ float bf2f(unsigned short s) {
    union { unsigned u; float f; } v; v.u = ((unsigned)s) << 16; return v.f;
}
__device__ __forceinline__ float sigf(float v)   { return 1.0f / (1.0f + __expf(-v)); }
__device__ __forceinline__ float tanhf_(float v) { return 2.0f / (1.0f + __expf(-2.0f * v)) - 1.0f; }

#define MFMA16(a, b, c) __builtin_amdgcn_mfma_f32_16x16x32_bf16(a, b, c, 0, 0, 0)

#define GLOAD_LDS16(g, l) \
    __builtin_amdgcn_global_load_lds((const __attribute__((address_space(1))) void*)(g), \
                                     (__attribute__((address_space(3))) void*)(l), 16, 0, 0)

// ---------- one-time prep, fused into a single dispatch:
//   blocks [0, 1024)    : pack 4 gate weight matrices into MFMA B-fragment order
//                         [gate][jtile(32)][kstep(32)][lane(64)][8]
//   blocks [1024, 9216) : x fp32 -> bf16
__global__ __launch_bounds__(256) void prep(
    const float* __restrict__ x,
    const float* __restrict__ Wi, const float* __restrict__ Wf,
    const float* __restrict__ Wo, const float* __restrict__ Wu,
    unsigned short* __restrict__ xb, unsigned short* __restrict__ wp,
    int* __restrict__ bar)
{
    const int b = blockIdx.x;
    if (b < 1024) {
        int t    = b * 256 + threadIdx.x;
        if (bar && t == 0) *bar = 0;   // reset tail spin-barrier each replay
        int lane = t & 63;
        int fid  = t >> 6;
        int ks   = fid & 31;
        int jt   = (fid >> 5) & 31;
        int g    = fid >> 10;
        const float* W = (g == 0) ? Wi : (g == 1) ? Wf : (g == 2) ? Wo : Wu;
        int row = jt * 16 + (lane & 15);
        int col = ks * 32 + (lane >> 4) * 8;
        const float* src = W + (size_t)row * 1024 + col;
        float4 f0 = *(const float4*)(src);
        float4 f1 = *(const float4*)(src + 4);
        uint4 o;
        o.x = (unsigned)rne_bf16(f0.x) | ((unsigned)rne_bf16(f0.y) << 16);
        o.y = (unsigned)rne_bf16(f0.z) | ((unsigned)rne_bf16(f0.w) << 16);
        o.z = (unsigned)rne_bf16(f1.x) | ((unsigned)rne_bf16(f1.y) << 16);
        o.w = (unsigned)rne_bf16(f1.z) | ((unsigned)rne_bf16(f1.w) << 16);
        ((uint4*)wp)[t] = o;
    } else {
        size_t idx = (size_t)(b - 1024) * 256 + threadIdx.x;
        if (idx >= 2097088) return;
        const float4* p = (const float4*)x + idx * 2;
        float4 f0 = p[0], f1 = p[1];
        uint4 o;
        o.x = (unsigned)rne_bf16(f0.x) | ((unsigned)rne_bf16(f0.y) << 16);
        o.y = (unsigned)rne_bf16(f0.z) | ((unsigned)rne_bf16(f0.w) << 16);
        o.z = (unsigned)rne_bf16(f1.x) | ((unsigned)rne_bf16(f1.y) << 16);
        o.w = (unsigned)rne_bf16(f1.z) | ((unsigned)rne_bf16(f1.w) << 16);
        ((uint4*)xb)[idx] = o;
    }
}

// ---------- leaf level: phase-1-only level_v3 structure (R4 known-good). LDS-staged A
// via global_load_lds (double-buffered), W register ping-pong, 3 gates (i,o,u).
// 64 rows x 4 jtiles/block, 4 waves; grid (256, 8) m-major. ----------
__global__ __launch_bounds__(256) void leaf_v3(
    const unsigned short* __restrict__ xb, const unsigned short* __restrict__ wp,
    const float* __restrict__ bi, const float* __restrict__ bo, const float* __restrict__ bu,
    unsigned short* __restrict__ hw, unsigned short* __restrict__ cw,
    unsigned short* __restrict__ hso,
    int start, int cnt)
{
    __shared__ __align__(16) unsigned short SH[2 * 2048];

    const int tid  = threadIdx.x;
    const int lane = tid & 63;
    const int wv   = tid >> 6;
    const int q    = lane >> 4;
    const int ln   = lane & 15;
    const int wm   = wv & 1;
    const int wj   = wv >> 1;
    const int mb   = blockIdx.x * 64;
    const int jt0  = blockIdx.y * 4 + wj * 2;

    const int srow   = lane >> 2;
    const int gchunk = (lane & 3) ^ ((lane >> 3) & 3);
    const int stage_row = mb + wv * 16 + srow;
    const int rdoff = ((q ^ ((ln >> 1) & 3)) * 8);

    const unsigned short* wpl = wp + (size_t)lane * 8;

    f32x4 zero = {0.f, 0.f, 0.f, 0.f};
    f32x4 acc_i[2][2], acc_o[2][2], acc_u[2][2];
    #pragma unroll
    for (int t = 0; t < 2; ++t)
        #pragma unroll
        for (int ji = 0; ji < 2; ++ji) {
            acc_i[t][ji] = zero; acc_o[t][ji] = zero; acc_u[t][ji] = zero;
        }

    bf16x8 WA[3][2], WB[3][2];

    // gate map: 0 -> Wi(0), 1 -> Wo(2), 2 -> Wu(3)
    auto loadW = [&](bf16x8 (&W)[3][2], int ksabs) {
        #pragma unroll
        for (int g = 0; g < 3; ++g) {
            const int gg = (g == 0) ? 0 : (g + 1);
            #pragma unroll
            for (int ji = 0; ji < 2; ++ji)
                W[g][ji] = *(const bf16x8*)(wpl + ((size_t)((gg * 32 + jt0 + ji) * 32 + ksabs)) * 512);
        }
    };

    loadW(WA, 0);
    {
        const unsigned short* g = xb + (size_t)(start + stage_row) * HHE + gchunk * 8;
        GLOAD_LDS16(g, &SH[0 * 2048 + wv * 512]);
    }
    __syncthreads();

    auto body = [&](int ks, bf16x8 (&WU)[3][2], bf16x8 (&WP)[3][2], int prefks) {
        const int cur = ks & 1;
        if (ks < 15) {
            const unsigned short* g = xb + (size_t)(start + stage_row) * HHE + (ks + 1) * 32 + gchunk * 8;
            GLOAD_LDS16(g, &SH[(cur ^ 1) * 2048 + wv * 512]);
        }
        loadW(WP, prefks);
        bf16x8 a0 = *(const bf16x8*)&SH[cur * 2048 + (wm * 32 + 0 + ln) * 32 + rdoff];
        bf16x8 a1 = *(const bf16x8*)&SH[cur * 2048 + (wm * 32 + 16 + ln) * 32 + rdoff];
        #pragma unroll
        for (int ji = 0; ji < 2; ++ji) {
            acc_i[0][ji] = MFMA16(a0, WU[0][ji], acc_i[0][ji]);
            acc_i[1][ji] = MFMA16(a1, WU[0][ji], acc_i[1][ji]);
            acc_o[0][ji] = MFMA16(a0, WU[1][ji], acc_o[0][ji]);
            acc_o[1][ji] = MFMA16(a1, WU[1][ji], acc_o[1][ji]);
            acc_u[0][ji] = MFMA16(a0, WU[2][ji], acc_u[0][ji]);
            acc_u[1][ji] = MFMA16(a1, WU[2][ji], acc_u[1][ji]);
        }
        __syncthreads();
    };

    for (int kk = 0; kk < 8; ++kk) {
        body(2 * kk,     WA, WB, 2 * kk + 1);
        body(2 * kk + 1, WB, WA, (kk == 7) ? 15 : 2 * kk + 2);   // last: dummy reload
    }

    // epilogue
    #pragma unroll
    for (int ji = 0; ji < 2; ++ji) {
        const int jj = (jt0 + ji) * 16 + ln;
        const float bij = bi[jj], boj = bo[jj], buj = bu[jj];
        #pragma unroll
        for (int t = 0; t < 2; ++t) {
            const int n0 = mb + wm * 32 + t * 16 + q * 4;
            float hv[4];
            #pragma unroll
            for (int r = 0; r < 4; ++r) {
                const int node = n0 + r;
                float gi = sigf(acc_i[t][ji][r] + bij);
                float go = sigf(acc_o[t][ji][r] + boj);
                float gu = tanhf_(acc_u[t][ji][r] + buj);
                float cnv = gi * gu;
                float hnv = go * tanhf_(cnv);
                hv[r] = hnv;
                size_t oix = (size_t)node * HHE + jj;
                hw[oix] = rne_bf16(hnv);
                cw[oix] = rne_bf16(cnv);
            }
            hso[(size_t)(n0 >> 1) * HHE + jj]       = rne_bf16(hv[0] + hv[1]);
            hso[(size_t)((n0 >> 1) + 1) * HHE + jj] = rne_bf16(hv[2] + hv[3]);
        }
    }
}

// ---------- big internal levels (R4 known-good): LDS-staged A, double-buffered,
// ping-pong register-prefetched weights; grid = (cnt/64, 8) m-major ----------
__global__ __launch_bounds__(256) void level_v3(
    const unsigned short* __restrict__ xb, const unsigned short* __restrict__ wp,
    const float* __restrict__ bi, const float* __restrict__ bfv,
    const float* __restrict__ bo, const float* __restrict__ bu,
    const unsigned short* __restrict__ hc, const unsigned short* __restrict__ cc,
    const unsigned short* __restrict__ hs,
    unsigned short* __restrict__ hw, unsigned short* __restrict__ cw,
    unsigned short* __restrict__ hso,
    int start, int cnt)
{
    __shared__ __align__(16) unsigned short SH[2 * 3 * 2048];

    const int tid  = threadIdx.x;
    const int lane = tid & 63;
    const int wv   = tid >> 6;
    const int q    = lane >> 4;
    const int ln   = lane & 15;
    const int wm   = wv & 1;
    const int wj   = wv >> 1;
    const int mb   = blockIdx.x * 64;
    const int jt0  = blockIdx.y * 4 + wj * 2;

    const int srow   = lane >> 2;
    const int gchunk = (lane & 3) ^ ((lane >> 3) & 3);
    const int stage_row = mb + wv * 16 + srow;
    const int rdoff = ((q ^ ((ln >> 1) & 3)) * 8);

    const unsigned short* wpl = wp + (size_t)lane * 8;

    f32x4 zero = {0.f, 0.f, 0.f, 0.f};
    f32x4 acc_i[2][2], acc_f[2][2], acc_o[2][2], acc_u[2][2];
    #pragma unroll
    for (int t = 0; t < 2; ++t)
        #pragma unroll
        for (int ji = 0; ji < 2; ++ji) {
            acc_i[t][ji] = zero; acc_f[t][ji] = zero;
            acc_o[t][ji] = zero; acc_u[t][ji] = zero;
        }

    bf16x8 WA[4][2], WB[4][2];

    auto loadW = [&](bf16x8 (&W)[4][2], int ksabs) {
        #pragma unroll
        for (int g = 0; g < 4; ++g)
            #pragma unroll
            for (int ji = 0; ji < 2; ++ji)
                W[g][ji] = *(const bf16x8*)(wpl + ((size_t)((g * 32 + jt0 + ji) * 32 + ksabs)) * 512);
    };

    // ---------------- phase 1: x ----------------
    loadW(WA, 0);
    {
        const unsigned short* g = xb + (size_t)(start + stage_row) * HHE + gchunk * 8;
        GLOAD_LDS16(g, &SH[(0 * 3 + 0) * 2048 + wv * 512]);
    }
    __syncthreads();

    auto p1_body = [&](int ks, bf16x8 (&WU)[4][2], bf16x8 (&WP)[4][2], int prefks) {
        const int cur = ks & 1;
        if (ks < 15) {
            const unsigned short* g = xb + (size_t)(start + stage_row) * HHE + (ks + 1) * 32 + gchunk * 8;
            GLOAD_LDS16(g, &SH[((cur ^ 1) * 3 + 0) * 2048 + wv * 512]);
        }
        loadW(WP, prefks);
        bf16x8 a0 = *(const bf16x8*)&SH[(cur * 3 + 0) * 2048 + (wm * 32 + 0 + ln) * 32 + rdoff];
        bf16x8 a1 = *(const bf16x8*)&SH[(cur * 3 + 0) * 2048 + (wm * 32 + 16 + ln) * 32 + rdoff];
        #pragma unroll
        for (int ji = 0; ji < 2; ++ji) {
            acc_i[0][ji] = MFMA16(a0, WU[0][ji], acc_i[0][ji]);
            acc_i[1][ji] = MFMA16(a1, WU[0][ji], acc_i[1][ji]);
            acc_f[0][ji] = MFMA16(a0, WU[1][ji], acc_f[0][ji]);
            acc_f[1][ji] = MFMA16(a1, WU[1][ji], acc_f[1][ji]);
            acc_o[0][ji] = MFMA16(a0, WU[2][ji], acc_o[0][ji]);
            acc_o[1][ji] = MFMA16(a1, WU[2][ji], acc_o[1][ji]);
            acc_u[0][ji] = MFMA16(a0, WU[3][ji], acc_u[0][ji]);
            acc_u[1][ji] = MFMA16(a1, WU[3][ji], acc_u[1][ji]);
        }
        __syncthreads();
    };

    for (int kk = 0; kk < 8; ++kk) {
        p1_body(2 * kk,     WA, WB, 2 * kk + 1);
        p1_body(2 * kk + 1, WB, WA, (kk == 7) ? 16 : 2 * kk + 2);
    }

    f32x4 acc_fl[2][2], acc_fr[2][2];
    #pragma unroll
    for (int t = 0; t < 2; ++t)
        #pragma unroll
        for (int ji = 0; ji < 2; ++ji) { acc_fl[t][ji] = acc_f[t][ji]; acc_fr[t][ji] = acc_f[t][ji]; }

    // ---------------- phase 2: hsum / h_l / h_r ----------------
    {
        const unsigned short* gs = hs + (size_t)stage_row * HHE + gchunk * 8;
        const unsigned short* gl = hc + ((size_t)(2 * stage_row)) * HHE + gchunk * 8;
        GLOAD_LDS16(gs, &SH[(0 * 3 + 0) * 2048 + wv * 512]);
        GLOAD_LDS16(gl, &SH[(0 * 3 + 1) * 2048 + wv * 512]);
        GLOAD_LDS16(gl + HHE, &SH[(0 * 3 + 2) * 2048 + wv * 512]);
    }
    __syncthreads();

    auto p2_body = [&](int ks, bf16x8 (&WU)[4][2], bf16x8 (&WP)[4][2], int prefks) {
        const int cur = ks & 1;
        if (ks < 15) {
            const unsigned short* gs = hs + (size_t)stage_row * HHE + (ks + 1) * 32 + gchunk * 8;
            const unsigned short* gl = hc + ((size_t)(2 * stage_row)) * HHE + (ks + 1) * 32 + gchunk * 8;
            GLOAD_LDS16(gs, &SH[((cur ^ 1) * 3 + 0) * 2048 + wv * 512]);
            GLOAD_LDS16(gl, &SH[((cur ^ 1) * 3 + 1) * 2048 + wv * 512]);
            GLOAD_LDS16(gl + HHE, &SH[((cur ^ 1) * 3 + 2) * 2048 + wv * 512]);
        }
        loadW(WP, prefks);
        bf16x8 s0 = *(const bf16x8*)&SH[(cur * 3 + 0) * 2048 + (wm * 32 + 0 + ln) * 32 + rdoff];
        bf16x8 s1 = *(const bf16x8*)&SH[(cur * 3 + 0) * 2048 + (wm * 32 + 16 + ln) * 32 + rdoff];
        bf16x8 l0 = *(const bf16x8*)&SH[(cur * 3 + 1) * 2048 + (wm * 32 + 0 + ln) * 32 + rdoff];
        bf16x8 l1 = *(const bf16x8*)&SH[(cur * 3 + 1) * 2048 + (wm * 32 + 16 + ln) * 32 + rdoff];
        bf16x8 r0 = *(const bf16x8*)&SH[(cur * 3 + 2) * 2048 + (wm * 32 + 0 + ln) * 32 + rdoff];
        bf16x8 r1 = *(const bf16x8*)&SH[(cur * 3 + 2) * 2048 + (wm * 32 + 16 + ln) * 32 + rdoff];
        #pragma unroll
        for (int ji = 0; ji < 2; ++ji) {
            acc_i[0][ji]  = MFMA16(s0, WU[0][ji], acc_i[0][ji]);
            acc_i[1][ji]  = MFMA16(s1, WU[0][ji], acc_i[1][ji]);
            acc_o[0][ji]  = MFMA16(s0, WU[2][ji], acc_o[0][ji]);
            acc_o[1][ji]  = MFMA16(s1, WU[2][ji], acc_o[1][ji]);
            acc_u[0][ji]  = MFMA16(s0, WU[3][ji], acc_u[0][ji]);
            acc_u[1][ji]  = MFMA16(s1, WU[3][ji], acc_u[1][ji]);
            acc_fl[0][ji] = MFMA16(l0, WU[1][ji], acc_fl[0][ji]);
            acc_fl[1][ji] = MFMA16(l1, WU[1][ji], acc_fl[1][ji]);
            acc_fr[0][ji] = MFMA16(r0, WU[1][ji], acc_fr[0][ji]);
            acc_fr[1][ji] = MFMA16(r1, WU[1][ji], acc_fr[1][ji]);
        }
        __syncthreads();
    };

    for (int kk = 0; kk < 8; ++kk) {
        p2_body(2 * kk,     WA, WB, 16 + 2 * kk + 1);
        p2_body(2 * kk + 1, WB, WA, (kk == 7) ? 31 : 16 + 2 * kk + 2);
    }

    // ---------------- epilogue ----------------
    #pragma unroll
    for (int ji = 0; ji < 2; ++ji) {
        const int jj = (jt0 + ji) * 16 + ln;
        const float bij = bi[jj], bfj = bfv[jj], boj = bo[jj], buj = bu[jj];
        #pragma unroll
        for (int t = 0; t < 2; ++t) {
            const int n0 = mb + wm * 32 + t * 16 + q * 4;
            float hv[4];
            #pragma unroll
            for (int r = 0; r < 4; ++r) {
                const int node = n0 + r;
                size_t cix = (size_t)(2 * node) * HHE + jj;
                float cl = bf2f(cc[cix]);
                float cr = bf2f(cc[cix + HHE]);
                float gi  = sigf(acc_i[t][ji][r] + bij);
                float gfl = sigf(acc_fl[t][ji][r] + bfj);
                float gfr = sigf(acc_fr[t][ji][r] + bfj);
                float go  = sigf(acc_o[t][ji][r] + boj);
                float gu  = tanhf_(acc_u[t][ji][r] + buj);
                float cnv = gi * gu + gfl * cl + gfr * cr;
                float hnv = go * tanhf_(cnv);
                hv[r] = hnv;
                size_t oix = (size_t)node * HHE + jj;
                hw[oix] = rne_bf16(hnv);
                cw[oix] = rne_bf16(cnv);
            }
            hso[(size_t)(n0 >> 1) * HHE + jj]       = rne_bf16(hv[0] + hv[1]);
            hso[(size_t)((n0 >> 1) + 1) * HHE + jj] = rne_bf16(hv[2] + hv[3]);
        }
    }
}

// ---------- small levels fallback (5..0): register kernel, 2 m-tiles/wave ----------
__global__ __launch_bounds__(256) void level_sm(
    const unsigned short* __restrict__ xb, const unsigned short* __restrict__ wp,
    const float* __restrict__ bi, const float* __restrict__ bfv,
    const float* __restrict__ bo, const float* __restrict__ bu,
    const unsigned short* __restrict__ hc, const unsigned short* __restrict__ cc,
    const unsigned short* __restrict__ hs,
    unsigned short* __restrict__ hw, unsigned short* __restrict__ cw,
    unsigned short* __restrict__ hso,
    float* __restrict__ f32out,
    int start, int cnt)
{
    const int tid  = threadIdx.x;
    const int lane = tid & 63;
    const int wv   = tid >> 6;
    const int quad = lane >> 4;
    const int ln   = lane & 15;
    const int mb   = blockIdx.x * 32;
    const int jt   = blockIdx.y * 4 + wv;
    const int j    = jt * 16 + ln;

    int row[2];
    #pragma unroll
    for (int t = 0; t < 2; ++t) {
        int r = mb + t * 16 + ln;
        row[t] = (r < cnt) ? r : (cnt - 1);
    }
    const unsigned short* ax[2];
    #pragma unroll
    for (int t = 0; t < 2; ++t) ax[t] = xb + (size_t)(start + row[t]) * HHE + quad * 8;

    const unsigned short* bw[4];
    #pragma unroll
    for (int g = 0; g < 4; ++g) bw[g] = wp + ((size_t)(g * 32 + jt) * 32) * 512 + lane * 8;

    f32x4 zero = {0.f, 0.f, 0.f, 0.f};
    f32x4 acc_i[2], acc_f[2], acc_o[2], acc_u[2];
    #pragma unroll
    for (int t = 0; t < 2; ++t) { acc_i[t] = zero; acc_f[t] = zero; acc_o[t] = zero; acc_u[t] = zero; }

    #pragma unroll 4
    for (int ks = 0; ks < 16; ++ks) {
        bf16x8 a[2];
        #pragma unroll
        for (int t = 0; t < 2; ++t) { a[t] = *(const bf16x8*)ax[t]; ax[t] += 32; }
        bf16x8 b0 = *(const bf16x8*)bw[0]; bw[0] += 512;
        bf16x8 b1 = *(const bf16x8*)bw[1]; bw[1] += 512;
        bf16x8 b2 = *(const bf16x8*)bw[2]; bw[2] += 512;
        bf16x8 b3 = *(const bf16x8*)bw[3]; bw[3] += 512;
        #pragma unroll
        for (int t = 0; t < 2; ++t) {
            acc_i[t] = MFMA16(a[t], b0, acc_i[t]);
            acc_f[t] = MFMA16(a[t], b1, acc_f[t]);
            acc_o[t] = MFMA16(a[t], b2, acc_o[t]);
            acc_u[t] = MFMA16(a[t], b3, acc_u[t]);
        }
    }

    f32x4 acc_fl[2], acc_fr[2];
    #pragma unroll
    for (int t = 0; t < 2; ++t) { acc_fl[t] = acc_f[t]; acc_fr[t] = acc_f[t]; }

    const unsigned short* as[2];
    const unsigned short* al[2];
    const unsigned short* ar[2];
    #pragma unroll
    for (int t = 0; t < 2; ++t) {
        as[t] = hs + (size_t)row[t] * HHE + quad * 8;
        al[t] = hc + (size_t)(2 * row[t]) * HHE + quad * 8;
        ar[t] = al[t] + HHE;
    }

    #pragma unroll 4
    for (int ks = 0; ks < 16; ++ks) {
        bf16x8 b0 = *(const bf16x8*)bw[0]; bw[0] += 512;
        bf16x8 b1 = *(const bf16x8*)bw[1]; bw[1] += 512;
        bf16x8 b2 = *(const bf16x8*)bw[2]; bw[2] += 512;
        bf16x8 b3 = *(const bf16x8*)bw[3]; bw[3] += 512;
        bf16x8 s[2];
        #pragma unroll
        for (int t = 0; t < 2; ++t) { s[t] = *(const bf16x8*)as[t]; as[t] += 32; }
        #pragma unroll
        for (int t = 0; t < 2; ++t) {
            acc_i[t] = MFMA16(s[t], b0, acc_i[t]);
            acc_o[t] = MFMA16(s[t], b2, acc_o[t]);
            acc_u[t] = MFMA16(s[t], b3, acc_u[t]);
        }
        bf16x8 l[2];
        #pragma unroll
        for (int t = 0; t < 2; ++t) { l[t] = *(const bf16x8*)al[t]; al[t] += 32; }
        #pragma unroll
        for (int t = 0; t < 2; ++t) acc_fl[t] = MFMA16(l[t], b1, acc_fl[t]);
        bf16x8 rr[2];
        #pragma unroll
        for (int t = 0; t < 2; ++t) { rr[t] = *(const bf16x8*)ar[t]; ar[t] += 32; }
        #pragma unroll
        for (int t = 0; t < 2; ++t) acc_fr[t] = MFMA16(rr[t], b1, acc_fr[t]);
    }

    const float bij = bi[j], bfj = bfv[j], boj = bo[j], buj = bu[j];
    #pragma unroll
    for (int t = 0; t < 2; ++t) {
        const int n0 = mb + t * 16 + quad * 4;
        float hv[4];
        #pragma unroll
        for (int r = 0; r < 4; ++r) {
            const int node = n0 + r;
            const int ncl  = (node < cnt) ? node : (cnt - 1);
            size_t cix = (size_t)(2 * ncl) * HHE + j;
            float cl = bf2f(cc[cix]);
            float cr = bf2f(cc[cix + HHE]);
            float gi  = sigf(acc_i[t][r] + bij);
            float gfl = sigf(acc_fl[t][r] + bfj);
            float gfr = sigf(acc_fr[t][r] + bfj);
            float go  = sigf(acc_o[t][r] + boj);
            float gu  = tanhf_(acc_u[t][r] + buj);
            float cnv = gi * gu + gfl * cl + gfr * cr;
            float hnv = go * tanhf_(cnv);
            hv[r] = hnv;
            if (node < cnt) {
                size_t oix = (size_t)node * HHE + j;
                hw[oix] = rne_bf16(hnv);
                cw[oix] = rne_bf16(cnv);
                if (f32out) {
                    f32out[(size_t)node * 1024 + j]       = hnv;
                    f32out[(size_t)node * 1024 + 512 + j] = cnv;
                }
            }
        }
        if (n0 + 1 < cnt) hso[(size_t)(n0 >> 1) * HHE + j]       = rne_bf16(hv[0] + hv[1]);
        if (n0 + 3 < cnt) hso[(size_t)((n0 >> 1) + 1) * HHE + j] = rne_bf16(hv[2] + hv[3]);
    }
}

// ---------- fused tail: levels 6..0 in ONE launch, 32 blocks (one jtile each),
// W staged once into 128 KB LDS (fence-immune), spin barrier between levels.
// Theory (r6): the 6-7 tail launches cost ~190 us, dominated by per-launch cold-L2
// W refetch; R1's fused tail failed because fences flushed W from L2 — W-in-LDS
// removes that cost; per-barrier flush is now only the tiny h/c/hsum data. ----------
#define TAIL_NBLK 32

__device__ __forceinline__ void tailbar(int* bar, int target) {
    __syncthreads();
    if (threadIdx.x == 0) {
        __threadfence();  // release: write back dirty h/c/hso so other XCDs see them
        __hip_atomic_fetch_add(bar, 1, __ATOMIC_RELAXED, __HIP_MEMORY_SCOPE_AGENT);
        while (__hip_atomic_load(bar, __ATOMIC_RELAXED, __HIP_MEMORY_SCOPE_AGENT) < target)
            __builtin_amdgcn_s_sleep(2);
        __threadfence();  // acquire: invalidate caches before reading peers' stores
    }
    __syncthreads();
}

__global__ __launch_bounds__(256) void tail_fused(
    const unsigned short* __restrict__ xb, const unsigned short* __restrict__ wp,
    const float* __restrict__ bi, const float* __restrict__ bfv,
    const float* __restrict__ bo, const float* __restrict__ bu,
    unsigned short* __restrict__ hA, unsigned short* __restrict__ cA,
    unsigned short* __restrict__ hB, unsigned short* __restrict__ cB,
    unsigned short* __restrict__ hs1, unsigned short* __restrict__ hs2,
    float* __restrict__ out, int* __restrict__ bar)
{
    __shared__ __align__(16) unsigned short WL[128 * 512];   // 128 KB: frag f = g*32+ks

    const int tid  = threadIdx.x;
    const int lane = tid & 63;
    const int wv   = tid >> 6;
    const int quad = lane >> 4;
    const int ln   = lane & 15;
    const int jt   = blockIdx.x;          // one jtile per block
    const int j    = jt * 16 + ln;
    const int wl   = lane * 8;

    // one-time: stage this jtile's full W (4 gates x 32 ks x 1 KB) into LDS
    #pragma unroll
    for (int i = 0; i < 32; ++i) {
        int f = i * 4 + wv;               // f = g*32 + ks
        const unsigned short* src = wp + ((size_t)(((f >> 5) * 32 + jt) * 32 + (f & 31))) * 512 + lane * 8;
        GLOAD_LDS16(src, &WL[f * 512]);
    }
    __syncthreads();   // vmcnt(0) drain -> W resident in LDS for the whole kernel

    const float bij = bi[j], bfj = bfv[j], boj = bo[j], buj = bu[j];

    int k = 0;
    for (int lvl = 6; lvl >= 0; --lvl) {
        const int cnt = 1 << lvl;
        const int start = cnt - 1;
        const unsigned short *hc, *cc, *hs;
        unsigned short *hw, *cw, *hso;
        if (lvl & 1) { hc = hA; cc = cA; hs = hs1; hw = hB; cw = cB; hso = hs2; }
        else         { hc = hB; cc = cB; hs = hs2; hw = hA; cw = cA; hso = hs1; }

        const int r0  = wv * 16 + ln;
        const int row = (r0 < cnt) ? r0 : (cnt - 1);

        f32x4 zero = {0.f, 0.f, 0.f, 0.f};
        f32x4 acc_i = zero, acc_f = zero, acc_o = zero, acc_u = zero;

        // phase 1: x @ {Wi,Wf,Wo,Wu} (k 0..511)
        const unsigned short* ax = xb + (size_t)(start + row) * HHE + quad * 8;
        #pragma unroll 4
        for (int ks = 0; ks < 16; ++ks) {
            bf16x8 a  = *(const bf16x8*)ax; ax += 32;
            bf16x8 w0 = *(const bf16x8*)&WL[(0 * 32 + ks) * 512 + wl];
            bf16x8 w1 = *(const bf16x8*)&WL[(1 * 32 + ks) * 512 + wl];
            bf16x8 w2 = *(const bf16x8*)&WL[(2 * 32 + ks) * 512 + wl];
            bf16x8 w3 = *(const bf16x8*)&WL[(3 * 32 + ks) * 512 + wl];
            acc_i = MFMA16(a, w0, acc_i);
            acc_f = MFMA16(a, w1, acc_f);
            acc_o = MFMA16(a, w2, acc_o);
            acc_u = MFMA16(a, w3, acc_u);
        }

        // phase 2: hsum @ {Wi,Wo,Wu}, h_l/h_r @ Wf (k 512..1023)
        f32x4 acc_fl = acc_f, acc_fr = acc_f;
        const unsigned short* as = hs + (size_t)row * HHE + quad * 8;
        const unsigned short* al = hc + (size_t)(2 * row) * HHE + quad * 8;
        const unsigned short* ar = al + HHE;
        #pragma unroll 4
        for (int ks = 0; ks < 16; ++ks) {
            bf16x8 w0 = *(const bf16x8*)&WL[(0 * 32 + 16 + ks) * 512 + wl];
            bf16x8 w1 = *(const bf16x8*)&WL[(1 * 32 + 16 + ks) * 512 + wl];
            bf16x8 w2 = *(const bf16x8*)&WL[(2 * 32 + 16 + ks) * 512 + wl];
            bf16x8 w3 = *(const bf16x8*)&WL[(3 * 32 + 16 + ks) * 512 + wl];
            bf16x8 s  = *(const bf16x8*)as; as += 32;
            bf16x8 l  = *(const bf16x8*)al; al += 32;
            bf16x8 rr = *(const bf16x8*)ar; ar += 32;
            acc_i  = MFMA16(s,  w0, acc_i);
            acc_o  = MFMA16(s,  w2, acc_o);
            acc_u  = MFMA16(s,  w3, acc_u);
            acc_fl = MFMA16(l,  w1, acc_fl);
            acc_fr = MFMA16(rr, w1, acc_fr);
        }

        // epilogue (one 16-row m-tile per wave)
        const int n0 = wv * 16 + quad * 4;
        float hv[4];
        #pragma unroll
        for (int r = 0; r < 4; ++r) {
            const int node = n0 + r;
            const int ncl  = (node < cnt) ? node : (cnt - 1);
            size_t cix = (size_t)(2 * ncl) * HHE + j;
            float cl = bf2f(cc[cix]);
            float cr = bf2f(cc[cix + HHE]);
            float gi  = sigf(acc_i[r] + bij);
            float gfl = sigf(acc_fl[r] + bfj);
            float gfr = sigf(acc_fr[r] + bfj);
            float go  = sigf(acc_o[r] + boj);
            float gu  = tanhf_(acc_u[r] + buj);
            float cnv = gi * gu + gfl * cl + gfr * cr;
            float hnv = go * tanhf_(cnv);
            hv[r] = hnv;
            if (node < cnt) {
                size_t oix = (size_t)node * HHE + j;
                hw[oix] = rne_bf16(hnv);
                cw[oix] = rne_bf16(cnv);
                if (lvl == 0) {
                    out[(size_t)node * 1024 + j]       = hnv;
                    out[(size_t)node * 1024 + 512 + j] = cnv;
                }
            }
        }
        if (n0 + 1 < cnt) hso[(size_t)(n0 >> 1) * HHE + j]       = rne_bf16(hv[0] + hv[1]);
        if (n0 + 3 < cnt) hso[(size_t)((n0 >> 1) + 1) * HHE + j] = rne_bf16(hv[2] + hv[3]);

        if (lvl > 0) { ++k; tailbar(bar, TAIL_NBLK * k); }
    }
}

extern "C" void kernel_launch(void* const* d_in, const int* in_sizes, int n_in,
                              void* d_out, int out_size, void* d_ws, size_t ws_size,
                              hipStream_t stream) {
    const float* x  = (const float*)d_in[0];
    const float* Wi = (const float*)d_in[1];
    const float* bi = (const float*)d_in[2];
    const float* Wf = (const float*)d_in[3];
    const float* bf = (const float*)d_in[4];
    const float* Wo = (const float*)d_in[5];
    const float* bo = (const float*)d_in[6];
    const float* Wu = (const float*)d_in[7];
    const float* bu = (const float*)d_in[8];
    float* out = (float*)d_out;

    unsigned short* xb  = (unsigned short*)d_ws;          // x bf16
    unsigned short* wp  = xb  + 16776704;                 // packed W bf16
    unsigned short* hA  = wp  + 2097152;                  // h ping (16384 rows)
    unsigned short* hB  = hA  + 8388608;                  // h pong ( 8192 rows)
    unsigned short* hs1 = hB  + 4194304;                  // hsum ( 8192 rows)
    unsigned short* hs2 = hs1 + 4194304;                  // hsum ( 4096 rows)
    unsigned short* cA  = hs2 + 2097152;                  // c ping
    unsigned short* cB  = cA  + 8388608;                  // c pong

    const size_t BAR_OFF = (size_t)96 << 20;   // layout ends at ~100.66 MB; bar at 96 MiB mark is past it
    const bool fused = ws_size >= BAR_OFF + 64;
    int* bar = (int*)((char*)d_ws + BAR_OFF);

    // fused one-time prep: W pack (1024 blocks) + x conversion (8192 blocks)
    prep<<<9216, 256, 0, stream>>>(x, Wi, Wf, Wo, Wu, xb, wp, fused ? bar : nullptr);

    // leaf: R4 structure; grid (256, 8) m-major
    leaf_v3<<<dim3(256, 8), 256, 0, stream>>>(xb, wp, bi, bo, bu, hA, cA, hs1, 16383, 16384);

    // levels 13..7 (cnt >= 128): R4 dbuf kernel
    for (int lvl = 13; lvl >= 7; --lvl) {
        int cnt   = 1 << lvl;
        int start = cnt - 1;
        const unsigned short *hc, *cc, *hs;
        unsigned short *hw, *cw, *hso;
        if (lvl & 1) { hc = hA; cc = cA; hs = hs1; hw = hB; cw = cB; hso = hs2; }
        else         { hc = hB; cc = cB; hs = hs2; hw = hA; cw = cA; hso = hs1; }
        level_v3<<<dim3(cnt / 64, 8), 256, 0, stream>>>(xb, wp, bi, bf, bo, bu,
                                                        hc, cc, hs, hw, cw, hso, start, cnt);
    }

    if (fused) {
        // levels 6..0 in one persistent launch, W in LDS, 32 co-resident blocks
        tail_fused<<<TAIL_NBLK, 256, 0, stream>>>(xb, wp, bi, bf, bo, bu,
                                                  hA, cA, hB, cB, hs1, hs2, out, bar);
    } else {
        // fallback: per-level launches (R4 path)
        level_v3<<<dim3(1, 8), 256, 0, stream>>>(xb, wp, bi, bf, bo, bu,
                                                 hB, cB, hs2, hA, cA, hs1, 63, 64);
        for (int lvl = 5; lvl >= 0; --lvl) {
            int cnt   = 1 << lvl;
            int start = cnt - 1;
            const unsigned short *hc, *cc, *hs;
            unsigned short *hw, *cw, *hso;
            if (lvl & 1) { hc = hA; cc = cA; hs = hs1; hw = hB; cw = cB; hso = hs2; }
            else         { hc = hB; cc = cB; hs = hs2; hw = hA; cw = cA; hso = hs1; }
            float* f32out = (lvl == 0) ? out : nullptr;
            level_sm<<<dim3((cnt + 31) / 32, 8), 256, 0, stream>>>(xb, wp, bi, bf, bo, bu,
                                                                   hc, cc, hs, hw, cw, hso, f32out,
                                                                   start, cnt);
        }
    }
}

// Round 8
// 511.166 us; speedup vs baseline: 1.2569x; 1.0130x over previous
//
#include <hip/hip_runtime.h>

typedef __attribute__((ext_vector_type(8))) short bf16x8;
typedef __attribute__((ext_vector_type(4))) float f32x4;

#define HHE 512

__device__ __forceinline__ unsigned short rne_bf16(float f) {
    union { float f; unsigned u; } v; v.f = f;
    unsigned r = v.u + 0x7FFFu + ((v.u >> 16) & 1u);
    return (unsigned short)(r >> 16);
}
__device__ __forceinline__ float bf2f(unsigned short s) {
    union { unsigned u; float f; } v; v.u = ((unsigned)s) << 16; return v.f;
}
__device__ __forceinline__ float sigf(float v)   { return 1.0f / (1.0f + __expf(-v)); }
__device__ __forceinline__ float tanhf_(float v) { return 2.0f / (1.0f + __expf(-2.0f * v)) - 1.0f; }

#define MFMA16(a, b, c) __builtin_amdgcn_mfma_f32_16x16x32_bf16(a, b, c, 0, 0, 0)

#define GLOAD_LDS16(g, l) \
    __builtin_amdgcn_global_load_lds((const __attribute__((address_space(1))) void*)(g), \
                                     (__attribute__((address_space(3))) void*)(l), 16, 0, 0)

// coherent (agent-scope, write-through) 2-byte store for cross-XCD exchange in the tail
#define CSTORE_US(p, v) __hip_atomic_store((p), (v), __ATOMIC_RELAXED, __HIP_MEMORY_SCOPE_AGENT)

// ---------- one-time prep, fused into a single dispatch:
//   blocks [0, 1024)    : pack 4 gate weight matrices into MFMA B-fragment order
//                         [gate][jtile(32)][kstep(32)][lane(64)][8]
//   blocks [1024, 9216) : x fp32 -> bf16
__global__ __launch_bounds__(256) void prep(
    const float* __restrict__ x,
    const float* __restrict__ Wi, const float* __restrict__ Wf,
    const float* __restrict__ Wo, const float* __restrict__ Wu,
    unsigned short* __restrict__ xb, unsigned short* __restrict__ wp,
    int* __restrict__ bar)
{
    const int b = blockIdx.x;
    if (b < 1024) {
        int t    = b * 256 + threadIdx.x;
        if (bar && t == 0) *bar = 0;   // reset tail spin-barrier each replay
        int lane = t & 63;
        int fid  = t >> 6;
        int ks   = fid & 31;
        int jt   = (fid >> 5) & 31;
        int g    = fid >> 10;
        const float* W = (g == 0) ? Wi : (g == 1) ? Wf : (g == 2) ? Wo : Wu;
        int row = jt * 16 + (lane & 15);
        int col = ks * 32 + (lane >> 4) * 8;
        const float* src = W + (size_t)row * 1024 + col;
        float4 f0 = *(const float4*)(src);
        float4 f1 = *(const float4*)(src + 4);
        uint4 o;
        o.x = (unsigned)rne_bf16(f0.x) | ((unsigned)rne_bf16(f0.y) << 16);
        o.y = (unsigned)rne_bf16(f0.z) | ((unsigned)rne_bf16(f0.w) << 16);
        o.z = (unsigned)rne_bf16(f1.x) | ((unsigned)rne_bf16(f1.y) << 16);
        o.w = (unsigned)rne_bf16(f1.z) | ((unsigned)rne_bf16(f1.w) << 16);
        ((uint4*)wp)[t] = o;
    } else {
        size_t idx = (size_t)(b - 1024) * 256 + threadIdx.x;
        if (idx >= 2097088) return;
        const float4* p = (const float4*)x + idx * 2;
        float4 f0 = p[0], f1 = p[1];
        uint4 o;
        o.x = (unsigned)rne_bf16(f0.x) | ((unsigned)rne_bf16(f0.y) << 16);
        o.y = (unsigned)rne_bf16(f0.z) | ((unsigned)rne_bf16(f0.w) << 16);
        o.z = (unsigned)rne_bf16(f1.x) | ((unsigned)rne_bf16(f1.y) << 16);
        o.w = (unsigned)rne_bf16(f1.z) | ((unsigned)rne_bf16(f1.w) << 16);
        ((uint4*)xb)[idx] = o;
    }
}

// ---------- leaf level: phase-1-only level_v3 structure (R4 known-good). LDS-staged A
// via global_load_lds (double-buffered), W register ping-pong, 3 gates (i,o,u).
// 64 rows x 4 jtiles/block, 4 waves; grid (256, 8) m-major. ----------
__global__ __launch_bounds__(256) void leaf_v3(
    const unsigned short* __restrict__ xb, const unsigned short* __restrict__ wp,
    const float* __restrict__ bi, const float* __restrict__ bo, const float* __restrict__ bu,
    unsigned short* __restrict__ hw, unsigned short* __restrict__ cw,
    unsigned short* __restrict__ hso,
    int start, int cnt)
{
    __shared__ __align__(16) unsigned short SH[2 * 2048];

    const int tid  = threadIdx.x;
    const int lane = tid & 63;
    const int wv   = tid >> 6;
    const int q    = lane >> 4;
    const int ln   = lane & 15;
    const int wm   = wv & 1;
    const int wj   = wv >> 1;
    const int mb   = blockIdx.x * 64;
    const int jt0  = blockIdx.y * 4 + wj * 2;

    const int srow   = lane >> 2;
    const int gchunk = (lane & 3) ^ ((lane >> 3) & 3);
    const int stage_row = mb + wv * 16 + srow;
    const int rdoff = ((q ^ ((ln >> 1) & 3)) * 8);

    const unsigned short* wpl = wp + (size_t)lane * 8;

    f32x4 zero = {0.f, 0.f, 0.f, 0.f};
    f32x4 acc_i[2][2], acc_o[2][2], acc_u[2][2];
    #pragma unroll
    for (int t = 0; t < 2; ++t)
        #pragma unroll
        for (int ji = 0; ji < 2; ++ji) {
            acc_i[t][ji] = zero; acc_o[t][ji] = zero; acc_u[t][ji] = zero;
        }

    bf16x8 WA[3][2], WB[3][2];

    // gate map: 0 -> Wi(0), 1 -> Wo(2), 2 -> Wu(3)
    auto loadW = [&](bf16x8 (&W)[3][2], int ksabs) {
        #pragma unroll
        for (int g = 0; g < 3; ++g) {
            const int gg = (g == 0) ? 0 : (g + 1);
            #pragma unroll
            for (int ji = 0; ji < 2; ++ji)
                W[g][ji] = *(const bf16x8*)(wpl + ((size_t)((gg * 32 + jt0 + ji) * 32 + ksabs)) * 512);
        }
    };

    loadW(WA, 0);
    {
        const unsigned short* g = xb + (size_t)(start + stage_row) * HHE + gchunk * 8;
        GLOAD_LDS16(g, &SH[0 * 2048 + wv * 512]);
    }
    __syncthreads();

    auto body = [&](int ks, bf16x8 (&WU)[3][2], bf16x8 (&WP)[3][2], int prefks) {
        const int cur = ks & 1;
        if (ks < 15) {
            const unsigned short* g = xb + (size_t)(start + stage_row) * HHE + (ks + 1) * 32 + gchunk * 8;
            GLOAD_LDS16(g, &SH[(cur ^ 1) * 2048 + wv * 512]);
        }
        loadW(WP, prefks);
        bf16x8 a0 = *(const bf16x8*)&SH[cur * 2048 + (wm * 32 + 0 + ln) * 32 + rdoff];
        bf16x8 a1 = *(const bf16x8*)&SH[cur * 2048 + (wm * 32 + 16 + ln) * 32 + rdoff];
        #pragma unroll
        for (int ji = 0; ji < 2; ++ji) {
            acc_i[0][ji] = MFMA16(a0, WU[0][ji], acc_i[0][ji]);
            acc_i[1][ji] = MFMA16(a1, WU[0][ji], acc_i[1][ji]);
            acc_o[0][ji] = MFMA16(a0, WU[1][ji], acc_o[0][ji]);
            acc_o[1][ji] = MFMA16(a1, WU[1][ji], acc_o[1][ji]);
            acc_u[0][ji] = MFMA16(a0, WU[2][ji], acc_u[0][ji]);
            acc_u[1][ji] = MFMA16(a1, WU[2][ji], acc_u[1][ji]);
        }
        __syncthreads();
    };

    for (int kk = 0; kk < 8; ++kk) {
        body(2 * kk,     WA, WB, 2 * kk + 1);
        body(2 * kk + 1, WB, WA, (kk == 7) ? 15 : 2 * kk + 2);   // last: dummy reload
    }

    // epilogue
    #pragma unroll
    for (int ji = 0; ji < 2; ++ji) {
        const int jj = (jt0 + ji) * 16 + ln;
        const float bij = bi[jj], boj = bo[jj], buj = bu[jj];
        #pragma unroll
        for (int t = 0; t < 2; ++t) {
            const int n0 = mb + wm * 32 + t * 16 + q * 4;
            float hv[4];
            #pragma unroll
            for (int r = 0; r < 4; ++r) {
                const int node = n0 + r;
                float gi = sigf(acc_i[t][ji][r] + bij);
                float go = sigf(acc_o[t][ji][r] + boj);
                float gu = tanhf_(acc_u[t][ji][r] + buj);
                float cnv = gi * gu;
                float hnv = go * tanhf_(cnv);
                hv[r] = hnv;
                size_t oix = (size_t)node * HHE + jj;
                hw[oix] = rne_bf16(hnv);
                cw[oix] = rne_bf16(cnv);
            }
            hso[(size_t)(n0 >> 1) * HHE + jj]       = rne_bf16(hv[0] + hv[1]);
            hso[(size_t)((n0 >> 1) + 1) * HHE + jj] = rne_bf16(hv[2] + hv[3]);
        }
    }
}

// ---------- big internal levels (R4 known-good): LDS-staged A, double-buffered,
// ping-pong register-prefetched weights; grid = (cnt/64, 8) m-major ----------
__global__ __launch_bounds__(256) void level_v3(
    const unsigned short* __restrict__ xb, const unsigned short* __restrict__ wp,
    const float* __restrict__ bi, const float* __restrict__ bfv,
    const float* __restrict__ bo, const float* __restrict__ bu,
    const unsigned short* __restrict__ hc, const unsigned short* __restrict__ cc,
    const unsigned short* __restrict__ hs,
    unsigned short* __restrict__ hw, unsigned short* __restrict__ cw,
    unsigned short* __restrict__ hso,
    int start, int cnt)
{
    __shared__ __align__(16) unsigned short SH[2 * 3 * 2048];

    const int tid  = threadIdx.x;
    const int lane = tid & 63;
    const int wv   = tid >> 6;
    const int q    = lane >> 4;
    const int ln   = lane & 15;
    const int wm   = wv & 1;
    const int wj   = wv >> 1;
    const int mb   = blockIdx.x * 64;
    const int jt0  = blockIdx.y * 4 + wj * 2;

    const int srow   = lane >> 2;
    const int gchunk = (lane & 3) ^ ((lane >> 3) & 3);
    const int stage_row = mb + wv * 16 + srow;
    const int rdoff = ((q ^ ((ln >> 1) & 3)) * 8);

    const unsigned short* wpl = wp + (size_t)lane * 8;

    f32x4 zero = {0.f, 0.f, 0.f, 0.f};
    f32x4 acc_i[2][2], acc_f[2][2], acc_o[2][2], acc_u[2][2];
    #pragma unroll
    for (int t = 0; t < 2; ++t)
        #pragma unroll
        for (int ji = 0; ji < 2; ++ji) {
            acc_i[t][ji] = zero; acc_f[t][ji] = zero;
            acc_o[t][ji] = zero; acc_u[t][ji] = zero;
        }

    bf16x8 WA[4][2], WB[4][2];

    auto loadW = [&](bf16x8 (&W)[4][2], int ksabs) {
        #pragma unroll
        for (int g = 0; g < 4; ++g)
            #pragma unroll
            for (int ji = 0; ji < 2; ++ji)
                W[g][ji] = *(const bf16x8*)(wpl + ((size_t)((g * 32 + jt0 + ji) * 32 + ksabs)) * 512);
    };

    // ---------------- phase 1: x ----------------
    loadW(WA, 0);
    {
        const unsigned short* g = xb + (size_t)(start + stage_row) * HHE + gchunk * 8;
        GLOAD_LDS16(g, &SH[(0 * 3 + 0) * 2048 + wv * 512]);
    }
    __syncthreads();

    auto p1_body = [&](int ks, bf16x8 (&WU)[4][2], bf16x8 (&WP)[4][2], int prefks) {
        const int cur = ks & 1;
        if (ks < 15) {
            const unsigned short* g = xb + (size_t)(start + stage_row) * HHE + (ks + 1) * 32 + gchunk * 8;
            GLOAD_LDS16(g, &SH[((cur ^ 1) * 3 + 0) * 2048 + wv * 512]);
        }
        loadW(WP, prefks);
        bf16x8 a0 = *(const bf16x8*)&SH[(cur * 3 + 0) * 2048 + (wm * 32 + 0 + ln) * 32 + rdoff];
        bf16x8 a1 = *(const bf16x8*)&SH[(cur * 3 + 0) * 2048 + (wm * 32 + 16 + ln) * 32 + rdoff];
        #pragma unroll
        for (int ji = 0; ji < 2; ++ji) {
            acc_i[0][ji] = MFMA16(a0, WU[0][ji], acc_i[0][ji]);
            acc_i[1][ji] = MFMA16(a1, WU[0][ji], acc_i[1][ji]);
            acc_f[0][ji] = MFMA16(a0, WU[1][ji], acc_f[0][ji]);
            acc_f[1][ji] = MFMA16(a1, WU[1][ji], acc_f[1][ji]);
            acc_o[0][ji] = MFMA16(a0, WU[2][ji], acc_o[0][ji]);
            acc_o[1][ji] = MFMA16(a1, WU[2][ji], acc_o[1][ji]);
            acc_u[0][ji] = MFMA16(a0, WU[3][ji], acc_u[0][ji]);
            acc_u[1][ji] = MFMA16(a1, WU[3][ji], acc_u[1][ji]);
        }
        __syncthreads();
    };

    for (int kk = 0; kk < 8; ++kk) {
        p1_body(2 * kk,     WA, WB, 2 * kk + 1);
        p1_body(2 * kk + 1, WB, WA, (kk == 7) ? 16 : 2 * kk + 2);
    }

    f32x4 acc_fl[2][2], acc_fr[2][2];
    #pragma unroll
    for (int t = 0; t < 2; ++t)
        #pragma unroll
        for (int ji = 0; ji < 2; ++ji) { acc_fl[t][ji] = acc_f[t][ji]; acc_fr[t][ji] = acc_f[t][ji]; }

    // ---------------- phase 2: hsum / h_l / h_r ----------------
    {
        const unsigned short* gs = hs + (size_t)stage_row * HHE + gchunk * 8;
        const unsigned short* gl = hc + ((size_t)(2 * stage_row)) * HHE + gchunk * 8;
        GLOAD_LDS16(gs, &SH[(0 * 3 + 0) * 2048 + wv * 512]);
        GLOAD_LDS16(gl, &SH[(0 * 3 + 1) * 2048 + wv * 512]);
        GLOAD_LDS16(gl + HHE, &SH[(0 * 3 + 2) * 2048 + wv * 512]);
    }
    __syncthreads();

    auto p2_body = [&](int ks, bf16x8 (&WU)[4][2], bf16x8 (&WP)[4][2], int prefks) {
        const int cur = ks & 1;
        if (ks < 15) {
            const unsigned short* gs = hs + (size_t)stage_row * HHE + (ks + 1) * 32 + gchunk * 8;
            const unsigned short* gl = hc + ((size_t)(2 * stage_row)) * HHE + (ks + 1) * 32 + gchunk * 8;
            GLOAD_LDS16(gs, &SH[((cur ^ 1) * 3 + 0) * 2048 + wv * 512]);
            GLOAD_LDS16(gl, &SH[((cur ^ 1) * 3 + 1) * 2048 + wv * 512]);
            GLOAD_LDS16(gl + HHE, &SH[((cur ^ 1) * 3 + 2) * 2048 + wv * 512]);
        }
        loadW(WP, prefks);
        bf16x8 s0 = *(const bf16x8*)&SH[(cur * 3 + 0) * 2048 + (wm * 32 + 0 + ln) * 32 + rdoff];
        bf16x8 s1 = *(const bf16x8*)&SH[(cur * 3 + 0) * 2048 + (wm * 32 + 16 + ln) * 32 + rdoff];
        bf16x8 l0 = *(const bf16x8*)&SH[(cur * 3 + 1) * 2048 + (wm * 32 + 0 + ln) * 32 + rdoff];
        bf16x8 l1 = *(const bf16x8*)&SH[(cur * 3 + 1) * 2048 + (wm * 32 + 16 + ln) * 32 + rdoff];
        bf16x8 r0 = *(const bf16x8*)&SH[(cur * 3 + 2) * 2048 + (wm * 32 + 0 + ln) * 32 + rdoff];
        bf16x8 r1 = *(const bf16x8*)&SH[(cur * 3 + 2) * 2048 + (wm * 32 + 16 + ln) * 32 + rdoff];
        #pragma unroll
        for (int ji = 0; ji < 2; ++ji) {
            acc_i[0][ji]  = MFMA16(s0, WU[0][ji], acc_i[0][ji]);
            acc_i[1][ji]  = MFMA16(s1, WU[0][ji], acc_i[1][ji]);
            acc_o[0][ji]  = MFMA16(s0, WU[2][ji], acc_o[0][ji]);
            acc_o[1][ji]  = MFMA16(s1, WU[2][ji], acc_o[1][ji]);
            acc_u[0][ji]  = MFMA16(s0, WU[3][ji], acc_u[0][ji]);
            acc_u[1][ji]  = MFMA16(s1, WU[3][ji], acc_u[1][ji]);
            acc_fl[0][ji] = MFMA16(l0, WU[1][ji], acc_fl[0][ji]);
            acc_fl[1][ji] = MFMA16(l1, WU[1][ji], acc_fl[1][ji]);
            acc_fr[0][ji] = MFMA16(r0, WU[1][ji], acc_fr[0][ji]);
            acc_fr[1][ji] = MFMA16(r1, WU[1][ji], acc_fr[1][ji]);
        }
        __syncthreads();
    };

    for (int kk = 0; kk < 8; ++kk) {
        p2_body(2 * kk,     WA, WB, 16 + 2 * kk + 1);
        p2_body(2 * kk + 1, WB, WA, (kk == 7) ? 31 : 16 + 2 * kk + 2);
    }

    // ---------------- epilogue ----------------
    #pragma unroll
    for (int ji = 0; ji < 2; ++ji) {
        const int jj = (jt0 + ji) * 16 + ln;
        const float bij = bi[jj], bfj = bfv[jj], boj = bo[jj], buj = bu[jj];
        #pragma unroll
        for (int t = 0; t < 2; ++t) {
            const int n0 = mb + wm * 32 + t * 16 + q * 4;
            float hv[4];
            #pragma unroll
            for (int r = 0; r < 4; ++r) {
                const int node = n0 + r;
                size_t cix = (size_t)(2 * node) * HHE + jj;
                float cl = bf2f(cc[cix]);
                float cr = bf2f(cc[cix + HHE]);
                float gi  = sigf(acc_i[t][ji][r] + bij);
                float gfl = sigf(acc_fl[t][ji][r] + bfj);
                float gfr = sigf(acc_fr[t][ji][r] + bfj);
                float go  = sigf(acc_o[t][ji][r] + boj);
                float gu  = tanhf_(acc_u[t][ji][r] + buj);
                float cnv = gi * gu + gfl * cl + gfr * cr;
                float hnv = go * tanhf_(cnv);
                hv[r] = hnv;
                size_t oix = (size_t)node * HHE + jj;
                hw[oix] = rne_bf16(hnv);
                cw[oix] = rne_bf16(cnv);
            }
            hso[(size_t)(n0 >> 1) * HHE + jj]       = rne_bf16(hv[0] + hv[1]);
            hso[(size_t)((n0 >> 1) + 1) * HHE + jj] = rne_bf16(hv[2] + hv[3]);
        }
    }
}

// ---------- small levels fallback (5..0): register kernel, 2 m-tiles/wave ----------
__global__ __launch_bounds__(256) void level_sm(
    const unsigned short* __restrict__ xb, const unsigned short* __restrict__ wp,
    const float* __restrict__ bi, const float* __restrict__ bfv,
    const float* __restrict__ bo, const float* __restrict__ bu,
    const unsigned short* __restrict__ hc, const unsigned short* __restrict__ cc,
    const unsigned short* __restrict__ hs,
    unsigned short* __restrict__ hw, unsigned short* __restrict__ cw,
    unsigned short* __restrict__ hso,
    float* __restrict__ f32out,
    int start, int cnt)
{
    const int tid  = threadIdx.x;
    const int lane = tid & 63;
    const int wv   = tid >> 6;
    const int quad = lane >> 4;
    const int ln   = lane & 15;
    const int mb   = blockIdx.x * 32;
    const int jt   = blockIdx.y * 4 + wv;
    const int j    = jt * 16 + ln;

    int row[2];
    #pragma unroll
    for (int t = 0; t < 2; ++t) {
        int r = mb + t * 16 + ln;
        row[t] = (r < cnt) ? r : (cnt - 1);
    }
    const unsigned short* ax[2];
    #pragma unroll
    for (int t = 0; t < 2; ++t) ax[t] = xb + (size_t)(start + row[t]) * HHE + quad * 8;

    const unsigned short* bw[4];
    #pragma unroll
    for (int g = 0; g < 4; ++g) bw[g] = wp + ((size_t)(g * 32 + jt) * 32) * 512 + lane * 8;

    f32x4 zero = {0.f, 0.f, 0.f, 0.f};
    f32x4 acc_i[2], acc_f[2], acc_o[2], acc_u[2];
    #pragma unroll
    for (int t = 0; t < 2; ++t) { acc_i[t] = zero; acc_f[t] = zero; acc_o[t] = zero; acc_u[t] = zero; }

    #pragma unroll 4
    for (int ks = 0; ks < 16; ++ks) {
        bf16x8 a[2];
        #pragma unroll
        for (int t = 0; t < 2; ++t) { a[t] = *(const bf16x8*)ax[t]; ax[t] += 32; }
        bf16x8 b0 = *(const bf16x8*)bw[0]; bw[0] += 512;
        bf16x8 b1 = *(const bf16x8*)bw[1]; bw[1] += 512;
        bf16x8 b2 = *(const bf16x8*)bw[2]; bw[2] += 512;
        bf16x8 b3 = *(const bf16x8*)bw[3]; bw[3] += 512;
        #pragma unroll
        for (int t = 0; t < 2; ++t) {
            acc_i[t] = MFMA16(a[t], b0, acc_i[t]);
            acc_f[t] = MFMA16(a[t], b1, acc_f[t]);
            acc_o[t] = MFMA16(a[t], b2, acc_o[t]);
            acc_u[t] = MFMA16(a[t], b3, acc_u[t]);
        }
    }

    f32x4 acc_fl[2], acc_fr[2];
    #pragma unroll
    for (int t = 0; t < 2; ++t) { acc_fl[t] = acc_f[t]; acc_fr[t] = acc_f[t]; }

    const unsigned short* as[2];
    const unsigned short* al[2];
    const unsigned short* ar[2];
    #pragma unroll
    for (int t = 0; t < 2; ++t) {
        as[t] = hs + (size_t)row[t] * HHE + quad * 8;
        al[t] = hc + (size_t)(2 * row[t]) * HHE + quad * 8;
        ar[t] = al[t] + HHE;
    }

    #pragma unroll 4
    for (int ks = 0; ks < 16; ++ks) {
        bf16x8 b0 = *(const bf16x8*)bw[0]; bw[0] += 512;
        bf16x8 b1 = *(const bf16x8*)bw[1]; bw[1] += 512;
        bf16x8 b2 = *(const bf16x8*)bw[2]; bw[2] += 512;
        bf16x8 b3 = *(const bf16x8*)bw[3]; bw[3] += 512;
        bf16x8 s[2];
        #pragma unroll
        for (int t = 0; t < 2; ++t) { s[t] = *(const bf16x8*)as[t]; as[t] += 32; }
        #pragma unroll
        for (int t = 0; t < 2; ++t) {
            acc_i[t] = MFMA16(s[t], b0, acc_i[t]);
            acc_o[t] = MFMA16(s[t], b2, acc_o[t]);
            acc_u[t] = MFMA16(s[t], b3, acc_u[t]);
        }
        bf16x8 l[2];
        #pragma unroll
        for (int t = 0; t < 2; ++t) { l[t] = *(const bf16x8*)al[t]; al[t] += 32; }
        #pragma unroll
        for (int t = 0; t < 2; ++t) acc_fl[t] = MFMA16(l[t], b1, acc_fl[t]);
        bf16x8 rr[2];
        #pragma unroll
        for (int t = 0; t < 2; ++t) { rr[t] = *(const bf16x8*)ar[t]; ar[t] += 32; }
        #pragma unroll
        for (int t = 0; t < 2; ++t) acc_fr[t] = MFMA16(rr[t], b1, acc_fr[t]);
    }

    const float bij = bi[j], bfj = bfv[j], boj = bo[j], buj = bu[j];
    #pragma unroll
    for (int t = 0; t < 2; ++t) {
        const int n0 = mb + t * 16 + quad * 4;
        float hv[4];
        #pragma unroll
        for (int r = 0; r < 4; ++r) {
            const int node = n0 + r;
            const int ncl  = (node < cnt) ? node : (cnt - 1);
            size_t cix = (size_t)(2 * ncl) * HHE + j;
            float cl = bf2f(cc[cix]);
            float cr = bf2f(cc[cix + HHE]);
            float gi  = sigf(acc_i[t][r] + bij);
            float gfl = sigf(acc_fl[t][r] + bfj);
            float gfr = sigf(acc_fr[t][r] + bfj);
            float go  = sigf(acc_o[t][r] + boj);
            float gu  = tanhf_(acc_u[t][r] + buj);
            float cnv = gi * gu + gfl * cl + gfr * cr;
            float hnv = go * tanhf_(cnv);
            hv[r] = hnv;
            if (node < cnt) {
                size_t oix = (size_t)node * HHE + j;
                hw[oix] = rne_bf16(hnv);
                cw[oix] = rne_bf16(cnv);
                if (f32out) {
                    f32out[(size_t)node * 1024 + j]       = hnv;
                    f32out[(size_t)node * 1024 + 512 + j] = cnv;
                }
            }
        }
        if (n0 + 1 < cnt) hso[(size_t)(n0 >> 1) * HHE + j]       = rne_bf16(hv[0] + hv[1]);
        if (n0 + 3 < cnt) hso[(size_t)((n0 >> 1) + 1) * HHE + j] = rne_bf16(hv[2] + hv[3]);
    }
}

// ---------- fused tail: levels 6..0 in ONE launch, 32 blocks (one jtile each),
// W staged once into 128 KB LDS. R8 barrier: exchanged h/c/hso written with
// agent-scope write-through stores -> NO release writeback fence needed
// (__syncthreads already drains vmcnt); acquire is invalidate-only; level
// lvl-1's phase-1 (x-only) overlaps the spin wait. ----------
#define TAIL_NBLK 32

__global__ __launch_bounds__(256) void tail_fused(
    const unsigned short* __restrict__ xb, const unsigned short* __restrict__ wp,
    const float* __restrict__ bi, const float* __restrict__ bfv,
    const float* __restrict__ bo, const float* __restrict__ bu,
    unsigned short* __restrict__ hA, unsigned short* __restrict__ cA,
    unsigned short* __restrict__ hB, unsigned short* __restrict__ cB,
    unsigned short* __restrict__ hs1, unsigned short* __restrict__ hs2,
    float* __restrict__ out, int* __restrict__ bar)
{
    __shared__ __align__(16) unsigned short WL[128 * 512];   // 128 KB: frag f = g*32+ks

    const int tid  = threadIdx.x;
    const int lane = tid & 63;
    const int wv   = tid >> 6;
    const int quad = lane >> 4;
    const int ln   = lane & 15;
    const int jt   = blockIdx.x;          // one jtile per block
    const int j    = jt * 16 + ln;
    const int wl   = lane * 8;

    // one-time: stage this jtile's full W (4 gates x 32 ks x 1 KB) into LDS
    #pragma unroll
    for (int i = 0; i < 32; ++i) {
        int f = i * 4 + wv;               // f = g*32 + ks
        const unsigned short* src = wp + ((size_t)(((f >> 5) * 32 + jt) * 32 + (f & 31))) * 512 + lane * 8;
        GLOAD_LDS16(src, &WL[f * 512]);
    }
    __syncthreads();   // vmcnt(0) drain -> W resident in LDS for the whole kernel

    const float bij = bi[j], bfj = bfv[j], boj = bo[j], buj = bu[j];
    f32x4 zero = {0.f, 0.f, 0.f, 0.f};

    // phase 1 of a level: x @ {Wi,Wf,Wo,Wu} — depends only on x and LDS W
    auto phase1 = [&](int lvl, f32x4& pi, f32x4& pf, f32x4& po, f32x4& pu) {
        const int cnt = 1 << lvl;
        const int start = cnt - 1;
        const int r0  = wv * 16 + ln;
        const int row = (r0 < cnt) ? r0 : (cnt - 1);
        pi = zero; pf = zero; po = zero; pu = zero;
        const unsigned short* ax = xb + (size_t)(start + row) * HHE + quad * 8;
        #pragma unroll 4
        for (int ks = 0; ks < 16; ++ks) {
            bf16x8 a  = *(const bf16x8*)ax; ax += 32;
            bf16x8 w0 = *(const bf16x8*)&WL[(0 * 32 + ks) * 512 + wl];
            bf16x8 w1 = *(const bf16x8*)&WL[(1 * 32 + ks) * 512 + wl];
            bf16x8 w2 = *(const bf16x8*)&WL[(2 * 32 + ks) * 512 + wl];
            bf16x8 w3 = *(const bf16x8*)&WL[(3 * 32 + ks) * 512 + wl];
            pi = MFMA16(a, w0, pi);
            pf = MFMA16(a, w1, pf);
            po = MFMA16(a, w2, po);
            pu = MFMA16(a, w3, pu);
        }
    };

    f32x4 p_i, p_f, p_o, p_u;
    phase1(6, p_i, p_f, p_o, p_u);

    int k = 0;
    for (int lvl = 6; lvl >= 0; --lvl) {
        const int cnt = 1 << lvl;
        const unsigned short *hc, *cc, *hs;
        unsigned short *hw, *cw, *hso;
        if (lvl & 1) { hc = hA; cc = cA; hs = hs1; hw = hB; cw = cB; hso = hs2; }
        else         { hc = hB; cc = cB; hs = hs2; hw = hA; cw = cA; hso = hs1; }

        const int r0  = wv * 16 + ln;
        const int row = (r0 < cnt) ? r0 : (cnt - 1);

        f32x4 acc_i = p_i, acc_o = p_o, acc_u = p_u;
        f32x4 acc_fl = p_f, acc_fr = p_f;

        // phase 2: hsum @ {Wi,Wo,Wu}, h_l/h_r @ Wf (k 512..1023)
        const unsigned short* as = hs + (size_t)row * HHE + quad * 8;
        const unsigned short* al = hc + (size_t)(2 * row) * HHE + quad * 8;
        const unsigned short* ar = al + HHE;
        #pragma unroll 4
        for (int ks = 0; ks < 16; ++ks) {
            bf16x8 w0 = *(const bf16x8*)&WL[(0 * 32 + 16 + ks) * 512 + wl];
            bf16x8 w1 = *(const bf16x8*)&WL[(1 * 32 + 16 + ks) * 512 + wl];
            bf16x8 w2 = *(const bf16x8*)&WL[(2 * 32 + 16 + ks) * 512 + wl];
            bf16x8 w3 = *(const bf16x8*)&WL[(3 * 32 + 16 + ks) * 512 + wl];
            bf16x8 s  = *(const bf16x8*)as; as += 32;
            bf16x8 l  = *(const bf16x8*)al; al += 32;
            bf16x8 rr = *(const bf16x8*)ar; ar += 32;
            acc_i  = MFMA16(s,  w0, acc_i);
            acc_o  = MFMA16(s,  w2, acc_o);
            acc_u  = MFMA16(s,  w3, acc_u);
            acc_fl = MFMA16(l,  w1, acc_fl);
            acc_fr = MFMA16(rr, w1, acc_fr);
        }

        // epilogue: exchanged h/c/hso written with agent-scope (write-through) stores
        const int n0 = wv * 16 + quad * 4;
        float hv[4];
        #pragma unroll
        for (int r = 0; r < 4; ++r) {
            const int node = n0 + r;
            const int ncl  = (node < cnt) ? node : (cnt - 1);
            size_t cix = (size_t)(2 * ncl) * HHE + j;
            float cl = bf2f(cc[cix]);
            float cr = bf2f(cc[cix + HHE]);
            float gi  = sigf(acc_i[r] + bij);
            float gfl = sigf(acc_fl[r] + bfj);
            float gfr = sigf(acc_fr[r] + bfj);
            float go  = sigf(acc_o[r] + boj);
            float gu  = tanhf_(acc_u[r] + buj);
            float cnv = gi * gu + gfl * cl + gfr * cr;
            float hnv = go * tanhf_(cnv);
            hv[r] = hnv;
            if (node < cnt) {
                size_t oix = (size_t)node * HHE + j;
                CSTORE_US(&hw[oix], rne_bf16(hnv));
                CSTORE_US(&cw[oix], rne_bf16(cnv));
                if (lvl == 0) {
                    out[(size_t)node * 1024 + j]       = hnv;
                    out[(size_t)node * 1024 + 512 + j] = cnv;
                }
            }
        }
        if (n0 + 1 < cnt) CSTORE_US(&hso[(size_t)(n0 >> 1) * HHE + j],       rne_bf16(hv[0] + hv[1]));
        if (n0 + 3 < cnt) CSTORE_US(&hso[(size_t)((n0 >> 1) + 1) * HHE + j], rne_bf16(hv[2] + hv[3]));

        if (lvl > 0) {
            ++k;
            __syncthreads();   // compiler drains vmcnt(0) here -> coherent stores visible
            if (tid == 0)
                __hip_atomic_fetch_add(bar, 1, __ATOMIC_RELAXED, __HIP_MEMORY_SCOPE_AGENT);
            // overlap: next level's x-phase while peers arrive (x and LDS W only)
            phase1(lvl - 1, p_i, p_f, p_o, p_u);
            if (tid == 0) {
                while (__hip_atomic_load(bar, __ATOMIC_RELAXED, __HIP_MEMORY_SCOPE_AGENT) < TAIL_NBLK * k)
                    __builtin_amdgcn_s_sleep(2);
            }
            __syncthreads();
            __builtin_amdgcn_fence(__ATOMIC_ACQUIRE, "agent");  // invalidate-only (no wb)
        }
    }
}

extern "C" void kernel_launch(void* const* d_in, const int* in_sizes, int n_in,
                              void* d_out, int out_size, void* d_ws, size_t ws_size,
                              hipStream_t stream) {
    const float* x  = (const float*)d_in[0];
    const float* Wi = (const float*)d_in[1];
    const float* bi = (const float*)d_in[2];
    const float* Wf = (const float*)d_in[3];
    const float* bf = (const float*)d_in[4];
    const float* Wo = (const float*)d_in[5];
    const float* bo = (const float*)d_in[6];
    const float* Wu = (const float*)d_in[7];
    const float* bu = (const float*)d_in[8];
    float* out = (float*)d_out;

    unsigned short* xb  = (unsigned short*)d_ws;          // x bf16
    unsigned short* wp  = xb  + 16776704;                 // packed W bf16
    unsigned short* hA  = wp  + 2097152;                  // h ping (16384 rows)
    unsigned short* hB  = hA  + 8388608;                  // h pong ( 8192 rows)
    unsigned short* hs1 = hB  + 4194304;                  // hsum ( 8192 rows)
    unsigned short* hs2 = hs1 + 4194304;                  // hsum ( 4096 rows)
    unsigned short* cA  = hs2 + 2097152;                  // c ping
    unsigned short* cB  = cA  + 8388608;                  // c pong

    const size_t BAR_OFF = (size_t)96 << 20;   // layout ends at ~100.66 MB; bar at 96 MiB is past it
    const bool fused = ws_size >= BAR_OFF + 64;
    int* bar = (int*)((char*)d_ws + BAR_OFF);

    // fused one-time prep: W pack (1024 blocks) + x conversion (8192 blocks)
    prep<<<9216, 256, 0, stream>>>(x, Wi, Wf, Wo, Wu, xb, wp, fused ? bar : nullptr);

    // leaf: R4 structure; grid (256, 8) m-major
    leaf_v3<<<dim3(256, 8), 256, 0, stream>>>(xb, wp, bi, bo, bu, hA, cA, hs1, 16383, 16384);

    // levels 13..7 (cnt >= 128): R4 dbuf kernel
    for (int lvl = 13; lvl >= 7; --lvl) {
        int cnt   = 1 << lvl;
        int start = cnt - 1;
        const unsigned short *hc, *cc, *hs;
        unsigned short *hw, *cw, *hso;
        if (lvl & 1) { hc = hA; cc = cA; hs = hs1; hw = hB; cw = cB; hso = hs2; }
        else         { hc = hB; cc = cB; hs = hs2; hw = hA; cw = cA; hso = hs1; }
        level_v3<<<dim3(cnt / 64, 8), 256, 0, stream>>>(xb, wp, bi, bf, bo, bu,
                                                        hc, cc, hs, hw, cw, hso, start, cnt);
    }

    if (fused) {
        // levels 6..0 in one persistent launch, W in LDS, 32 co-resident blocks
        tail_fused<<<TAIL_NBLK, 256, 0, stream>>>(xb, wp, bi, bf, bo, bu,
                                                  hA, cA, hB, cB, hs1, hs2, out, bar);
    } else {
        // fallback: per-level launches (R4 path)
        level_v3<<<dim3(1, 8), 256, 0, stream>>>(xb, wp, bi, bf, bo, bu,
                                                 hB, cB, hs2, hA, cA, hs1, 63, 64);
        for (int lvl = 5; lvl >= 0; --lvl) {
            int cnt   = 1 << lvl;
            int start = cnt - 1;
            const unsigned short *hc, *cc, *hs;
            unsigned short *hw, *cw, *hso;
            if (lvl & 1) { hc = hA; cc = cA; hs = hs1; hw = hB; cw = cB; hso = hs2; }
            else         { hc = hB; cc = cB; hs = hs2; hw = hA; cw = cA; hso = hs1; }
            float* f32out = (lvl == 0) ? out : nullptr;
            level_sm<<<dim3((cnt + 31) / 32, 8), 256, 0, stream>>>(xb, wp, bi, bf, bo, bu,
                                                                   hc, cc, hs, hw, cw, hso, f32out,
                                                                   start, cnt);
        }
    }
}

// Round 9
// 509.184 us; speedup vs baseline: 1.2618x; 1.0039x over previous
//
#include <hip/hip_runtime.h>

typedef __attribute__((ext_vector_type(8))) short bf16x8;
typedef __attribute__((ext_vector_type(4))) float f32x4;

#define HHE 512

__device__ __forceinline__ unsigned short rne_bf16(float f) {
    union { float f; unsigned u; } v; v.f = f;
    unsigned r = v.u + 0x7FFFu + ((v.u >> 16) & 1u);
    return (unsigned short)(r >> 16);
}
__device__ __forceinline__ float bf2f(unsigned short s) {
    union { unsigned u; float f; } v; v.u = ((unsigned)s) << 16; return v.f;
}
__device__ __forceinline__ float sigf(float v)   { return 1.0f / (1.0f + __expf(-v)); }
__device__ __forceinline__ float tanhf_(float v) { return 2.0f / (1.0f + __expf(-2.0f * v)) - 1.0f; }

#define MFMA16(a, b, c) __builtin_amdgcn_mfma_f32_16x16x32_bf16(a, b, c, 0, 0, 0)

#define GLOAD_LDS16(g, l) \
    __builtin_amdgcn_global_load_lds((const __attribute__((address_space(1))) void*)(g), \
                                     (__attribute__((address_space(3))) void*)(l), 16, 0, 0)

// coherent (agent-scope, write-through) 2-byte store for cross-XCD exchange in the tail
#define CSTORE_US(p, v) __hip_atomic_store((p), (v), __ATOMIC_RELAXED, __HIP_MEMORY_SCOPE_AGENT)

// ---------- one-time prep, fused into a single dispatch:
//   blocks [0, 1024)    : pack 4 gate weight matrices into MFMA B-fragment order
//                         [gate][jtile(32)][kstep(32)][lane(64)][8]
//   blocks [1024, 9216) : x fp32 -> bf16
__global__ __launch_bounds__(256) void prep(
    const float* __restrict__ x,
    const float* __restrict__ Wi, const float* __restrict__ Wf,
    const float* __restrict__ Wo, const float* __restrict__ Wu,
    unsigned short* __restrict__ xb, unsigned short* __restrict__ wp,
    int* __restrict__ bar)
{
    const int b = blockIdx.x;
    if (b < 1024) {
        int t    = b * 256 + threadIdx.x;
        if (bar && t < 1024) bar[t] = 0;   // zero the 4 KB slot-array each replay
        int lane = t & 63;
        int fid  = t >> 6;
        int ks   = fid & 31;
        int jt   = (fid >> 5) & 31;
        int g    = fid >> 10;
        const float* W = (g == 0) ? Wi : (g == 1) ? Wf : (g == 2) ? Wo : Wu;
        int row = jt * 16 + (lane & 15);
        int col = ks * 32 + (lane >> 4) * 8;
        const float* src = W + (size_t)row * 1024 + col;
        float4 f0 = *(const float4*)(src);
        float4 f1 = *(const float4*)(src + 4);
        uint4 o;
        o.x = (unsigned)rne_bf16(f0.x) | ((unsigned)rne_bf16(f0.y) << 16);
        o.y = (unsigned)rne_bf16(f0.z) | ((unsigned)rne_bf16(f0.w) << 16);
        o.z = (unsigned)rne_bf16(f1.x) | ((unsigned)rne_bf16(f1.y) << 16);
        o.w = (unsigned)rne_bf16(f1.z) | ((unsigned)rne_bf16(f1.w) << 16);
        ((uint4*)wp)[t] = o;
    } else {
        size_t idx = (size_t)(b - 1024) * 256 + threadIdx.x;
        if (idx >= 2097088) return;
        const float4* p = (const float4*)x + idx * 2;
        float4 f0 = p[0], f1 = p[1];
        uint4 o;
        o.x = (unsigned)rne_bf16(f0.x) | ((unsigned)rne_bf16(f0.y) << 16);
        o.y = (unsigned)rne_bf16(f0.z) | ((unsigned)rne_bf16(f0.w) << 16);
        o.z = (unsigned)rne_bf16(f1.x) | ((unsigned)rne_bf16(f1.y) << 16);
        o.w = (unsigned)rne_bf16(f1.z) | ((unsigned)rne_bf16(f1.w) << 16);
        ((uint4*)xb)[idx] = o;
    }
}

// ---------- leaf level: phase-1-only level_v3 structure (R4 known-good). LDS-staged A
// via global_load_lds (double-buffered), W register ping-pong, 3 gates (i,o,u).
// 64 rows x 4 jtiles/block, 4 waves; grid (256, 8) m-major. ----------
__global__ __launch_bounds__(256) void leaf_v3(
    const unsigned short* __restrict__ xb, const unsigned short* __restrict__ wp,
    const float* __restrict__ bi, const float* __restrict__ bo, const float* __restrict__ bu,
    unsigned short* __restrict__ hw, unsigned short* __restrict__ cw,
    unsigned short* __restrict__ hso,
    int start, int cnt)
{
    __shared__ __align__(16) unsigned short SH[2 * 2048];

    const int tid  = threadIdx.x;
    const int lane = tid & 63;
    const int wv   = tid >> 6;
    const int q    = lane >> 4;
    const int ln   = lane & 15;
    const int wm   = wv & 1;
    const int wj   = wv >> 1;
    const int mb   = blockIdx.x * 64;
    const int jt0  = blockIdx.y * 4 + wj * 2;

    const int srow   = lane >> 2;
    const int gchunk = (lane & 3) ^ ((lane >> 3) & 3);
    const int stage_row = mb + wv * 16 + srow;
    const int rdoff = ((q ^ ((ln >> 1) & 3)) * 8);

    const unsigned short* wpl = wp + (size_t)lane * 8;

    f32x4 zero = {0.f, 0.f, 0.f, 0.f};
    f32x4 acc_i[2][2], acc_o[2][2], acc_u[2][2];
    #pragma unroll
    for (int t = 0; t < 2; ++t)
        #pragma unroll
        for (int ji = 0; ji < 2; ++ji) {
            acc_i[t][ji] = zero; acc_o[t][ji] = zero; acc_u[t][ji] = zero;
        }

    bf16x8 WA[3][2], WB[3][2];

    // gate map: 0 -> Wi(0), 1 -> Wo(2), 2 -> Wu(3)
    auto loadW = [&](bf16x8 (&W)[3][2], int ksabs) {
        #pragma unroll
        for (int g = 0; g < 3; ++g) {
            const int gg = (g == 0) ? 0 : (g + 1);
            #pragma unroll
            for (int ji = 0; ji < 2; ++ji)
                W[g][ji] = *(const bf16x8*)(wpl + ((size_t)((gg * 32 + jt0 + ji) * 32 + ksabs)) * 512);
        }
    };

    loadW(WA, 0);
    {
        const unsigned short* g = xb + (size_t)(start + stage_row) * HHE + gchunk * 8;
        GLOAD_LDS16(g, &SH[0 * 2048 + wv * 512]);
    }
    __syncthreads();

    auto body = [&](int ks, bf16x8 (&WU)[3][2], bf16x8 (&WP)[3][2], int prefks) {
        const int cur = ks & 1;
        if (ks < 15) {
            const unsigned short* g = xb + (size_t)(start + stage_row) * HHE + (ks + 1) * 32 + gchunk * 8;
            GLOAD_LDS16(g, &SH[(cur ^ 1) * 2048 + wv * 512]);
        }
        loadW(WP, prefks);
        bf16x8 a0 = *(const bf16x8*)&SH[cur * 2048 + (wm * 32 + 0 + ln) * 32 + rdoff];
        bf16x8 a1 = *(const bf16x8*)&SH[cur * 2048 + (wm * 32 + 16 + ln) * 32 + rdoff];
        #pragma unroll
        for (int ji = 0; ji < 2; ++ji) {
            acc_i[0][ji] = MFMA16(a0, WU[0][ji], acc_i[0][ji]);
            acc_i[1][ji] = MFMA16(a1, WU[0][ji], acc_i[1][ji]);
            acc_o[0][ji] = MFMA16(a0, WU[1][ji], acc_o[0][ji]);
            acc_o[1][ji] = MFMA16(a1, WU[1][ji], acc_o[1][ji]);
            acc_u[0][ji] = MFMA16(a0, WU[2][ji], acc_u[0][ji]);
            acc_u[1][ji] = MFMA16(a1, WU[2][ji], acc_u[1][ji]);
        }
        __syncthreads();
    };

    for (int kk = 0; kk < 8; ++kk) {
        body(2 * kk,     WA, WB, 2 * kk + 1);
        body(2 * kk + 1, WB, WA, (kk == 7) ? 15 : 2 * kk + 2);   // last: dummy reload
    }

    // epilogue
    #pragma unroll
    for (int ji = 0; ji < 2; ++ji) {
        const int jj = (jt0 + ji) * 16 + ln;
        const float bij = bi[jj], boj = bo[jj], buj = bu[jj];
        #pragma unroll
        for (int t = 0; t < 2; ++t) {
            const int n0 = mb + wm * 32 + t * 16 + q * 4;
            float hv[4];
            #pragma unroll
            for (int r = 0; r < 4; ++r) {
                const int node = n0 + r;
                float gi = sigf(acc_i[t][ji][r] + bij);
                float go = sigf(acc_o[t][ji][r] + boj);
                float gu = tanhf_(acc_u[t][ji][r] + buj);
                float cnv = gi * gu;
                float hnv = go * tanhf_(cnv);
                hv[r] = hnv;
                size_t oix = (size_t)node * HHE + jj;
                hw[oix] = rne_bf16(hnv);
                cw[oix] = rne_bf16(cnv);
            }
            hso[(size_t)(n0 >> 1) * HHE + jj]       = rne_bf16(hv[0] + hv[1]);
            hso[(size_t)((n0 >> 1) + 1) * HHE + jj] = rne_bf16(hv[2] + hv[3]);
        }
    }
}

// ---------- big internal levels (R4 known-good): LDS-staged A, double-buffered,
// ping-pong register-prefetched weights; grid = (cnt/64, 8) m-major ----------
__global__ __launch_bounds__(256) void level_v3(
    const unsigned short* __restrict__ xb, const unsigned short* __restrict__ wp,
    const float* __restrict__ bi, const float* __restrict__ bfv,
    const float* __restrict__ bo, const float* __restrict__ bu,
    const unsigned short* __restrict__ hc, const unsigned short* __restrict__ cc,
    const unsigned short* __restrict__ hs,
    unsigned short* __restrict__ hw, unsigned short* __restrict__ cw,
    unsigned short* __restrict__ hso,
    int start, int cnt)
{
    __shared__ __align__(16) unsigned short SH[2 * 3 * 2048];

    const int tid  = threadIdx.x;
    const int lane = tid & 63;
    const int wv   = tid >> 6;
    const int q    = lane >> 4;
    const int ln   = lane & 15;
    const int wm   = wv & 1;
    const int wj   = wv >> 1;
    const int mb   = blockIdx.x * 64;
    const int jt0  = blockIdx.y * 4 + wj * 2;

    const int srow   = lane >> 2;
    const int gchunk = (lane & 3) ^ ((lane >> 3) & 3);
    const int stage_row = mb + wv * 16 + srow;
    const int rdoff = ((q ^ ((ln >> 1) & 3)) * 8);

    const unsigned short* wpl = wp + (size_t)lane * 8;

    f32x4 zero = {0.f, 0.f, 0.f, 0.f};
    f32x4 acc_i[2][2], acc_f[2][2], acc_o[2][2], acc_u[2][2];
    #pragma unroll
    for (int t = 0; t < 2; ++t)
        #pragma unroll
        for (int ji = 0; ji < 2; ++ji) {
            acc_i[t][ji] = zero; acc_f[t][ji] = zero;
            acc_o[t][ji] = zero; acc_u[t][ji] = zero;
        }

    bf16x8 WA[4][2], WB[4][2];

    auto loadW = [&](bf16x8 (&W)[4][2], int ksabs) {
        #pragma unroll
        for (int g = 0; g < 4; ++g)
            #pragma unroll
            for (int ji = 0; ji < 2; ++ji)
                W[g][ji] = *(const bf16x8*)(wpl + ((size_t)((g * 32 + jt0 + ji) * 32 + ksabs)) * 512);
    };

    // ---------------- phase 1: x ----------------
    loadW(WA, 0);
    {
        const unsigned short* g = xb + (size_t)(start + stage_row) * HHE + gchunk * 8;
        GLOAD_LDS16(g, &SH[(0 * 3 + 0) * 2048 + wv * 512]);
    }
    __syncthreads();

    auto p1_body = [&](int ks, bf16x8 (&WU)[4][2], bf16x8 (&WP)[4][2], int prefks) {
        const int cur = ks & 1;
        if (ks < 15) {
            const unsigned short* g = xb + (size_t)(start + stage_row) * HHE + (ks + 1) * 32 + gchunk * 8;
            GLOAD_LDS16(g, &SH[((cur ^ 1) * 3 + 0) * 2048 + wv * 512]);
        }
        loadW(WP, prefks);
        bf16x8 a0 = *(const bf16x8*)&SH[(cur * 3 + 0) * 2048 + (wm * 32 + 0 + ln) * 32 + rdoff];
        bf16x8 a1 = *(const bf16x8*)&SH[(cur * 3 + 0) * 2048 + (wm * 32 + 16 + ln) * 32 + rdoff];
        #pragma unroll
        for (int ji = 0; ji < 2; ++ji) {
            acc_i[0][ji] = MFMA16(a0, WU[0][ji], acc_i[0][ji]);
            acc_i[1][ji] = MFMA16(a1, WU[0][ji], acc_i[1][ji]);
            acc_f[0][ji] = MFMA16(a0, WU[1][ji], acc_f[0][ji]);
            acc_f[1][ji] = MFMA16(a1, WU[1][ji], acc_f[1][ji]);
            acc_o[0][ji] = MFMA16(a0, WU[2][ji], acc_o[0][ji]);
            acc_o[1][ji] = MFMA16(a1, WU[2][ji], acc_o[1][ji]);
            acc_u[0][ji] = MFMA16(a0, WU[3][ji], acc_u[0][ji]);
            acc_u[1][ji] = MFMA16(a1, WU[3][ji], acc_u[1][ji]);
        }
        __syncthreads();
    };

    for (int kk = 0; kk < 8; ++kk) {
        p1_body(2 * kk,     WA, WB, 2 * kk + 1);
        p1_body(2 * kk + 1, WB, WA, (kk == 7) ? 16 : 2 * kk + 2);
    }

    f32x4 acc_fl[2][2], acc_fr[2][2];
    #pragma unroll
    for (int t = 0; t < 2; ++t)
        #pragma unroll
        for (int ji = 0; ji < 2; ++ji) { acc_fl[t][ji] = acc_f[t][ji]; acc_fr[t][ji] = acc_f[t][ji]; }

    // ---------------- phase 2: hsum / h_l / h_r ----------------
    {
        const unsigned short* gs = hs + (size_t)stage_row * HHE + gchunk * 8;
        const unsigned short* gl = hc + ((size_t)(2 * stage_row)) * HHE + gchunk * 8;
        GLOAD_LDS16(gs, &SH[(0 * 3 + 0) * 2048 + wv * 512]);
        GLOAD_LDS16(gl, &SH[(0 * 3 + 1) * 2048 + wv * 512]);
        GLOAD_LDS16(gl + HHE, &SH[(0 * 3 + 2) * 2048 + wv * 512]);
    }
    __syncthreads();

    auto p2_body = [&](int ks, bf16x8 (&WU)[4][2], bf16x8 (&WP)[4][2], int prefks) {
        const int cur = ks & 1;
        if (ks < 15) {
            const unsigned short* gs = hs + (size_t)stage_row * HHE + (ks + 1) * 32 + gchunk * 8;
            const unsigned short* gl = hc + ((size_t)(2 * stage_row)) * HHE + (ks + 1) * 32 + gchunk * 8;
            GLOAD_LDS16(gs, &SH[((cur ^ 1) * 3 + 0) * 2048 + wv * 512]);
            GLOAD_LDS16(gl, &SH[((cur ^ 1) * 3 + 1) * 2048 + wv * 512]);
            GLOAD_LDS16(gl + HHE, &SH[((cur ^ 1) * 3 + 2) * 2048 + wv * 512]);
        }
        loadW(WP, prefks);
        bf16x8 s0 = *(const bf16x8*)&SH[(cur * 3 + 0) * 2048 + (wm * 32 + 0 + ln) * 32 + rdoff];
        bf16x8 s1 = *(const bf16x8*)&SH[(cur * 3 + 0) * 2048 + (wm * 32 + 16 + ln) * 32 + rdoff];
        bf16x8 l0 = *(const bf16x8*)&SH[(cur * 3 + 1) * 2048 + (wm * 32 + 0 + ln) * 32 + rdoff];
        bf16x8 l1 = *(const bf16x8*)&SH[(cur * 3 + 1) * 2048 + (wm * 32 + 16 + ln) * 32 + rdoff];
        bf16x8 r0 = *(const bf16x8*)&SH[(cur * 3 + 2) * 2048 + (wm * 32 + 0 + ln) * 32 + rdoff];
        bf16x8 r1 = *(const bf16x8*)&SH[(cur * 3 + 2) * 2048 + (wm * 32 + 16 + ln) * 32 + rdoff];
        #pragma unroll
        for (int ji = 0; ji < 2; ++ji) {
            acc_i[0][ji]  = MFMA16(s0, WU[0][ji], acc_i[0][ji]);
            acc_i[1][ji]  = MFMA16(s1, WU[0][ji], acc_i[1][ji]);
            acc_o[0][ji]  = MFMA16(s0, WU[2][ji], acc_o[0][ji]);
            acc_o[1][ji]  = MFMA16(s1, WU[2][ji], acc_o[1][ji]);
            acc_u[0][ji]  = MFMA16(s0, WU[3][ji], acc_u[0][ji]);
            acc_u[1][ji]  = MFMA16(s1, WU[3][ji], acc_u[1][ji]);
            acc_fl[0][ji] = MFMA16(l0, WU[1][ji], acc_fl[0][ji]);
            acc_fl[1][ji] = MFMA16(l1, WU[1][ji], acc_fl[1][ji]);
            acc_fr[0][ji] = MFMA16(r0, WU[1][ji], acc_fr[0][ji]);
            acc_fr[1][ji] = MFMA16(r1, WU[1][ji], acc_fr[1][ji]);
        }
        __syncthreads();
    };

    for (int kk = 0; kk < 8; ++kk) {
        p2_body(2 * kk,     WA, WB, 16 + 2 * kk + 1);
        p2_body(2 * kk + 1, WB, WA, (kk == 7) ? 31 : 16 + 2 * kk + 2);
    }

    // ---------------- epilogue ----------------
    #pragma unroll
    for (int ji = 0; ji < 2; ++ji) {
        const int jj = (jt0 + ji) * 16 + ln;
        const float bij = bi[jj], bfj = bfv[jj], boj = bo[jj], buj = bu[jj];
        #pragma unroll
        for (int t = 0; t < 2; ++t) {
            const int n0 = mb + wm * 32 + t * 16 + q * 4;
            float hv[4];
            #pragma unroll
            for (int r = 0; r < 4; ++r) {
                const int node = n0 + r;
                size_t cix = (size_t)(2 * node) * HHE + jj;
                float cl = bf2f(cc[cix]);
                float cr = bf2f(cc[cix + HHE]);
                float gi  = sigf(acc_i[t][ji][r] + bij);
                float gfl = sigf(acc_fl[t][ji][r] + bfj);
                float gfr = sigf(acc_fr[t][ji][r] + bfj);
                float go  = sigf(acc_o[t][ji][r] + boj);
                float gu  = tanhf_(acc_u[t][ji][r] + buj);
                float cnv = gi * gu + gfl * cl + gfr * cr;
                float hnv = go * tanhf_(cnv);
                hv[r] = hnv;
                size_t oix = (size_t)node * HHE + jj;
                hw[oix] = rne_bf16(hnv);
                cw[oix] = rne_bf16(cnv);
            }
            hso[(size_t)(n0 >> 1) * HHE + jj]       = rne_bf16(hv[0] + hv[1]);
            hso[(size_t)((n0 >> 1) + 1) * HHE + jj] = rne_bf16(hv[2] + hv[3]);
        }
    }
}

// ---------- small levels fallback (5..0): register kernel, 2 m-tiles/wave ----------
__global__ __launch_bounds__(256) void level_sm(
    const unsigned short* __restrict__ xb, const unsigned short* __restrict__ wp,
    const float* __restrict__ bi, const float* __restrict__ bfv,
    const float* __restrict__ bo, const float* __restrict__ bu,
    const unsigned short* __restrict__ hc, const unsigned short* __restrict__ cc,
    const unsigned short* __restrict__ hs,
    unsigned short* __restrict__ hw, unsigned short* __restrict__ cw,
    unsigned short* __restrict__ hso,
    float* __restrict__ f32out,
    int start, int cnt)
{
    const int tid  = threadIdx.x;
    const int lane = tid & 63;
    const int wv   = tid >> 6;
    const int quad = lane >> 4;
    const int ln   = lane & 15;
    const int mb   = blockIdx.x * 32;
    const int jt   = blockIdx.y * 4 + wv;
    const int j    = jt * 16 + ln;

    int row[2];
    #pragma unroll
    for (int t = 0; t < 2; ++t) {
        int r = mb + t * 16 + ln;
        row[t] = (r < cnt) ? r : (cnt - 1);
    }
    const unsigned short* ax[2];
    #pragma unroll
    for (int t = 0; t < 2; ++t) ax[t] = xb + (size_t)(start + row[t]) * HHE + quad * 8;

    const unsigned short* bw[4];
    #pragma unroll
    for (int g = 0; g < 4; ++g) bw[g] = wp + ((size_t)(g * 32 + jt) * 32) * 512 + lane * 8;

    f32x4 zero = {0.f, 0.f, 0.f, 0.f};
    f32x4 acc_i[2], acc_f[2], acc_o[2], acc_u[2];
    #pragma unroll
    for (int t = 0; t < 2; ++t) { acc_i[t] = zero; acc_f[t] = zero; acc_o[t] = zero; acc_u[t] = zero; }

    #pragma unroll 4
    for (int ks = 0; ks < 16; ++ks) {
        bf16x8 a[2];
        #pragma unroll
        for (int t = 0; t < 2; ++t) { a[t] = *(const bf16x8*)ax[t]; ax[t] += 32; }
        bf16x8 b0 = *(const bf16x8*)bw[0]; bw[0] += 512;
        bf16x8 b1 = *(const bf16x8*)bw[1]; bw[1] += 512;
        bf16x8 b2 = *(const bf16x8*)bw[2]; bw[2] += 512;
        bf16x8 b3 = *(const bf16x8*)bw[3]; bw[3] += 512;
        #pragma unroll
        for (int t = 0; t < 2; ++t) {
            acc_i[t] = MFMA16(a[t], b0, acc_i[t]);
            acc_f[t] = MFMA16(a[t], b1, acc_f[t]);
            acc_o[t] = MFMA16(a[t], b2, acc_o[t]);
            acc_u[t] = MFMA16(a[t], b3, acc_u[t]);
        }
    }

    f32x4 acc_fl[2], acc_fr[2];
    #pragma unroll
    for (int t = 0; t < 2; ++t) { acc_fl[t] = acc_f[t]; acc_fr[t] = acc_f[t]; }

    const unsigned short* as[2];
    const unsigned short* al[2];
    const unsigned short* ar[2];
    #pragma unroll
    for (int t = 0; t < 2; ++t) {
        as[t] = hs + (size_t)row[t] * HHE + quad * 8;
        al[t] = hc + (size_t)(2 * row[t]) * HHE + quad * 8;
        ar[t] = al[t] + HHE;
    }

    #pragma unroll 4
    for (int ks = 0; ks < 16; ++ks) {
        bf16x8 b0 = *(const bf16x8*)bw[0]; bw[0] += 512;
        bf16x8 b1 = *(const bf16x8*)bw[1]; bw[1] += 512;
        bf16x8 b2 = *(const bf16x8*)bw[2]; bw[2] += 512;
        bf16x8 b3 = *(const bf16x8*)bw[3]; bw[3] += 512;
        bf16x8 s[2];
        #pragma unroll
        for (int t = 0; t < 2; ++t) { s[t] = *(const bf16x8*)as[t]; as[t] += 32; }
        #pragma unroll
        for (int t = 0; t < 2; ++t) {
            acc_i[t] = MFMA16(s[t], b0, acc_i[t]);
            acc_o[t] = MFMA16(s[t], b2, acc_o[t]);
            acc_u[t] = MFMA16(s[t], b3, acc_u[t]);
        }
        bf16x8 l[2];
        #pragma unroll
        for (int t = 0; t < 2; ++t) { l[t] = *(const bf16x8*)al[t]; al[t] += 32; }
        #pragma unroll
        for (int t = 0; t < 2; ++t) acc_fl[t] = MFMA16(l[t], b1, acc_fl[t]);
        bf16x8 rr[2];
        #pragma unroll
        for (int t = 0; t < 2; ++t) { rr[t] = *(const bf16x8*)ar[t]; ar[t] += 32; }
        #pragma unroll
        for (int t = 0; t < 2; ++t) acc_fr[t] = MFMA16(rr[t], b1, acc_fr[t]);
    }

    const float bij = bi[j], bfj = bfv[j], boj = bo[j], buj = bu[j];
    #pragma unroll
    for (int t = 0; t < 2; ++t) {
        const int n0 = mb + t * 16 + quad * 4;
        float hv[4];
        #pragma unroll
        for (int r = 0; r < 4; ++r) {
            const int node = n0 + r;
            const int ncl  = (node < cnt) ? node : (cnt - 1);
            size_t cix = (size_t)(2 * ncl) * HHE + j;
            float cl = bf2f(cc[cix]);
            float cr = bf2f(cc[cix + HHE]);
            float gi  = sigf(acc_i[t][r] + bij);
            float gfl = sigf(acc_fl[t][r] + bfj);
            float gfr = sigf(acc_fr[t][r] + bfj);
            float go  = sigf(acc_o[t][r] + boj);
            float gu  = tanhf_(acc_u[t][r] + buj);
            float cnv = gi * gu + gfl * cl + gfr * cr;
            float hnv = go * tanhf_(cnv);
            hv[r] = hnv;
            if (node < cnt) {
                size_t oix = (size_t)node * HHE + j;
                hw[oix] = rne_bf16(hnv);
                cw[oix] = rne_bf16(cnv);
                if (f32out) {
                    f32out[(size_t)node * 1024 + j]       = hnv;
                    f32out[(size_t)node * 1024 + 512 + j] = cnv;
                }
            }
        }
        if (n0 + 1 < cnt) hso[(size_t)(n0 >> 1) * HHE + j]       = rne_bf16(hv[0] + hv[1]);
        if (n0 + 3 < cnt) hso[(size_t)((n0 >> 1) + 1) * HHE + j] = rne_bf16(hv[2] + hv[3]);
    }
}

// ---------- fused tail: levels 6..0 in ONE launch, 32 blocks (one jtile each),
// W staged once into 128 KB LDS. R9 barrier: slot-array (one 128B line per block)
// — arrive is a parallel agent store, wait is wave0's 32 lanes polling one slot
// each. No shared-counter RMW serialization. Coherent data stores + invalidate-
// only acquire as in R8; level lvl-1's x-phase overlaps the wait. ----------
#define TAIL_NBLK 32

__global__ __launch_bounds__(256) void tail_fused(
    const unsigned short* __restrict__ xb, const unsigned short* __restrict__ wp,
    const float* __restrict__ bi, const float* __restrict__ bfv,
    const float* __restrict__ bo, const float* __restrict__ bu,
    unsigned short* __restrict__ hA, unsigned short* __restrict__ cA,
    unsigned short* __restrict__ hB, unsigned short* __restrict__ cB,
    unsigned short* __restrict__ hs1, unsigned short* __restrict__ hs2,
    float* __restrict__ out, int* __restrict__ bar)
{
    __shared__ __align__(16) unsigned short WL[128 * 512];   // 128 KB: frag f = g*32+ks

    const int tid  = threadIdx.x;
    const int lane = tid & 63;
    const int wv   = tid >> 6;
    const int quad = lane >> 4;
    const int ln   = lane & 15;
    const int jt   = blockIdx.x;          // one jtile per block
    const int j    = jt * 16 + ln;
    const int wl   = lane * 8;

    // one-time: stage this jtile's full W (4 gates x 32 ks x 1 KB) into LDS
    #pragma unroll
    for (int i = 0; i < 32; ++i) {
        int f = i * 4 + wv;               // f = g*32 + ks
        const unsigned short* src = wp + ((size_t)(((f >> 5) * 32 + jt) * 32 + (f & 31))) * 512 + lane * 8;
        GLOAD_LDS16(src, &WL[f * 512]);
    }
    __syncthreads();   // vmcnt(0) drain -> W resident in LDS for the whole kernel

    const float bij = bi[j], bfj = bfv[j], boj = bo[j], buj = bu[j];
    f32x4 zero = {0.f, 0.f, 0.f, 0.f};

    // phase 1 of a level: x @ {Wi,Wf,Wo,Wu} — depends only on x and LDS W
    auto phase1 = [&](int lvl, f32x4& pi, f32x4& pf, f32x4& po, f32x4& pu) {
        const int cnt = 1 << lvl;
        const int start = cnt - 1;
        const int r0  = wv * 16 + ln;
        const int row = (r0 < cnt) ? r0 : (cnt - 1);
        pi = zero; pf = zero; po = zero; pu = zero;
        const unsigned short* ax = xb + (size_t)(start + row) * HHE + quad * 8;
        #pragma unroll 4
        for (int ks = 0; ks < 16; ++ks) {
            bf16x8 a  = *(const bf16x8*)ax; ax += 32;
            bf16x8 w0 = *(const bf16x8*)&WL[(0 * 32 + ks) * 512 + wl];
            bf16x8 w1 = *(const bf16x8*)&WL[(1 * 32 + ks) * 512 + wl];
            bf16x8 w2 = *(const bf16x8*)&WL[(2 * 32 + ks) * 512 + wl];
            bf16x8 w3 = *(const bf16x8*)&WL[(3 * 32 + ks) * 512 + wl];
            pi = MFMA16(a, w0, pi);
            pf = MFMA16(a, w1, pf);
            po = MFMA16(a, w2, po);
            pu = MFMA16(a, w3, pu);
        }
    };

    f32x4 p_i, p_f, p_o, p_u;
    phase1(6, p_i, p_f, p_o, p_u);

    int k = 0;
    for (int lvl = 6; lvl >= 0; --lvl) {
        const int cnt = 1 << lvl;
        const unsigned short *hc, *cc, *hs;
        unsigned short *hw, *cw, *hso;
        if (lvl & 1) { hc = hA; cc = cA; hs = hs1; hw = hB; cw = cB; hso = hs2; }
        else         { hc = hB; cc = cB; hs = hs2; hw = hA; cw = cA; hso = hs1; }

        const int r0  = wv * 16 + ln;
        const int row = (r0 < cnt) ? r0 : (cnt - 1);

        f32x4 acc_i = p_i, acc_o = p_o, acc_u = p_u;
        f32x4 acc_fl = p_f, acc_fr = p_f;

        // phase 2: hsum @ {Wi,Wo,Wu}, h_l/h_r @ Wf (k 512..1023)
        const unsigned short* as = hs + (size_t)row * HHE + quad * 8;
        const unsigned short* al = hc + (size_t)(2 * row) * HHE + quad * 8;
        const unsigned short* ar = al + HHE;
        #pragma unroll 4
        for (int ks = 0; ks < 16; ++ks) {
            bf16x8 w0 = *(const bf16x8*)&WL[(0 * 32 + 16 + ks) * 512 + wl];
            bf16x8 w1 = *(const bf16x8*)&WL[(1 * 32 + 16 + ks) * 512 + wl];
            bf16x8 w2 = *(const bf16x8*)&WL[(2 * 32 + 16 + ks) * 512 + wl];
            bf16x8 w3 = *(const bf16x8*)&WL[(3 * 32 + 16 + ks) * 512 + wl];
            bf16x8 s  = *(const bf16x8*)as; as += 32;
            bf16x8 l  = *(const bf16x8*)al; al += 32;
            bf16x8 rr = *(const bf16x8*)ar; ar += 32;
            acc_i  = MFMA16(s,  w0, acc_i);
            acc_o  = MFMA16(s,  w2, acc_o);
            acc_u  = MFMA16(s,  w3, acc_u);
            acc_fl = MFMA16(l,  w1, acc_fl);
            acc_fr = MFMA16(rr, w1, acc_fr);
        }

        // epilogue: exchanged h/c/hso written with agent-scope (write-through) stores
        const int n0 = wv * 16 + quad * 4;
        float hv[4];
        #pragma unroll
        for (int r = 0; r < 4; ++r) {
            const int node = n0 + r;
            const int ncl  = (node < cnt) ? node : (cnt - 1);
            size_t cix = (size_t)(2 * ncl) * HHE + j;
            float cl = bf2f(cc[cix]);
            float cr = bf2f(cc[cix + HHE]);
            float gi  = sigf(acc_i[r] + bij);
            float gfl = sigf(acc_fl[r] + bfj);
            float gfr = sigf(acc_fr[r] + bfj);
            float go  = sigf(acc_o[r] + boj);
            float gu  = tanhf_(acc_u[r] + buj);
            float cnv = gi * gu + gfl * cl + gfr * cr;
            float hnv = go * tanhf_(cnv);
            hv[r] = hnv;
            if (node < cnt) {
                size_t oix = (size_t)node * HHE + j;
                CSTORE_US(&hw[oix], rne_bf16(hnv));
                CSTORE_US(&cw[oix], rne_bf16(cnv));
                if (lvl == 0) {
                    out[(size_t)node * 1024 + j]       = hnv;
                    out[(size_t)node * 1024 + 512 + j] = cnv;
                }
            }
        }
        if (n0 + 1 < cnt) CSTORE_US(&hso[(size_t)(n0 >> 1) * HHE + j],       rne_bf16(hv[0] + hv[1]));
        if (n0 + 3 < cnt) CSTORE_US(&hso[(size_t)((n0 >> 1) + 1) * HHE + j], rne_bf16(hv[2] + hv[3]));

        if (lvl > 0) {
            ++k;
            __syncthreads();   // drains vmcnt(0) -> this block's coherent stores visible
            // arrive: parallel store of epoch k to this block's own 128B slot
            if (tid == 0)
                __hip_atomic_store(&bar[jt * 32], k, __ATOMIC_RELAXED, __HIP_MEMORY_SCOPE_AGENT);
            // overlap: next level's x-phase while peers arrive (x and LDS W only)
            phase1(lvl - 1, p_i, p_f, p_o, p_u);
            // wait: wave0's 32 lanes poll one slot each (pipelined, no line sharing)
            if (wv == 0 && lane < TAIL_NBLK) {
                while (__hip_atomic_load(&bar[lane * 32], __ATOMIC_RELAXED, __HIP_MEMORY_SCOPE_AGENT) < k)
                    __builtin_amdgcn_s_sleep(2);
            }
            __syncthreads();
            __builtin_amdgcn_fence(__ATOMIC_ACQUIRE, "agent");  // invalidate-only (no wb)
        }
    }
}

extern "C" void kernel_launch(void* const* d_in, const int* in_sizes, int n_in,
                              void* d_out, int out_size, void* d_ws, size_t ws_size,
                              hipStream_t stream) {
    const float* x  = (const float*)d_in[0];
    const float* Wi = (const float*)d_in[1];
    const float* bi = (const float*)d_in[2];
    const float* Wf = (const float*)d_in[3];
    const float* bf = (const float*)d_in[4];
    const float* Wo = (const float*)d_in[5];
    const float* bo = (const float*)d_in[6];
    const float* Wu = (const float*)d_in[7];
    const float* bu = (const float*)d_in[8];
    float* out = (float*)d_out;

    unsigned short* xb  = (unsigned short*)d_ws;          // x bf16
    unsigned short* wp  = xb  + 16776704;                 // packed W bf16
    unsigned short* hA  = wp  + 2097152;                  // h ping (16384 rows)
    unsigned short* hB  = hA  + 8388608;                  // h pong ( 8192 rows)
    unsigned short* hs1 = hB  + 4194304;                  // hsum ( 8192 rows)
    unsigned short* hs2 = hs1 + 4194304;                  // hsum ( 4096 rows)
    unsigned short* cA  = hs2 + 2097152;                  // c ping
    unsigned short* cB  = cA  + 8388608;                  // c pong

    const size_t BAR_OFF = (size_t)96 << 20;   // layout ends at ~100.66 MB; slots at 96 MiB are past it
    const bool fused = ws_size >= BAR_OFF + 4096;
    int* bar = (int*)((char*)d_ws + BAR_OFF);  // 32 slots x 128 B

    // fused one-time prep: W pack (1024 blocks) + x conversion (8192 blocks)
    prep<<<9216, 256, 0, stream>>>(x, Wi, Wf, Wo, Wu, xb, wp, fused ? bar : nullptr);

    // leaf: R4 structure; grid (256, 8) m-major
    leaf_v3<<<dim3(256, 8), 256, 0, stream>>>(xb, wp, bi, bo, bu, hA, cA, hs1, 16383, 16384);

    // levels 13..7 (cnt >= 128): R4 dbuf kernel
    for (int lvl = 13; lvl >= 7; --lvl) {
        int cnt   = 1 << lvl;
        int start = cnt - 1;
        const unsigned short *hc, *cc, *hs;
        unsigned short *hw, *cw, *hso;
        if (lvl & 1) { hc = hA; cc = cA; hs = hs1; hw = hB; cw = cB; hso = hs2; }
        else         { hc = hB; cc = cB; hs = hs2; hw = hA; cw = cA; hso = hs1; }
        level_v3<<<dim3(cnt / 64, 8), 256, 0, stream>>>(xb, wp, bi, bf, bo, bu,
                                                        hc, cc, hs, hw, cw, hso, start, cnt);
    }

    if (fused) {
        // levels 6..0 in one persistent launch, W in LDS, 32 co-resident blocks
        tail_fused<<<TAIL_NBLK, 256, 0, stream>>>(xb, wp, bi, bf, bo, bu,
                                                  hA, cA, hB, cB, hs1, hs2, out, bar);
    } else {
        // fallback: per-level launches (R4 path)
        level_v3<<<dim3(1, 8), 256, 0, stream>>>(xb, wp, bi, bf, bo, bu,
                                                 hB, cB, hs2, hA, cA, hs1, 63, 64);
        for (int lvl = 5; lvl >= 0; --lvl) {
            int cnt   = 1 << lvl;
            int start = cnt - 1;
            const unsigned short *hc, *cc, *hs;
            unsigned short *hw, *cw, *hso;
            if (lvl & 1) { hc = hA; cc = cA; hs = hs1; hw = hB; cw = cB; hso = hs2; }
            else         { hc = hB; cc = cB; hs = hs2; hw = hA; cw = cA; hso = hs1; }
            float* f32out = (lvl == 0) ? out : nullptr;
            level_sm<<<dim3((cnt + 31) / 32, 8), 256, 0, stream>>>(xb, wp, bi, bf, bo, bu,
                                                                   hc, cc, hs, hw, cw, hso, f32out,
                                                                   start, cnt);
        }
    }
}

// Round 10
// 488.893 us; speedup vs baseline: 1.3142x; 1.0415x over previous
//
#include <hip/hip_runtime.h>

typedef __attribute__((ext_vector_type(8))) short bf16x8;
typedef __attribute__((ext_vector_type(4))) float f32x4;

#define HHE 512

__device__ __forceinline__ unsigned short rne_bf16(float f) {
    union { float f; unsigned u; } v; v.f = f;
    unsigned r = v.u + 0x7FFFu + ((v.u >> 16) & 1u);
    return (unsigned short)(r >> 16);
}
__device__ __forceinline__ float bf2f(unsigned short s) {
    union { unsigned u; float f; } v; v.u = ((unsigned)s) << 16; return v.f;
}
__device__ __forceinline__ float sigf(float v)   { return 1.0f / (1.0f + __expf(-v)); }
__device__ __forceinline__ float tanhf_(float v) { return 2.0f / (1.0f + __expf(-2.0f * v)) - 1.0f; }

#define MFMA16(a, b, c) __builtin_amdgcn_mfma_f32_16x16x32_bf16(a, b, c, 0, 0, 0)

#define GLOAD_LDS16(g, l) \
    __builtin_amdgcn_global_load_lds((const __attribute__((address_space(1))) void*)(g), \
                                     (__attribute__((address_space(3))) void*)(l), 16, 0, 0)

// coherent (agent-scope, write-through) 2-byte store for cross-XCD exchange in the tail
#define CSTORE_US(p, v) __hip_atomic_store((p), (v), __ATOMIC_RELAXED, __HIP_MEMORY_SCOPE_AGENT)

// ---------- one-time prep, fused into a single dispatch:
//   blocks [0, 1024)    : pack 4 gate weight matrices into MFMA B-fragment order
//                         [gate][jtile(32)][kstep(32)][lane(64)][8]
//   blocks [1024, 9216) : x fp32 -> bf16
__global__ __launch_bounds__(256) void prep(
    const float* __restrict__ x,
    const float* __restrict__ Wi, const float* __restrict__ Wf,
    const float* __restrict__ Wo, const float* __restrict__ Wu,
    unsigned short* __restrict__ xb, unsigned short* __restrict__ wp,
    int* __restrict__ bar)
{
    const int b = blockIdx.x;
    if (b < 1024) {
        int t    = b * 256 + threadIdx.x;
        if (bar && t < 1024) bar[t] = 0;   // zero the 4 KB slot-array each replay
        int lane = t & 63;
        int fid  = t >> 6;
        int ks   = fid & 31;
        int jt   = (fid >> 5) & 31;
        int g    = fid >> 10;
        const float* W = (g == 0) ? Wi : (g == 1) ? Wf : (g == 2) ? Wo : Wu;
        int row = jt * 16 + (lane & 15);
        int col = ks * 32 + (lane >> 4) * 8;
        const float* src = W + (size_t)row * 1024 + col;
        float4 f0 = *(const float4*)(src);
        float4 f1 = *(const float4*)(src + 4);
        uint4 o;
        o.x = (unsigned)rne_bf16(f0.x) | ((unsigned)rne_bf16(f0.y) << 16);
        o.y = (unsigned)rne_bf16(f0.z) | ((unsigned)rne_bf16(f0.w) << 16);
        o.z = (unsigned)rne_bf16(f1.x) | ((unsigned)rne_bf16(f1.y) << 16);
        o.w = (unsigned)rne_bf16(f1.z) | ((unsigned)rne_bf16(f1.w) << 16);
        ((uint4*)wp)[t] = o;
    } else {
        size_t idx = (size_t)(b - 1024) * 256 + threadIdx.x;
        if (idx >= 2097088) return;
        const float4* p = (const float4*)x + idx * 2;
        float4 f0 = p[0], f1 = p[1];
        uint4 o;
        o.x = (unsigned)rne_bf16(f0.x) | ((unsigned)rne_bf16(f0.y) << 16);
        o.y = (unsigned)rne_bf16(f0.z) | ((unsigned)rne_bf16(f0.w) << 16);
        o.z = (unsigned)rne_bf16(f1.x) | ((unsigned)rne_bf16(f1.y) << 16);
        o.w = (unsigned)rne_bf16(f1.z) | ((unsigned)rne_bf16(f1.w) << 16);
        ((uint4*)xb)[idx] = o;
    }
}

// ---------- leaf level: phase-1-only level_v3 structure (R4 known-good). LDS-staged A
// via global_load_lds (double-buffered), W register ping-pong, 3 gates (i,o,u).
// 64 rows x 4 jtiles/block, 4 waves; grid (256, 8) m-major. ----------
__global__ __launch_bounds__(256) void leaf_v3(
    const unsigned short* __restrict__ xb, const unsigned short* __restrict__ wp,
    const float* __restrict__ bi, const float* __restrict__ bo, const float* __restrict__ bu,
    unsigned short* __restrict__ hw, unsigned short* __restrict__ cw,
    unsigned short* __restrict__ hso,
    int start, int cnt)
{
    __shared__ __align__(16) unsigned short SH[2 * 2048];

    const int tid  = threadIdx.x;
    const int lane = tid & 63;
    const int wv   = tid >> 6;
    const int q    = lane >> 4;
    const int ln   = lane & 15;
    const int wm   = wv & 1;
    const int wj   = wv >> 1;
    const int mb   = blockIdx.x * 64;
    const int jt0  = blockIdx.y * 4 + wj * 2;

    const int srow   = lane >> 2;
    const int gchunk = (lane & 3) ^ ((lane >> 3) & 3);
    const int stage_row = mb + wv * 16 + srow;
    const int rdoff = ((q ^ ((ln >> 1) & 3)) * 8);

    const unsigned short* wpl = wp + (size_t)lane * 8;

    f32x4 zero = {0.f, 0.f, 0.f, 0.f};
    f32x4 acc_i[2][2], acc_o[2][2], acc_u[2][2];
    #pragma unroll
    for (int t = 0; t < 2; ++t)
        #pragma unroll
        for (int ji = 0; ji < 2; ++ji) {
            acc_i[t][ji] = zero; acc_o[t][ji] = zero; acc_u[t][ji] = zero;
        }

    bf16x8 WA[3][2], WB[3][2];

    // gate map: 0 -> Wi(0), 1 -> Wo(2), 2 -> Wu(3)
    auto loadW = [&](bf16x8 (&W)[3][2], int ksabs) {
        #pragma unroll
        for (int g = 0; g < 3; ++g) {
            const int gg = (g == 0) ? 0 : (g + 1);
            #pragma unroll
            for (int ji = 0; ji < 2; ++ji)
                W[g][ji] = *(const bf16x8*)(wpl + ((size_t)((gg * 32 + jt0 + ji) * 32 + ksabs)) * 512);
        }
    };

    loadW(WA, 0);
    {
        const unsigned short* g = xb + (size_t)(start + stage_row) * HHE + gchunk * 8;
        GLOAD_LDS16(g, &SH[0 * 2048 + wv * 512]);
    }
    __syncthreads();

    auto body = [&](int ks, bf16x8 (&WU)[3][2], bf16x8 (&WP)[3][2], int prefks) {
        const int cur = ks & 1;
        if (ks < 15) {
            const unsigned short* g = xb + (size_t)(start + stage_row) * HHE + (ks + 1) * 32 + gchunk * 8;
            GLOAD_LDS16(g, &SH[(cur ^ 1) * 2048 + wv * 512]);
        }
        loadW(WP, prefks);
        bf16x8 a0 = *(const bf16x8*)&SH[cur * 2048 + (wm * 32 + 0 + ln) * 32 + rdoff];
        bf16x8 a1 = *(const bf16x8*)&SH[cur * 2048 + (wm * 32 + 16 + ln) * 32 + rdoff];
        #pragma unroll
        for (int ji = 0; ji < 2; ++ji) {
            acc_i[0][ji] = MFMA16(a0, WU[0][ji], acc_i[0][ji]);
            acc_i[1][ji] = MFMA16(a1, WU[0][ji], acc_i[1][ji]);
            acc_o[0][ji] = MFMA16(a0, WU[1][ji], acc_o[0][ji]);
            acc_o[1][ji] = MFMA16(a1, WU[1][ji], acc_o[1][ji]);
            acc_u[0][ji] = MFMA16(a0, WU[2][ji], acc_u[0][ji]);
            acc_u[1][ji] = MFMA16(a1, WU[2][ji], acc_u[1][ji]);
        }
        __syncthreads();
    };

    for (int kk = 0; kk < 8; ++kk) {
        body(2 * kk,     WA, WB, 2 * kk + 1);
        body(2 * kk + 1, WB, WA, (kk == 7) ? 15 : 2 * kk + 2);   // last: dummy reload
    }

    // epilogue
    #pragma unroll
    for (int ji = 0; ji < 2; ++ji) {
        const int jj = (jt0 + ji) * 16 + ln;
        const float bij = bi[jj], boj = bo[jj], buj = bu[jj];
        #pragma unroll
        for (int t = 0; t < 2; ++t) {
            const int n0 = mb + wm * 32 + t * 16 + q * 4;
            float hv[4];
            #pragma unroll
            for (int r = 0; r < 4; ++r) {
                const int node = n0 + r;
                float gi = sigf(acc_i[t][ji][r] + bij);
                float go = sigf(acc_o[t][ji][r] + boj);
                float gu = tanhf_(acc_u[t][ji][r] + buj);
                float cnv = gi * gu;
                float hnv = go * tanhf_(cnv);
                hv[r] = hnv;
                size_t oix = (size_t)node * HHE + jj;
                hw[oix] = rne_bf16(hnv);
                cw[oix] = rne_bf16(cnv);
            }
            hso[(size_t)(n0 >> 1) * HHE + jj]       = rne_bf16(hv[0] + hv[1]);
            hso[(size_t)((n0 >> 1) + 1) * HHE + jj] = rne_bf16(hv[2] + hv[3]);
        }
    }
}

// ---------- merged-phase internal levels 13..7: BOTH phases share ONE barrier per
// K-step (17 barriers vs level_v3's 33). Lockstep stage->barrier->read preserved
// (R5 lesson: drift kills L2 W-reuse). Wave = 1 jtile x 64 rows (4 m-tiles).
// LDS = [2 bufs][4 ops: x,hsum,h_l,h_r][64x32] = 32 KB. W single-buffered in two
// 4-frag halves (W1 hidden by stage+barrier, W2 by phase-1 MFMAs + ds_reads).
// f-gate x-part kept in acc_f, added into fl/fr at epilogue. ----------
__global__ __launch_bounds__(256) void level_m(
    const unsigned short* __restrict__ xb, const unsigned short* __restrict__ wp,
    const float* __restrict__ bi, const float* __restrict__ bfv,
    const float* __restrict__ bo, const float* __restrict__ bu,
    const unsigned short* __restrict__ hc, const unsigned short* __restrict__ cc,
    const unsigned short* __restrict__ hs,
    unsigned short* __restrict__ hw, unsigned short* __restrict__ cw,
    unsigned short* __restrict__ hso,
    int start, int cnt)
{
    __shared__ __align__(16) unsigned short SH[2 * 4 * 2048];   // 32 KB

    const int tid  = threadIdx.x;
    const int lane = tid & 63;
    const int wv   = tid >> 6;          // wave = one jtile
    const int q    = lane >> 4;
    const int ln   = lane & 15;
    const int mb   = blockIdx.x * 64;
    const int jt   = blockIdx.y * 4 + wv;
    const int j    = jt * 16 + ln;

    const int srow   = lane >> 2;
    const int gchunk = (lane & 3) ^ ((lane >> 3) & 3);
    const int stage_row = mb + wv * 16 + srow;
    const int rdoff  = ((q ^ ((ln >> 1) & 3)) * 8);

    // frag index = g*1024 + jt*32 + ks  (x512 shorts)
    const unsigned short* wpl = wp + ((size_t)jt * 32) * 512 + (size_t)lane * 8;

    const unsigned short* gx0 = xb + (size_t)(start + stage_row) * HHE + gchunk * 8;
    const unsigned short* gs0 = hs + (size_t)stage_row * HHE + gchunk * 8;
    const unsigned short* gl0 = hc + (size_t)(2 * stage_row) * HHE + gchunk * 8;

    f32x4 zero = {0.f, 0.f, 0.f, 0.f};
    f32x4 acc_i[4], acc_f[4], acc_o[4], acc_u[4], acc_fl[4], acc_fr[4];
    #pragma unroll
    for (int m = 0; m < 4; ++m) {
        acc_i[m] = zero; acc_f[m] = zero; acc_o[m] = zero;
        acc_u[m] = zero; acc_fl[m] = zero; acc_fr[m] = zero;
    }

    // prologue: stage K-step 0 (all 4 streams) into buffer 0
    GLOAD_LDS16(gx0,       &SH[(0 * 4 + 0) * 2048 + wv * 512]);
    GLOAD_LDS16(gs0,       &SH[(0 * 4 + 1) * 2048 + wv * 512]);
    GLOAD_LDS16(gl0,       &SH[(0 * 4 + 2) * 2048 + wv * 512]);
    GLOAD_LDS16(gl0 + HHE, &SH[(0 * 4 + 3) * 2048 + wv * 512]);
    __syncthreads();

    #pragma unroll 2
    for (int ks = 0; ks < 16; ++ks) {
        const int cur = ks & 1;

        // W half-1: x-phase gates (k-block ks)
        bf16x8 W1[4];
        #pragma unroll
        for (int g = 0; g < 4; ++g)
            W1[g] = *(const bf16x8*)(wpl + ((size_t)(g * 1024 + ks)) * 512);

        // stage next K-step (4 streams) into the other buffer
        if (ks < 15) {
            const int col = (ks + 1) * 32;
            GLOAD_LDS16(gx0 + col,       &SH[((cur ^ 1) * 4 + 0) * 2048 + wv * 512]);
            GLOAD_LDS16(gs0 + col,       &SH[((cur ^ 1) * 4 + 1) * 2048 + wv * 512]);
            GLOAD_LDS16(gl0 + col,       &SH[((cur ^ 1) * 4 + 2) * 2048 + wv * 512]);
            GLOAD_LDS16(gl0 + col + HHE, &SH[((cur ^ 1) * 4 + 3) * 2048 + wv * 512]);
        }

        // phase-1: x @ {Wi,Wf,Wo,Wu}
        {
            bf16x8 a0 = *(const bf16x8*)&SH[(cur * 4 + 0) * 2048 + ( 0 + ln) * 32 + rdoff];
            bf16x8 a1 = *(const bf16x8*)&SH[(cur * 4 + 0) * 2048 + (16 + ln) * 32 + rdoff];
            bf16x8 a2 = *(const bf16x8*)&SH[(cur * 4 + 0) * 2048 + (32 + ln) * 32 + rdoff];
            bf16x8 a3 = *(const bf16x8*)&SH[(cur * 4 + 0) * 2048 + (48 + ln) * 32 + rdoff];
            acc_i[0] = MFMA16(a0, W1[0], acc_i[0]);
            acc_i[1] = MFMA16(a1, W1[0], acc_i[1]);
            acc_i[2] = MFMA16(a2, W1[0], acc_i[2]);
            acc_i[3] = MFMA16(a3, W1[0], acc_i[3]);
            acc_f[0] = MFMA16(a0, W1[1], acc_f[0]);
            acc_f[1] = MFMA16(a1, W1[1], acc_f[1]);
            acc_f[2] = MFMA16(a2, W1[1], acc_f[2]);
            acc_f[3] = MFMA16(a3, W1[1], acc_f[3]);
            acc_o[0] = MFMA16(a0, W1[2], acc_o[0]);
            acc_o[1] = MFMA16(a1, W1[2], acc_o[1]);
            acc_o[2] = MFMA16(a2, W1[2], acc_o[2]);
            acc_o[3] = MFMA16(a3, W1[2], acc_o[3]);
            acc_u[0] = MFMA16(a0, W1[3], acc_u[0]);
            acc_u[1] = MFMA16(a1, W1[3], acc_u[1]);
            acc_u[2] = MFMA16(a2, W1[3], acc_u[2]);
            acc_u[3] = MFMA16(a3, W1[3], acc_u[3]);
        }

        // W half-2: h-phase gates (k-block 16+ks)
        bf16x8 W2[4];
        #pragma unroll
        for (int g = 0; g < 4; ++g)
            W2[g] = *(const bf16x8*)(wpl + ((size_t)(g * 1024 + 16 + ks)) * 512);

        // phase-2: hsum @ {Wi,Wo,Wu}, h_l/h_r @ Wf — two m-halves bound live temps
        #pragma unroll
        for (int h = 0; h < 2; ++h) {
            const int m0 = h * 2;
            const int ro = m0 * 16;
            bf16x8 s0 = *(const bf16x8*)&SH[(cur * 4 + 1) * 2048 + (ro +  0 + ln) * 32 + rdoff];
            bf16x8 s1 = *(const bf16x8*)&SH[(cur * 4 + 1) * 2048 + (ro + 16 + ln) * 32 + rdoff];
            bf16x8 l0 = *(const bf16x8*)&SH[(cur * 4 + 2) * 2048 + (ro +  0 + ln) * 32 + rdoff];
            bf16x8 l1 = *(const bf16x8*)&SH[(cur * 4 + 2) * 2048 + (ro + 16 + ln) * 32 + rdoff];
            bf16x8 r0 = *(const bf16x8*)&SH[(cur * 4 + 3) * 2048 + (ro +  0 + ln) * 32 + rdoff];
            bf16x8 r1 = *(const bf16x8*)&SH[(cur * 4 + 3) * 2048 + (ro + 16 + ln) * 32 + rdoff];
            acc_i[m0]      = MFMA16(s0, W2[0], acc_i[m0]);
            acc_i[m0 + 1]  = MFMA16(s1, W2[0], acc_i[m0 + 1]);
            acc_o[m0]      = MFMA16(s0, W2[2], acc_o[m0]);
            acc_o[m0 + 1]  = MFMA16(s1, W2[2], acc_o[m0 + 1]);
            acc_u[m0]      = MFMA16(s0, W2[3], acc_u[m0]);
            acc_u[m0 + 1]  = MFMA16(s1, W2[3], acc_u[m0 + 1]);
            acc_fl[m0]     = MFMA16(l0, W2[1], acc_fl[m0]);
            acc_fl[m0 + 1] = MFMA16(l1, W2[1], acc_fl[m0 + 1]);
            acc_fr[m0]     = MFMA16(r0, W2[1], acc_fr[m0]);
            acc_fr[m0 + 1] = MFMA16(r1, W2[1], acc_fr[m0 + 1]);
        }

        __syncthreads();
    }

    // ---------------- epilogue ----------------
    const float bij = bi[j], bfj = bfv[j], boj = bo[j], buj = bu[j];
    #pragma unroll
    for (int m = 0; m < 4; ++m) {
        const int n0 = mb + m * 16 + q * 4;
        float hv[4];
        #pragma unroll
        for (int r = 0; r < 4; ++r) {
            const int node = n0 + r;
            size_t cix = (size_t)(2 * node) * HHE + j;
            float cl = bf2f(cc[cix]);
            float cr = bf2f(cc[cix + HHE]);
            float gi  = sigf(acc_i[m][r] + bij);
            float gfl = sigf(acc_f[m][r] + acc_fl[m][r] + bfj);
            float gfr = sigf(acc_f[m][r] + acc_fr[m][r] + bfj);
            float go  = sigf(acc_o[m][r] + boj);
            float gu  = tanhf_(acc_u[m][r] + buj);
            float cnv = gi * gu + gfl * cl + gfr * cr;
            float hnv = go * tanhf_(cnv);
            hv[r] = hnv;
            size_t oix = (size_t)node * HHE + j;
            hw[oix] = rne_bf16(hnv);
            cw[oix] = rne_bf16(cnv);
        }
        hso[(size_t)(n0 >> 1) * HHE + j]       = rne_bf16(hv[0] + hv[1]);
        hso[(size_t)((n0 >> 1) + 1) * HHE + j] = rne_bf16(hv[2] + hv[3]);
    }
}

// ---------- level 6 fallback (cnt = 64): R4 64-row 4-wave dbuf kernel ----------
__global__ __launch_bounds__(256) void level_v3(
    const unsigned short* __restrict__ xb, const unsigned short* __restrict__ wp,
    const float* __restrict__ bi, const float* __restrict__ bfv,
    const float* __restrict__ bo, const float* __restrict__ bu,
    const unsigned short* __restrict__ hc, const unsigned short* __restrict__ cc,
    const unsigned short* __restrict__ hs,
    unsigned short* __restrict__ hw, unsigned short* __restrict__ cw,
    unsigned short* __restrict__ hso,
    int start, int cnt)
{
    __shared__ __align__(16) unsigned short SH[2 * 3 * 2048];

    const int tid  = threadIdx.x;
    const int lane = tid & 63;
    const int wv   = tid >> 6;
    const int q    = lane >> 4;
    const int ln   = lane & 15;
    const int wm   = wv & 1;
    const int wj   = wv >> 1;
    const int mb   = blockIdx.x * 64;
    const int jt0  = blockIdx.y * 4 + wj * 2;

    const int srow   = lane >> 2;
    const int gchunk = (lane & 3) ^ ((lane >> 3) & 3);
    const int stage_row = mb + wv * 16 + srow;
    const int rdoff = ((q ^ ((ln >> 1) & 3)) * 8);

    const unsigned short* wpl = wp + (size_t)lane * 8;

    f32x4 zero = {0.f, 0.f, 0.f, 0.f};
    f32x4 acc_i[2][2], acc_f[2][2], acc_o[2][2], acc_u[2][2];
    #pragma unroll
    for (int t = 0; t < 2; ++t)
        #pragma unroll
        for (int ji = 0; ji < 2; ++ji) {
            acc_i[t][ji] = zero; acc_f[t][ji] = zero;
            acc_o[t][ji] = zero; acc_u[t][ji] = zero;
        }

    bf16x8 WA[4][2], WB[4][2];

    auto loadW = [&](bf16x8 (&W)[4][2], int ksabs) {
        #pragma unroll
        for (int g = 0; g < 4; ++g)
            #pragma unroll
            for (int ji = 0; ji < 2; ++ji)
                W[g][ji] = *(const bf16x8*)(wpl + ((size_t)((g * 32 + jt0 + ji) * 32 + ksabs)) * 512);
    };

    loadW(WA, 0);
    {
        const unsigned short* g = xb + (size_t)(start + stage_row) * HHE + gchunk * 8;
        GLOAD_LDS16(g, &SH[(0 * 3 + 0) * 2048 + wv * 512]);
    }
    __syncthreads();

    auto p1_body = [&](int ks, bf16x8 (&WU)[4][2], bf16x8 (&WP)[4][2], int prefks) {
        const int cur = ks & 1;
        if (ks < 15) {
            const unsigned short* g = xb + (size_t)(start + stage_row) * HHE + (ks + 1) * 32 + gchunk * 8;
            GLOAD_LDS16(g, &SH[((cur ^ 1) * 3 + 0) * 2048 + wv * 512]);
        }
        loadW(WP, prefks);
        bf16x8 a0 = *(const bf16x8*)&SH[(cur * 3 + 0) * 2048 + (wm * 32 + 0 + ln) * 32 + rdoff];
        bf16x8 a1 = *(const bf16x8*)&SH[(cur * 3 + 0) * 2048 + (wm * 32 + 16 + ln) * 32 + rdoff];
        #pragma unroll
        for (int ji = 0; ji < 2; ++ji) {
            acc_i[0][ji] = MFMA16(a0, WU[0][ji], acc_i[0][ji]);
            acc_i[1][ji] = MFMA16(a1, WU[0][ji], acc_i[1][ji]);
            acc_f[0][ji] = MFMA16(a0, WU[1][ji], acc_f[0][ji]);
            acc_f[1][ji] = MFMA16(a1, WU[1][ji], acc_f[1][ji]);
            acc_o[0][ji] = MFMA16(a0, WU[2][ji], acc_o[0][ji]);
            acc_o[1][ji] = MFMA16(a1, WU[2][ji], acc_o[1][ji]);
            acc_u[0][ji] = MFMA16(a0, WU[3][ji], acc_u[0][ji]);
            acc_u[1][ji] = MFMA16(a1, WU[3][ji], acc_u[1][ji]);
        }
        __syncthreads();
    };

    for (int kk = 0; kk < 8; ++kk) {
        p1_body(2 * kk,     WA, WB, 2 * kk + 1);
        p1_body(2 * kk + 1, WB, WA, (kk == 7) ? 16 : 2 * kk + 2);
    }

    f32x4 acc_fl[2][2], acc_fr[2][2];
    #pragma unroll
    for (int t = 0; t < 2; ++t)
        #pragma unroll
        for (int ji = 0; ji < 2; ++ji) { acc_fl[t][ji] = acc_f[t][ji]; acc_fr[t][ji] = acc_f[t][ji]; }

    {
        const unsigned short* gs = hs + (size_t)stage_row * HHE + gchunk * 8;
        const unsigned short* gl = hc + ((size_t)(2 * stage_row)) * HHE + gchunk * 8;
        GLOAD_LDS16(gs, &SH[(0 * 3 + 0) * 2048 + wv * 512]);
        GLOAD_LDS16(gl, &SH[(0 * 3 + 1) * 2048 + wv * 512]);
        GLOAD_LDS16(gl + HHE, &SH[(0 * 3 + 2) * 2048 + wv * 512]);
    }
    __syncthreads();

    auto p2_body = [&](int ks, bf16x8 (&WU)[4][2], bf16x8 (&WP)[4][2], int prefks) {
        const int cur = ks & 1;
        if (ks < 15) {
            const unsigned short* gs = hs + (size_t)stage_row * HHE + (ks + 1) * 32 + gchunk * 8;
            const unsigned short* gl = hc + ((size_t)(2 * stage_row)) * HHE + (ks + 1) * 32 + gchunk * 8;
            GLOAD_LDS16(gs, &SH[((cur ^ 1) * 3 + 0) * 2048 + wv * 512]);
            GLOAD_LDS16(gl, &SH[((cur ^ 1) * 3 + 1) * 2048 + wv * 512]);
            GLOAD_LDS16(gl + HHE, &SH[((cur ^ 1) * 3 + 2) * 2048 + wv * 512]);
        }
        loadW(WP, prefks);
        bf16x8 s0 = *(const bf16x8*)&SH[(cur * 3 + 0) * 2048 + (wm * 32 + 0 + ln) * 32 + rdoff];
        bf16x8 s1 = *(const bf16x8*)&SH[(cur * 3 + 0) * 2048 + (wm * 32 + 16 + ln) * 32 + rdoff];
        bf16x8 l0 = *(const bf16x8*)&SH[(cur * 3 + 1) * 2048 + (wm * 32 + 0 + ln) * 32 + rdoff];
        bf16x8 l1 = *(const bf16x8*)&SH[(cur * 3 + 1) * 2048 + (wm * 32 + 16 + ln) * 32 + rdoff];
        bf16x8 r0 = *(const bf16x8*)&SH[(cur * 3 + 2) * 2048 + (wm * 32 + 0 + ln) * 32 + rdoff];
        bf16x8 r1 = *(const bf16x8*)&SH[(cur * 3 + 2) * 2048 + (wm * 32 + 16 + ln) * 32 + rdoff];
        #pragma unroll
        for (int ji = 0; ji < 2; ++ji) {
            acc_i[0][ji]  = MFMA16(s0, WU[0][ji], acc_i[0][ji]);
            acc_i[1][ji]  = MFMA16(s1, WU[0][ji], acc_i[1][ji]);
            acc_o[0][ji]  = MFMA16(s0, WU[2][ji], acc_o[0][ji]);
            acc_o[1][ji]  = MFMA16(s1, WU[2][ji], acc_o[1][ji]);
            acc_u[0][ji]  = MFMA16(s0, WU[3][ji], acc_u[0][ji]);
            acc_u[1][ji]  = MFMA16(s1, WU[3][ji], acc_u[1][ji]);
            acc_fl[0][ji] = MFMA16(l0, WU[1][ji], acc_fl[0][ji]);
            acc_fl[1][ji] = MFMA16(l1, WU[1][ji], acc_fl[1][ji]);
            acc_fr[0][ji] = MFMA16(r0, WU[1][ji], acc_fr[0][ji]);
            acc_fr[1][ji] = MFMA16(r1, WU[1][ji], acc_fr[1][ji]);
        }
        __syncthreads();
    };

    for (int kk = 0; kk < 8; ++kk) {
        p2_body(2 * kk,     WA, WB, 16 + 2 * kk + 1);
        p2_body(2 * kk + 1, WB, WA, (kk == 7) ? 31 : 16 + 2 * kk + 2);
    }

    #pragma unroll
    for (int ji = 0; ji < 2; ++ji) {
        const int jj = (jt0 + ji) * 16 + ln;
        const float bij = bi[jj], bfj = bfv[jj], boj = bo[jj], buj = bu[jj];
        #pragma unroll
        for (int t = 0; t < 2; ++t) {
            const int n0 = mb + wm * 32 + t * 16 + q * 4;
            float hv[4];
            #pragma unroll
            for (int r = 0; r < 4; ++r) {
                const int node = n0 + r;
                size_t cix = (size_t)(2 * node) * HHE + jj;
                float cl = bf2f(cc[cix]);
                float cr = bf2f(cc[cix + HHE]);
                float gi  = sigf(acc_i[t][ji][r] + bij);
                float gfl = sigf(acc_fl[t][ji][r] + bfj);
                float gfr = sigf(acc_fr[t][ji][r] + bfj);
                float go  = sigf(acc_o[t][ji][r] + boj);
                float gu  = tanhf_(acc_u[t][ji][r] + buj);
                float cnv = gi * gu + gfl * cl + gfr * cr;
                float hnv = go * tanhf_(cnv);
                hv[r] = hnv;
                size_t oix = (size_t)node * HHE + jj;
                hw[oix] = rne_bf16(hnv);
                cw[oix] = rne_bf16(cnv);
            }
            hso[(size_t)(n0 >> 1) * HHE + jj]       = rne_bf16(hv[0] + hv[1]);
            hso[(size_t)((n0 >> 1) + 1) * HHE + jj] = rne_bf16(hv[2] + hv[3]);
        }
    }
}

// ---------- small levels fallback (5..0): register kernel, 2 m-tiles/wave ----------
__global__ __launch_bounds__(256) void level_sm(
    const unsigned short* __restrict__ xb, const unsigned short* __restrict__ wp,
    const float* __restrict__ bi, const float* __restrict__ bfv,
    const float* __restrict__ bo, const float* __restrict__ bu,
    const unsigned short* __restrict__ hc, const unsigned short* __restrict__ cc,
    const unsigned short* __restrict__ hs,
    unsigned short* __restrict__ hw, unsigned short* __restrict__ cw,
    unsigned short* __restrict__ hso,
    float* __restrict__ f32out,
    int start, int cnt)
{
    const int tid  = threadIdx.x;
    const int lane = tid & 63;
    const int wv   = tid >> 6;
    const int quad = lane >> 4;
    const int ln   = lane & 15;
    const int mb   = blockIdx.x * 32;
    const int jt   = blockIdx.y * 4 + wv;
    const int j    = jt * 16 + ln;

    int row[2];
    #pragma unroll
    for (int t = 0; t < 2; ++t) {
        int r = mb + t * 16 + ln;
        row[t] = (r < cnt) ? r : (cnt - 1);
    }
    const unsigned short* ax[2];
    #pragma unroll
    for (int t = 0; t < 2; ++t) ax[t] = xb + (size_t)(start + row[t]) * HHE + quad * 8;

    const unsigned short* bw[4];
    #pragma unroll
    for (int g = 0; g < 4; ++g) bw[g] = wp + ((size_t)(g * 32 + jt) * 32) * 512 + lane * 8;

    f32x4 zero = {0.f, 0.f, 0.f, 0.f};
    f32x4 acc_i[2], acc_f[2], acc_o[2], acc_u[2];
    #pragma unroll
    for (int t = 0; t < 2; ++t) { acc_i[t] = zero; acc_f[t] = zero; acc_o[t] = zero; acc_u[t] = zero; }

    #pragma unroll 4
    for (int ks = 0; ks < 16; ++ks) {
        bf16x8 a[2];
        #pragma unroll
        for (int t = 0; t < 2; ++t) { a[t] = *(const bf16x8*)ax[t]; ax[t] += 32; }
        bf16x8 b0 = *(const bf16x8*)bw[0]; bw[0] += 512;
        bf16x8 b1 = *(const bf16x8*)bw[1]; bw[1] += 512;
        bf16x8 b2 = *(const bf16x8*)bw[2]; bw[2] += 512;
        bf16x8 b3 = *(const bf16x8*)bw[3]; bw[3] += 512;
        #pragma unroll
        for (int t = 0; t < 2; ++t) {
            acc_i[t] = MFMA16(a[t], b0, acc_i[t]);
            acc_f[t] = MFMA16(a[t], b1, acc_f[t]);
            acc_o[t] = MFMA16(a[t], b2, acc_o[t]);
            acc_u[t] = MFMA16(a[t], b3, acc_u[t]);
        }
    }

    f32x4 acc_fl[2], acc_fr[2];
    #pragma unroll
    for (int t = 0; t < 2; ++t) { acc_fl[t] = acc_f[t]; acc_fr[t] = acc_f[t]; }

    const unsigned short* as[2];
    const unsigned short* al[2];
    const unsigned short* ar[2];
    #pragma unroll
    for (int t = 0; t < 2; ++t) {
        as[t] = hs + (size_t)row[t] * HHE + quad * 8;
        al[t] = hc + (size_t)(2 * row[t]) * HHE + quad * 8;
        ar[t] = al[t] + HHE;
    }

    #pragma unroll 4
    for (int ks = 0; ks < 16; ++ks) {
        bf16x8 b0 = *(const bf16x8*)bw[0]; bw[0] += 512;
        bf16x8 b1 = *(const bf16x8*)bw[1]; bw[1] += 512;
        bf16x8 b2 = *(const bf16x8*)bw[2]; bw[2] += 512;
        bf16x8 b3 = *(const bf16x8*)bw[3]; bw[3] += 512;
        bf16x8 s[2];
        #pragma unroll
        for (int t = 0; t < 2; ++t) { s[t] = *(const bf16x8*)as[t]; as[t] += 32; }
        #pragma unroll
        for (int t = 0; t < 2; ++t) {
            acc_i[t] = MFMA16(s[t], b0, acc_i[t]);
            acc_o[t] = MFMA16(s[t], b2, acc_o[t]);
            acc_u[t] = MFMA16(s[t], b3, acc_u[t]);
        }
        bf16x8 l[2];
        #pragma unroll
        for (int t = 0; t < 2; ++t) { l[t] = *(const bf16x8*)al[t]; al[t] += 32; }
        #pragma unroll
        for (int t = 0; t < 2; ++t) acc_fl[t] = MFMA16(l[t], b1, acc_fl[t]);
        bf16x8 rr[2];
        #pragma unroll
        for (int t = 0; t < 2; ++t) { rr[t] = *(const bf16x8*)ar[t]; ar[t] += 32; }
        #pragma unroll
        for (int t = 0; t < 2; ++t) acc_fr[t] = MFMA16(rr[t], b1, acc_fr[t]);
    }

    const float bij = bi[j], bfj = bfv[j], boj = bo[j], buj = bu[j];
    #pragma unroll
    for (int t = 0; t < 2; ++t) {
        const int n0 = mb + t * 16 + quad * 4;
        float hv[4];
        #pragma unroll
        for (int r = 0; r < 4; ++r) {
            const int node = n0 + r;
            const int ncl  = (node < cnt) ? node : (cnt - 1);
            size_t cix = (size_t)(2 * ncl) * HHE + j;
            float cl = bf2f(cc[cix]);
            float cr = bf2f(cc[cix + HHE]);
            float gi  = sigf(acc_i[t][r] + bij);
            float gfl = sigf(acc_fl[t][r] + bfj);
            float gfr = sigf(acc_fr[t][r] + bfj);
            float go  = sigf(acc_o[t][r] + boj);
            float gu  = tanhf_(acc_u[t][r] + buj);
            float cnv = gi * gu + gfl * cl + gfr * cr;
            float hnv = go * tanhf_(cnv);
            hv[r] = hnv;
            if (node < cnt) {
                size_t oix = (size_t)node * HHE + j;
                hw[oix] = rne_bf16(hnv);
                cw[oix] = rne_bf16(cnv);
                if (f32out) {
                    f32out[(size_t)node * 1024 + j]       = hnv;
                    f32out[(size_t)node * 1024 + 512 + j] = cnv;
                }
            }
        }
        if (n0 + 1 < cnt) hso[(size_t)(n0 >> 1) * HHE + j]       = rne_bf16(hv[0] + hv[1]);
        if (n0 + 3 < cnt) hso[(size_t)((n0 >> 1) + 1) * HHE + j] = rne_bf16(hv[2] + hv[3]);
    }
}

// ---------- fused tail: levels 6..0 in ONE launch, 32 blocks (one jtile each),
// W staged once into 128 KB LDS. Slot-array barrier (R9), coherent data stores,
// invalidate-only acquire; level lvl-1's x-phase overlaps the wait. ----------
#define TAIL_NBLK 32

__global__ __launch_bounds__(256) void tail_fused(
    const unsigned short* __restrict__ xb, const unsigned short* __restrict__ wp,
    const float* __restrict__ bi, const float* __restrict__ bfv,
    const float* __restrict__ bo, const float* __restrict__ bu,
    unsigned short* __restrict__ hA, unsigned short* __restrict__ cA,
    unsigned short* __restrict__ hB, unsigned short* __restrict__ cB,
    unsigned short* __restrict__ hs1, unsigned short* __restrict__ hs2,
    float* __restrict__ out, int* __restrict__ bar)
{
    __shared__ __align__(16) unsigned short WL[128 * 512];   // 128 KB: frag f = g*32+ks

    const int tid  = threadIdx.x;
    const int lane = tid & 63;
    const int wv   = tid >> 6;
    const int quad = lane >> 4;
    const int ln   = lane & 15;
    const int jt   = blockIdx.x;          // one jtile per block
    const int j    = jt * 16 + ln;
    const int wl   = lane * 8;

    // one-time: stage this jtile's full W (4 gates x 32 ks x 1 KB) into LDS
    #pragma unroll
    for (int i = 0; i < 32; ++i) {
        int f = i * 4 + wv;               // f = g*32 + ks
        const unsigned short* src = wp + ((size_t)(((f >> 5) * 32 + jt) * 32 + (f & 31))) * 512 + lane * 8;
        GLOAD_LDS16(src, &WL[f * 512]);
    }
    __syncthreads();   // vmcnt(0) drain -> W resident in LDS for the whole kernel

    const float bij = bi[j], bfj = bfv[j], boj = bo[j], buj = bu[j];
    f32x4 zero = {0.f, 0.f, 0.f, 0.f};

    // phase 1 of a level: x @ {Wi,Wf,Wo,Wu} — depends only on x and LDS W
    auto phase1 = [&](int lvl, f32x4& pi, f32x4& pf, f32x4& po, f32x4& pu) {
        const int cnt = 1 << lvl;
        const int start = cnt - 1;
        const int r0  = wv * 16 + ln;
        const int row = (r0 < cnt) ? r0 : (cnt - 1);
        pi = zero; pf = zero; po = zero; pu = zero;
        const unsigned short* ax = xb + (size_t)(start + row) * HHE + quad * 8;
        #pragma unroll 4
        for (int ks = 0; ks < 16; ++ks) {
            bf16x8 a  = *(const bf16x8*)ax; ax += 32;
            bf16x8 w0 = *(const bf16x8*)&WL[(0 * 32 + ks) * 512 + wl];
            bf16x8 w1 = *(const bf16x8*)&WL[(1 * 32 + ks) * 512 + wl];
            bf16x8 w2 = *(const bf16x8*)&WL[(2 * 32 + ks) * 512 + wl];
            bf16x8 w3 = *(const bf16x8*)&WL[(3 * 32 + ks) * 512 + wl];
            pi = MFMA16(a, w0, pi);
            pf = MFMA16(a, w1, pf);
            po = MFMA16(a, w2, po);
            pu = MFMA16(a, w3, pu);
        }
    };

    f32x4 p_i, p_f, p_o, p_u;
    phase1(6, p_i, p_f, p_o, p_u);

    int k = 0;
    for (int lvl = 6; lvl >= 0; --lvl) {
        const int cnt = 1 << lvl;
        const unsigned short *hc, *cc, *hs;
        unsigned short *hw, *cw, *hso;
        if (lvl & 1) { hc = hA; cc = cA; hs = hs1; hw = hB; cw = cB; hso = hs2; }
        else         { hc = hB; cc = cB; hs = hs2; hw = hA; cw = cA; hso = hs1; }

        const int r0  = wv * 16 + ln;
        const int row = (r0 < cnt) ? r0 : (cnt - 1);

        f32x4 acc_i = p_i, acc_o = p_o, acc_u = p_u;
        f32x4 acc_fl = p_f, acc_fr = p_f;

        // phase 2: hsum @ {Wi,Wo,Wu}, h_l/h_r @ Wf (k 512..1023)
        const unsigned short* as = hs + (size_t)row * HHE + quad * 8;
        const unsigned short* al = hc + (size_t)(2 * row) * HHE + quad * 8;
        const unsigned short* ar = al + HHE;
        #pragma unroll 4
        for (int ks = 0; ks < 16; ++ks) {
            bf16x8 w0 = *(const bf16x8*)&WL[(0 * 32 + 16 + ks) * 512 + wl];
            bf16x8 w1 = *(const bf16x8*)&WL[(1 * 32 + 16 + ks) * 512 + wl];
            bf16x8 w2 = *(const bf16x8*)&WL[(2 * 32 + 16 + ks) * 512 + wl];
            bf16x8 w3 = *(const bf16x8*)&WL[(3 * 32 + 16 + ks) * 512 + wl];
            bf16x8 s  = *(const bf16x8*)as; as += 32;
            bf16x8 l  = *(const bf16x8*)al; al += 32;
            bf16x8 rr = *(const bf16x8*)ar; ar += 32;
            acc_i  = MFMA16(s,  w0, acc_i);
            acc_o  = MFMA16(s,  w2, acc_o);
            acc_u  = MFMA16(s,  w3, acc_u);
            acc_fl = MFMA16(l,  w1, acc_fl);
            acc_fr = MFMA16(rr, w1, acc_fr);
        }

        // epilogue: exchanged h/c/hso written with agent-scope (write-through) stores
        const int n0 = wv * 16 + quad * 4;
        float hv[4];
        #pragma unroll
        for (int r = 0; r < 4; ++r) {
            const int node = n0 + r;
            const int ncl  = (node < cnt) ? node : (cnt - 1);
            size_t cix = (size_t)(2 * ncl) * HHE + j;
            float cl = bf2f(cc[cix]);
            float cr = bf2f(cc[cix + HHE]);
            float gi  = sigf(acc_i[r] + bij);
            float gfl = sigf(acc_fl[r] + bfj);
            float gfr = sigf(acc_fr[r] + bfj);
            float go  = sigf(acc_o[r] + boj);
            float gu  = tanhf_(acc_u[r] + buj);
            float cnv = gi * gu + gfl * cl + gfr * cr;
            float hnv = go * tanhf_(cnv);
            hv[r] = hnv;
            if (node < cnt) {
                size_t oix = (size_t)node * HHE + j;
                CSTORE_US(&hw[oix], rne_bf16(hnv));
                CSTORE_US(&cw[oix], rne_bf16(cnv));
                if (lvl == 0) {
                    out[(size_t)node * 1024 + j]       = hnv;
                    out[(size_t)node * 1024 + 512 + j] = cnv;
                }
            }
        }
        if (n0 + 1 < cnt) CSTORE_US(&hso[(size_t)(n0 >> 1) * HHE + j],       rne_bf16(hv[0] + hv[1]));
        if (n0 + 3 < cnt) CSTORE_US(&hso[(size_t)((n0 >> 1) + 1) * HHE + j], rne_bf16(hv[2] + hv[3]));

        if (lvl > 0) {
            ++k;
            __syncthreads();   // drains vmcnt(0) -> this block's coherent stores visible
            if (tid == 0)
                __hip_atomic_store(&bar[jt * 32], k, __ATOMIC_RELAXED, __HIP_MEMORY_SCOPE_AGENT);
            phase1(lvl - 1, p_i, p_f, p_o, p_u);
            if (wv == 0 && lane < TAIL_NBLK) {
                while (__hip_atomic_load(&bar[lane * 32], __ATOMIC_RELAXED, __HIP_MEMORY_SCOPE_AGENT) < k)
                    __builtin_amdgcn_s_sleep(2);
            }
            __syncthreads();
            __builtin_amdgcn_fence(__ATOMIC_ACQUIRE, "agent");  // invalidate-only (no wb)
        }
    }
}

extern "C" void kernel_launch(void* const* d_in, const int* in_sizes, int n_in,
                              void* d_out, int out_size, void* d_ws, size_t ws_size,
                              hipStream_t stream) {
    const float* x  = (const float*)d_in[0];
    const float* Wi = (const float*)d_in[1];
    const float* bi = (const float*)d_in[2];
    const float* Wf = (const float*)d_in[3];
    const float* bf = (const float*)d_in[4];
    const float* Wo = (const float*)d_in[5];
    const float* bo = (const float*)d_in[6];
    const float* Wu = (const float*)d_in[7];
    const float* bu = (const float*)d_in[8];
    float* out = (float*)d_out;

    unsigned short* xb  = (unsigned short*)d_ws;          // x bf16
    unsigned short* wp  = xb  + 16776704;                 // packed W bf16
    unsigned short* hA  = wp  + 2097152;                  // h ping (16384 rows)
    unsigned short* hB  = hA  + 8388608;                  // h pong ( 8192 rows)
    unsigned short* hs1 = hB  + 4194304;                  // hsum ( 8192 rows)
    unsigned short* hs2 = hs1 + 4194304;                  // hsum ( 4096 rows)
    unsigned short* cA  = hs2 + 2097152;                  // c ping
    unsigned short* cB  = cA  + 8388608;                  // c pong

    const size_t BAR_OFF = (size_t)96 << 20;   // layout ends at ~100.66 MB; slots at 96 MiB are past it
    const bool fused = ws_size >= BAR_OFF + 4096;
    int* bar = (int*)((char*)d_ws + BAR_OFF);  // 32 slots x 128 B

    // fused one-time prep: W pack (1024 blocks) + x conversion (8192 blocks)
    prep<<<9216, 256, 0, stream>>>(x, Wi, Wf, Wo, Wu, xb, wp, fused ? bar : nullptr);

    // leaf: R4 structure; grid (256, 8) m-major
    leaf_v3<<<dim3(256, 8), 256, 0, stream>>>(xb, wp, bi, bo, bu, hA, cA, hs1, 16383, 16384);

    // levels 13..7 (cnt >= 128): merged-phase kernel (one barrier per K-step)
    for (int lvl = 13; lvl >= 7; --lvl) {
        int cnt   = 1 << lvl;
        int start = cnt - 1;
        const unsigned short *hc, *cc, *hs;
        unsigned short *hw, *cw, *hso;
        if (lvl & 1) { hc = hA; cc = cA; hs = hs1; hw = hB; cw = cB; hso = hs2; }
        else         { hc = hB; cc = cB; hs = hs2; hw = hA; cw = cA; hso = hs1; }
        level_m<<<dim3(cnt / 64, 8), 256, 0, stream>>>(xb, wp, bi, bf, bo, bu,
                                                       hc, cc, hs, hw, cw, hso, start, cnt);
    }

    if (fused) {
        // levels 6..0 in one persistent launch, W in LDS, 32 co-resident blocks
        tail_fused<<<TAIL_NBLK, 256, 0, stream>>>(xb, wp, bi, bf, bo, bu,
                                                  hA, cA, hB, cB, hs1, hs2, out, bar);
    } else {
        // fallback: per-level launches (R4 path)
        level_v3<<<dim3(1, 8), 256, 0, stream>>>(xb, wp, bi, bf, bo, bu,
                                                 hB, cB, hs2, hA, cA, hs1, 63, 64);
        for (int lvl = 5; lvl >= 0; --lvl) {
            int cnt   = 1 << lvl;
            int start = cnt - 1;
            const unsigned short *hc, *cc, *hs;
            unsigned short *hw, *cw, *hso;
            if (lvl & 1) { hc = hA; cc = cA; hs = hs1; hw = hB; cw = cB; hso = hs2; }
            else         { hc = hB; cc = cB; hs = hs2; hw = hA; cw = cA; hso = hs1; }
            float* f32out = (lvl == 0) ? out : nullptr;
            level_sm<<<dim3((cnt + 31) / 32, 8), 256, 0, stream>>>(xb, wp, bi, bf, bo, bu,
                                                                   hc, cc, hs, hw, cw, hso, f32out,
                                                                   start, cnt);
        }
    }
}